// Round 1
// baseline (3044.124 us; speedup 1.0000x reference)
//
#include <hip/hip_runtime.h>

#define NN 100000
#define NE 1600000
// IN_CH = HID = 64, OUT_CH = 16

// ---------------------------------------------------------------------------
// Detect int64 vs int32 edge_index: for int64 (values < 2^31) every odd
// 32-bit word is 0; for int32 the odd words are src values (random in
// [0,100000), essentially never all zero across 256 samples).
__global__ void detect_mode_kernel(const int* ei32, int* flag) {
    __shared__ int any_nonzero;
    if (threadIdx.x == 0) any_nonzero = 0;
    __syncthreads();
    int idx = 1 + 2 * threadIdx.x;   // odd 32-bit indices 1,3,...,511
    if (ei32[idx] != 0) atomicOr(&any_nonzero, 1);
    __syncthreads();
    if (threadIdx.x == 0) flag[0] = (any_nonzero == 0) ? 1 : 0;  // 1 => int64
}

__device__ __forceinline__ void load_edge(const void* ei, int is64, int e,
                                          int& s, int& d) {
    if (is64) {
        const long long* p = (const long long*)ei;
        s = (int)p[e];
        d = (int)p[NE + e];
    } else {
        const int* p = (const int*)ei;
        s = p[e];
        d = p[NE + e];
    }
}

// ---------------------------------------------------------------------------
// Scatter-add aggregation: 16 threads per edge, each handles 4 channels.
// Optionally also accumulates degree counts (countToo != 0).
__global__ void scatter_add_kernel(const void* ei, const int* flag,
                                   const float* __restrict__ feat,
                                   float* __restrict__ agg,
                                   float* __restrict__ cnt, int countToo) {
    const int is64 = *flag;
    long long tid = (long long)blockIdx.x * blockDim.x + threadIdx.x;
    const long long total = (long long)NE * 16;
    const long long stride = (long long)gridDim.x * blockDim.x;
    for (; tid < total; tid += stride) {
        int e = (int)(tid >> 4);
        int q = (int)(tid & 15);
        int s, d;
        load_edge(ei, is64, e, s, d);
        const float4 v = ((const float4*)feat)[s * 16 + q];
        float* a = agg + (size_t)d * 64 + q * 4;
        atomicAdd(a + 0, v.x);
        atomicAdd(a + 1, v.y);
        atomicAdd(a + 2, v.z);
        atomicAdd(a + 3, v.w);
        if (countToo && q == 0) atomicAdd(cnt + d, 1.0f);
    }
}

// ---------------------------------------------------------------------------
// Per-node SAGE layer: h[n,c] = relu( sum_k agg_mean[n,k]*Wl[c,k]
//                                   + sum_k xroot[n,k]*Wr[c,k] + b[c] )
// Block = 256 threads = 4 nodes; lane (0..63) = output channel.
// Weights stored transposed in LDS: Wt[k*64+c] = W[c*64+k]  -> conflict-free.
__global__ void sage_node_kernel(const float* __restrict__ agg,
                                 const float* __restrict__ cnt,
                                 const float* __restrict__ xroot,
                                 const float* __restrict__ Wl,
                                 const float* __restrict__ b,
                                 const float* __restrict__ Wr,
                                 float* __restrict__ hout) {
    __shared__ float WtL[64 * 64];
    __shared__ float WtR[64 * 64];
    __shared__ float bs[64];
    __shared__ float vs[4][64];
    __shared__ float xs[4][64];

    for (int idx = threadIdx.x; idx < 64 * 64; idx += 256) {
        int c = idx >> 6, k = idx & 63;
        WtL[k * 64 + c] = Wl[idx];
        WtR[k * 64 + c] = Wr[idx];
    }
    if (threadIdx.x < 64) bs[threadIdx.x] = b[threadIdx.x];
    __syncthreads();

    const int ln = threadIdx.x >> 6;   // local node 0..3
    const int c  = threadIdx.x & 63;   // output channel

    for (int base = blockIdx.x * 4; base < NN; base += gridDim.x * 4) {
        const int n = base + ln;
        if (n < NN) {
            float inv = 1.0f / fmaxf(cnt[n], 1.0f);
            vs[ln][c] = agg[(size_t)n * 64 + c] * inv;
            xs[ln][c] = xroot[(size_t)n * 64 + c];
        }
        __syncthreads();
        if (n < NN) {
            float acc = bs[c];
#pragma unroll
            for (int k = 0; k < 64; ++k) {
                acc = fmaf(vs[ln][k], WtL[k * 64 + c], acc);
                acc = fmaf(xs[ln][k], WtR[k * 64 + c], acc);
            }
            hout[(size_t)n * 64 + c] = fmaxf(acc, 0.0f);
        }
        __syncthreads();
    }
}

// ---------------------------------------------------------------------------
// Layer-2 node kernel fused with the final 64->16 projection.
__global__ void sage_node_out_kernel(const float* __restrict__ agg,
                                     const float* __restrict__ cnt,
                                     const float* __restrict__ h1,
                                     const float* __restrict__ Wl,
                                     const float* __restrict__ b,
                                     const float* __restrict__ Wr,
                                     const float* __restrict__ Wlin,
                                     const float* __restrict__ blin,
                                     float* __restrict__ out) {
    __shared__ float WtL[64 * 64];
    __shared__ float WtR[64 * 64];
    __shared__ float WtO[64 * 16];
    __shared__ float bs[64];
    __shared__ float bo[16];
    __shared__ float vs[4][64];
    __shared__ float xs[4][64];
    __shared__ float hs[4][64];

    for (int idx = threadIdx.x; idx < 64 * 64; idx += 256) {
        int c = idx >> 6, k = idx & 63;
        WtL[k * 64 + c] = Wl[idx];
        WtR[k * 64 + c] = Wr[idx];
    }
    for (int idx = threadIdx.x; idx < 16 * 64; idx += 256) {
        int o = idx >> 6, k = idx & 63;
        WtO[k * 16 + o] = Wlin[idx];
    }
    if (threadIdx.x < 64) bs[threadIdx.x] = b[threadIdx.x];
    if (threadIdx.x < 16) bo[threadIdx.x] = blin[threadIdx.x];
    __syncthreads();

    const int ln = threadIdx.x >> 6;
    const int c  = threadIdx.x & 63;

    for (int base = blockIdx.x * 4; base < NN; base += gridDim.x * 4) {
        const int n = base + ln;
        if (n < NN) {
            float inv = 1.0f / fmaxf(cnt[n], 1.0f);
            vs[ln][c] = agg[(size_t)n * 64 + c] * inv;
            xs[ln][c] = h1[(size_t)n * 64 + c];
        }
        __syncthreads();
        if (n < NN) {
            float acc = bs[c];
#pragma unroll
            for (int k = 0; k < 64; ++k) {
                acc = fmaf(vs[ln][k], WtL[k * 64 + c], acc);
                acc = fmaf(xs[ln][k], WtR[k * 64 + c], acc);
            }
            hs[ln][c] = fmaxf(acc, 0.0f);   // h2
        }
        __syncthreads();
        if (n < NN && c < 16) {
            float acc = bo[c];
#pragma unroll
            for (int k = 0; k < 64; ++k)
                acc = fmaf(hs[ln][k], WtO[k * 16 + c], acc);
            out[(size_t)n * 16 + c] = acc;
        }
        __syncthreads();
    }
}

// ---------------------------------------------------------------------------
extern "C" void kernel_launch(void* const* d_in, const int* in_sizes, int n_in,
                              void* d_out, int out_size, void* d_ws, size_t ws_size,
                              hipStream_t stream) {
    const float* x    = (const float*)d_in[0];
    const void*  ei   = d_in[1];
    const float* W1l  = (const float*)d_in[2];
    const float* b1   = (const float*)d_in[3];
    const float* W1r  = (const float*)d_in[4];
    const float* W2l  = (const float*)d_in[5];
    const float* b2   = (const float*)d_in[6];
    const float* W2r  = (const float*)d_in[7];
    const float* Wlin = (const float*)d_in[8];
    const float* blin = (const float*)d_in[9];
    float* out = (float*)d_out;

    char* w = (char*)d_ws;
    int*   flag = (int*)w;                                    // 4 B
    float* cnt  = (float*)(w + 1024);                         // 400 KB
    float* agg  = (float*)(w + 1024 + 1024 * 1024);           // 25.6 MB
    float* h1   = (float*)(w + 1024 + 1024 * 1024 + 28 * 1024 * 1024); // 25.6 MB

    detect_mode_kernel<<<1, 256, 0, stream>>>((const int*)ei, flag);

    hipMemsetAsync(cnt, 0, (size_t)NN * sizeof(float), stream);
    hipMemsetAsync(agg, 0, (size_t)NN * 64 * sizeof(float), stream);

    // ---- layer 1 ----
    scatter_add_kernel<<<8192, 256, 0, stream>>>(ei, flag, x, agg, cnt, 1);
    sage_node_kernel<<<1024, 256, 0, stream>>>(agg, cnt, x, W1l, b1, W1r, h1);

    // ---- layer 2 + output head ----
    hipMemsetAsync(agg, 0, (size_t)NN * 64 * sizeof(float), stream);
    scatter_add_kernel<<<8192, 256, 0, stream>>>(ei, flag, h1, agg, cnt, 0);
    sage_node_out_kernel<<<1024, 256, 0, stream>>>(agg, cnt, h1, W2l, b2, W2r,
                                                   Wlin, blin, out);
}

// Round 2
// 732.107 us; speedup vs baseline: 4.1580x; 4.1580x over previous
//
#include <hip/hip_runtime.h>

#define NN 100000
#define NE 1600000
// IN_CH = HID = 64, OUT_CH = 16

// ---------------------------------------------------------------------------
// Detect int64 vs int32 edge_index: for int64 (values < 2^31) every odd
// 32-bit word is 0; for int32 the odd words are src values (random in
// [0,100000), essentially never all zero across 256 samples).
__global__ void detect_mode_kernel(const int* ei32, int* flag) {
    __shared__ int any_nonzero;
    if (threadIdx.x == 0) any_nonzero = 0;
    __syncthreads();
    int idx = 1 + 2 * threadIdx.x;   // odd 32-bit indices 1,3,...,511
    if (ei32[idx] != 0) atomicOr(&any_nonzero, 1);
    __syncthreads();
    if (threadIdx.x == 0) flag[0] = (any_nonzero == 0) ? 1 : 0;  // 1 => int64
}

__device__ __forceinline__ void load_edge(const void* ei, int is64, int e,
                                          int& s, int& d) {
    if (is64) {
        const long long* p = (const long long*)ei;
        s = (int)p[e];
        d = (int)p[NE + e];
    } else {
        const int* p = (const int*)ei;
        s = p[e];
        d = p[NE + e];
    }
}

// ---------------------------------------------------------------------------
// CSR build step 1: degree histogram of dst.
__global__ void hist_kernel(const void* ei, const int* flag, int* deg) {
    const int is64 = *flag;
    int e = blockIdx.x * blockDim.x + threadIdx.x;
    if (e < NE) {
        int s, d;
        load_edge(ei, is64, e, s, d);
        atomicAdd(&deg[d], 1);
    }
}

// CSR build step 2: exclusive scan of deg -> rowptr (single workgroup).
__global__ void scan_kernel(const int* __restrict__ deg, int* __restrict__ rowptr) {
    __shared__ int part[1024];
    const int T = 1024;
    const int t = threadIdx.x;
    const int CH = (NN + T - 1) / T;   // 98 elements per thread
    const int base = t * CH;
    int s = 0;
    for (int i = 0; i < CH; ++i) {
        int idx = base + i;
        if (idx < NN) s += deg[idx];
    }
    part[t] = s;
    __syncthreads();
    // Hillis-Steele inclusive scan over 1024 partials
    for (int off = 1; off < T; off <<= 1) {
        int v = (t >= off) ? part[t - off] : 0;
        __syncthreads();
        part[t] += v;
        __syncthreads();
    }
    int run = (t == 0) ? 0 : part[t - 1];   // exclusive prefix of this chunk
    for (int i = 0; i < CH; ++i) {
        int idx = base + i;
        if (idx < NN) { rowptr[idx] = run; run += deg[idx]; }
    }
    if (t == T - 1) rowptr[NN] = run;       // == NE
}

// CSR build step 3: scatter src ids into col[] slots.
__global__ void fill_kernel(const void* ei, const int* flag,
                            const int* __restrict__ rowptr,
                            int* __restrict__ fill, int* __restrict__ col) {
    const int is64 = *flag;
    int e = blockIdx.x * blockDim.x + threadIdx.x;
    if (e < NE) {
        int s, d;
        load_edge(ei, is64, e, s, d);
        int pos = rowptr[d] + atomicAdd(&fill[d], 1);
        col[pos] = s;
    }
}

// ---------------------------------------------------------------------------
// Gather-based mean aggregation: one wave per node, lane = channel.
// Each edge read is one fully-coalesced 256 B row of feat.
__global__ void aggregate_kernel(const int* __restrict__ rowptr,
                                 const int* __restrict__ col,
                                 const float* __restrict__ feat,
                                 float* __restrict__ agg) {
    const int wid  = (blockIdx.x * blockDim.x + threadIdx.x) >> 6;  // node id
    const int lane = threadIdx.x & 63;                              // channel
    if (wid >= NN) return;
    const int beg = rowptr[wid], end = rowptr[wid + 1];
    float a0 = 0.f, a1 = 0.f, a2 = 0.f, a3 = 0.f;
    int j = beg;
    for (; j + 4 <= end; j += 4) {
        int s0 = col[j], s1 = col[j + 1], s2 = col[j + 2], s3 = col[j + 3];
        a0 += feat[(size_t)s0 * 64 + lane];
        a1 += feat[(size_t)s1 * 64 + lane];
        a2 += feat[(size_t)s2 * 64 + lane];
        a3 += feat[(size_t)s3 * 64 + lane];
    }
    for (; j < end; ++j) a0 += feat[(size_t)col[j] * 64 + lane];
    float sum = (a0 + a1) + (a2 + a3);
    float inv = 1.0f / fmaxf((float)(end - beg), 1.0f);
    agg[(size_t)wid * 64 + lane] = sum * inv;   // mean fused here
}

// ---------------------------------------------------------------------------
// Per-node SAGE layer: h[n,c] = relu( sum_k agg[n,k]*Wl[c,k]
//                                   + sum_k xroot[n,k]*Wr[c,k] + b[c] )
// Block = 256 threads = 4 nodes; lane (0..63) = output channel.
// Weights stored transposed in LDS: Wt[k*64+c] = W[c*64+k]  -> conflict-free.
__global__ void sage_node_kernel(const float* __restrict__ agg,
                                 const float* __restrict__ xroot,
                                 const float* __restrict__ Wl,
                                 const float* __restrict__ b,
                                 const float* __restrict__ Wr,
                                 float* __restrict__ hout) {
    __shared__ float WtL[64 * 64];
    __shared__ float WtR[64 * 64];
    __shared__ float bs[64];
    __shared__ float vs[4][64];
    __shared__ float xs[4][64];

    for (int idx = threadIdx.x; idx < 64 * 64; idx += 256) {
        int c = idx >> 6, k = idx & 63;
        WtL[k * 64 + c] = Wl[idx];
        WtR[k * 64 + c] = Wr[idx];
    }
    if (threadIdx.x < 64) bs[threadIdx.x] = b[threadIdx.x];
    __syncthreads();

    const int ln = threadIdx.x >> 6;   // local node 0..3
    const int c  = threadIdx.x & 63;   // output channel

    for (int base = blockIdx.x * 4; base < NN; base += gridDim.x * 4) {
        const int n = base + ln;
        if (n < NN) {
            vs[ln][c] = agg[(size_t)n * 64 + c];
            xs[ln][c] = xroot[(size_t)n * 64 + c];
        }
        __syncthreads();
        if (n < NN) {
            float acc = bs[c];
#pragma unroll
            for (int k = 0; k < 64; ++k) {
                acc = fmaf(vs[ln][k], WtL[k * 64 + c], acc);
                acc = fmaf(xs[ln][k], WtR[k * 64 + c], acc);
            }
            hout[(size_t)n * 64 + c] = fmaxf(acc, 0.0f);
        }
        __syncthreads();
    }
}

// ---------------------------------------------------------------------------
// Layer-2 node kernel fused with the final 64->16 projection.
__global__ void sage_node_out_kernel(const float* __restrict__ agg,
                                     const float* __restrict__ h1,
                                     const float* __restrict__ Wl,
                                     const float* __restrict__ b,
                                     const float* __restrict__ Wr,
                                     const float* __restrict__ Wlin,
                                     const float* __restrict__ blin,
                                     float* __restrict__ out) {
    __shared__ float WtL[64 * 64];
    __shared__ float WtR[64 * 64];
    __shared__ float WtO[64 * 16];
    __shared__ float bs[64];
    __shared__ float bo[16];
    __shared__ float vs[4][64];
    __shared__ float xs[4][64];
    __shared__ float hs[4][64];

    for (int idx = threadIdx.x; idx < 64 * 64; idx += 256) {
        int c = idx >> 6, k = idx & 63;
        WtL[k * 64 + c] = Wl[idx];
        WtR[k * 64 + c] = Wr[idx];
    }
    for (int idx = threadIdx.x; idx < 16 * 64; idx += 256) {
        int o = idx >> 6, k = idx & 63;
        WtO[k * 16 + o] = Wlin[idx];
    }
    if (threadIdx.x < 64) bs[threadIdx.x] = b[threadIdx.x];
    if (threadIdx.x < 16) bo[threadIdx.x] = blin[threadIdx.x];
    __syncthreads();

    const int ln = threadIdx.x >> 6;
    const int c  = threadIdx.x & 63;

    for (int base = blockIdx.x * 4; base < NN; base += gridDim.x * 4) {
        const int n = base + ln;
        if (n < NN) {
            vs[ln][c] = agg[(size_t)n * 64 + c];
            xs[ln][c] = h1[(size_t)n * 64 + c];
        }
        __syncthreads();
        if (n < NN) {
            float acc = bs[c];
#pragma unroll
            for (int k = 0; k < 64; ++k) {
                acc = fmaf(vs[ln][k], WtL[k * 64 + c], acc);
                acc = fmaf(xs[ln][k], WtR[k * 64 + c], acc);
            }
            hs[ln][c] = fmaxf(acc, 0.0f);   // h2
        }
        __syncthreads();
        if (n < NN && c < 16) {
            float acc = bo[c];
#pragma unroll
            for (int k = 0; k < 64; ++k)
                acc = fmaf(hs[ln][k], WtO[k * 16 + c], acc);
            out[(size_t)n * 16 + c] = acc;
        }
        __syncthreads();
    }
}

// ---------------------------------------------------------------------------
extern "C" void kernel_launch(void* const* d_in, const int* in_sizes, int n_in,
                              void* d_out, int out_size, void* d_ws, size_t ws_size,
                              hipStream_t stream) {
    const float* x    = (const float*)d_in[0];
    const void*  ei   = d_in[1];
    const float* W1l  = (const float*)d_in[2];
    const float* b1   = (const float*)d_in[3];
    const float* W1r  = (const float*)d_in[4];
    const float* W2l  = (const float*)d_in[5];
    const float* b2   = (const float*)d_in[6];
    const float* W2r  = (const float*)d_in[7];
    const float* Wlin = (const float*)d_in[8];
    const float* blin = (const float*)d_in[9];
    float* out = (float*)d_out;

    char* w = (char*)d_ws;
    int*   flag   = (int*)w;                                   // 4 B       @ 0
    int*   deg    = (int*)(w + (size_t)4 * 1024);              // 400 KB    @ 4K
    int*   fill   = (int*)(w + (size_t)512 * 1024);            // 400 KB    @ 512K
    int*   rowptr = (int*)(w + (size_t)1024 * 1024);           // 400 KB+4  @ 1M
    int*   col    = (int*)(w + (size_t)2 * 1024 * 1024);       // 6.4 MB    @ 2M
    float* agg    = (float*)(w + (size_t)10 * 1024 * 1024);    // 25.6 MB   @ 10M
    float* h1     = (float*)(w + (size_t)36 * 1024 * 1024);    // 25.6 MB   @ 36M

    detect_mode_kernel<<<1, 256, 0, stream>>>((const int*)ei, flag);

    // ---- CSR build (per call; no cached state allowed) ----
    hipMemsetAsync(deg, 0, (size_t)NN * sizeof(int), stream);
    hipMemsetAsync(fill, 0, (size_t)NN * sizeof(int), stream);
    hist_kernel<<<(NE + 255) / 256, 256, 0, stream>>>(ei, flag, deg);
    scan_kernel<<<1, 1024, 0, stream>>>(deg, rowptr);
    fill_kernel<<<(NE + 255) / 256, 256, 0, stream>>>(ei, flag, rowptr, fill, col);

    const int aggBlocks = (NN * 64 + 255) / 256;   // one wave per node

    // ---- layer 1 ----
    aggregate_kernel<<<aggBlocks, 256, 0, stream>>>(rowptr, col, x, agg);
    sage_node_kernel<<<1024, 256, 0, stream>>>(agg, x, W1l, b1, W1r, h1);

    // ---- layer 2 + output head ----
    aggregate_kernel<<<aggBlocks, 256, 0, stream>>>(rowptr, col, h1, agg);
    sage_node_out_kernel<<<1024, 256, 0, stream>>>(agg, h1, W2l, b2, W2r,
                                                   Wlin, blin, out);
}

// Round 3
// 551.796 us; speedup vs baseline: 5.5168x; 1.3268x over previous
//
#include <hip/hip_runtime.h>

#define NN 100000
#define NE 1600000
// IN_CH = HID = 64, OUT_CH = 16

#define SCAN_BS 128
#define SCAN_NB ((NN + SCAN_BS - 1) / SCAN_BS)   // 782

// ---------------------------------------------------------------------------
// Detect int64 vs int32 edge_index: for int64 (values < 2^31) every odd
// 32-bit word is 0; for int32 the odd words are src values (random in
// [0,100000), essentially never all zero across 256 samples).
__global__ void detect_mode_kernel(const int* ei32, int* flag) {
    __shared__ int any_nonzero;
    if (threadIdx.x == 0) any_nonzero = 0;
    __syncthreads();
    int idx = 1 + 2 * threadIdx.x;   // odd 32-bit indices 1,3,...,511
    if (ei32[idx] != 0) atomicOr(&any_nonzero, 1);
    __syncthreads();
    if (threadIdx.x == 0) flag[0] = (any_nonzero == 0) ? 1 : 0;  // 1 => int64
}

__device__ __forceinline__ void load_edge(const void* ei, int is64, int e,
                                          int& s, int& d) {
    if (is64) {
        const long long* p = (const long long*)ei;
        s = (int)p[e];
        d = (int)p[NE + e];
    } else {
        const int* p = (const int*)ei;
        s = p[e];
        d = p[NE + e];
    }
}

// ---------------------------------------------------------------------------
// CSR build step 1: degree histogram of dst.
__global__ void hist_kernel(const void* ei, const int* flag, int* deg) {
    const int is64 = *flag;
    int e = blockIdx.x * blockDim.x + threadIdx.x;
    if (e < NE) {
        int s, d;
        load_edge(ei, is64, e, s, d);
        atomicAdd(&deg[d], 1);
    }
}

// ---------------------------------------------------------------------------
// CSR build step 2: hierarchical exclusive scan of deg -> rowptr.
// Phase A: per-block (128-wide) partial sums.
__global__ void partial_sum_kernel(const int* __restrict__ deg,
                                   int* __restrict__ partial) {
    __shared__ int sm[SCAN_BS];
    const int t = threadIdx.x;
    const int idx = blockIdx.x * SCAN_BS + t;
    sm[t] = (idx < NN) ? deg[idx] : 0;
    __syncthreads();
    for (int off = SCAN_BS / 2; off > 0; off >>= 1) {
        if (t < off) sm[t] += sm[t + off];
        __syncthreads();
    }
    if (t == 0) partial[blockIdx.x] = sm[0];
}

// Phase B: single block scans the 782 partials (padded to 1024).
__global__ void scan_partials_kernel(const int* __restrict__ partial,
                                     int* __restrict__ pprefix,
                                     int* __restrict__ rowptr) {
    __shared__ int sm[1024];
    const int t = threadIdx.x;
    int v = (t < SCAN_NB) ? partial[t] : 0;
    sm[t] = v;
    __syncthreads();
    for (int off = 1; off < 1024; off <<= 1) {
        int u = (t >= off) ? sm[t - off] : 0;
        __syncthreads();
        sm[t] += u;
        __syncthreads();
    }
    if (t < SCAN_NB) pprefix[t] = sm[t] - v;   // exclusive prefix of chunks
    if (t == 0) rowptr[NN] = NE;               // total degree == NE always
}

// Phase C: in-block scan + chunk offset -> rowptr.
__global__ void writeout_kernel(const int* __restrict__ deg,
                                const int* __restrict__ pprefix,
                                int* __restrict__ rowptr) {
    __shared__ int sm[SCAN_BS];
    const int t = threadIdx.x;
    const int idx = blockIdx.x * SCAN_BS + t;
    int v = (idx < NN) ? deg[idx] : 0;
    sm[t] = v;
    __syncthreads();
    for (int off = 1; off < SCAN_BS; off <<= 1) {
        int u = (t >= off) ? sm[t - off] : 0;
        __syncthreads();
        sm[t] += u;
        __syncthreads();
    }
    if (idx < NN) rowptr[idx] = pprefix[blockIdx.x] + sm[t] - v;
}

// ---------------------------------------------------------------------------
// CSR build step 3: scatter src ids into col[] slots.
__global__ void fill_kernel(const void* ei, const int* flag,
                            const int* __restrict__ rowptr,
                            int* __restrict__ fill, int* __restrict__ col) {
    const int is64 = *flag;
    int e = blockIdx.x * blockDim.x + threadIdx.x;
    if (e < NE) {
        int s, d;
        load_edge(ei, is64, e, s, d);
        int pos = rowptr[d] + atomicAdd(&fill[d], 1);
        col[pos] = s;
    }
}

// ---------------------------------------------------------------------------
// Gather-based mean aggregation: one wave per node, lane = channel.
// Each edge read is one fully-coalesced 256 B row of feat.
__global__ void aggregate_kernel(const int* __restrict__ rowptr,
                                 const int* __restrict__ col,
                                 const float* __restrict__ feat,
                                 float* __restrict__ agg) {
    const int wid  = (blockIdx.x * blockDim.x + threadIdx.x) >> 6;  // node id
    const int lane = threadIdx.x & 63;                              // channel
    if (wid >= NN) return;
    const int beg = rowptr[wid], end = rowptr[wid + 1];
    float a0 = 0.f, a1 = 0.f, a2 = 0.f, a3 = 0.f;
    int j = beg;
    for (; j + 4 <= end; j += 4) {
        int s0 = col[j], s1 = col[j + 1], s2 = col[j + 2], s3 = col[j + 3];
        a0 += feat[(size_t)s0 * 64 + lane];
        a1 += feat[(size_t)s1 * 64 + lane];
        a2 += feat[(size_t)s2 * 64 + lane];
        a3 += feat[(size_t)s3 * 64 + lane];
    }
    for (; j < end; ++j) a0 += feat[(size_t)col[j] * 64 + lane];
    float sum = (a0 + a1) + (a2 + a3);
    float inv = 1.0f / fmaxf((float)(end - beg), 1.0f);
    agg[(size_t)wid * 64 + lane] = sum * inv;   // mean fused here
}

// ---------------------------------------------------------------------------
// Per-node SAGE layer: h[n,c] = relu( sum_k agg[n,k]*Wl[c,k]
//                                   + sum_k xroot[n,k]*Wr[c,k] + b[c] )
// Block = 256 threads = 4 nodes; lane (0..63) = output channel.
// Weights stored transposed in LDS: Wt[k*64+c] = W[c*64+k]  -> conflict-free.
__global__ void sage_node_kernel(const float* __restrict__ agg,
                                 const float* __restrict__ xroot,
                                 const float* __restrict__ Wl,
                                 const float* __restrict__ b,
                                 const float* __restrict__ Wr,
                                 float* __restrict__ hout) {
    __shared__ float WtL[64 * 64];
    __shared__ float WtR[64 * 64];
    __shared__ float bs[64];
    __shared__ float vs[4][64];
    __shared__ float xs[4][64];

    for (int idx = threadIdx.x; idx < 64 * 64; idx += 256) {
        int c = idx >> 6, k = idx & 63;
        WtL[k * 64 + c] = Wl[idx];
        WtR[k * 64 + c] = Wr[idx];
    }
    if (threadIdx.x < 64) bs[threadIdx.x] = b[threadIdx.x];
    __syncthreads();

    const int ln = threadIdx.x >> 6;   // local node 0..3
    const int c  = threadIdx.x & 63;   // output channel

    for (int base = blockIdx.x * 4; base < NN; base += gridDim.x * 4) {
        const int n = base + ln;
        if (n < NN) {
            vs[ln][c] = agg[(size_t)n * 64 + c];
            xs[ln][c] = xroot[(size_t)n * 64 + c];
        }
        __syncthreads();
        if (n < NN) {
            float acc = bs[c];
#pragma unroll
            for (int k = 0; k < 64; ++k) {
                acc = fmaf(vs[ln][k], WtL[k * 64 + c], acc);
                acc = fmaf(xs[ln][k], WtR[k * 64 + c], acc);
            }
            hout[(size_t)n * 64 + c] = fmaxf(acc, 0.0f);
        }
        __syncthreads();
    }
}

// ---------------------------------------------------------------------------
// Layer-2 node kernel fused with the final 64->16 projection.
__global__ void sage_node_out_kernel(const float* __restrict__ agg,
                                     const float* __restrict__ h1,
                                     const float* __restrict__ Wl,
                                     const float* __restrict__ b,
                                     const float* __restrict__ Wr,
                                     const float* __restrict__ Wlin,
                                     const float* __restrict__ blin,
                                     float* __restrict__ out) {
    __shared__ float WtL[64 * 64];
    __shared__ float WtR[64 * 64];
    __shared__ float WtO[64 * 16];
    __shared__ float bs[64];
    __shared__ float bo[16];
    __shared__ float vs[4][64];
    __shared__ float xs[4][64];
    __shared__ float hs[4][64];

    for (int idx = threadIdx.x; idx < 64 * 64; idx += 256) {
        int c = idx >> 6, k = idx & 63;
        WtL[k * 64 + c] = Wl[idx];
        WtR[k * 64 + c] = Wr[idx];
    }
    for (int idx = threadIdx.x; idx < 16 * 64; idx += 256) {
        int o = idx >> 6, k = idx & 63;
        WtO[k * 16 + o] = Wlin[idx];
    }
    if (threadIdx.x < 64) bs[threadIdx.x] = b[threadIdx.x];
    if (threadIdx.x < 16) bo[threadIdx.x] = blin[threadIdx.x];
    __syncthreads();

    const int ln = threadIdx.x >> 6;
    const int c  = threadIdx.x & 63;

    for (int base = blockIdx.x * 4; base < NN; base += gridDim.x * 4) {
        const int n = base + ln;
        if (n < NN) {
            vs[ln][c] = agg[(size_t)n * 64 + c];
            xs[ln][c] = h1[(size_t)n * 64 + c];
        }
        __syncthreads();
        if (n < NN) {
            float acc = bs[c];
#pragma unroll
            for (int k = 0; k < 64; ++k) {
                acc = fmaf(vs[ln][k], WtL[k * 64 + c], acc);
                acc = fmaf(xs[ln][k], WtR[k * 64 + c], acc);
            }
            hs[ln][c] = fmaxf(acc, 0.0f);   // h2
        }
        __syncthreads();
        if (n < NN && c < 16) {
            float acc = bo[c];
#pragma unroll
            for (int k = 0; k < 64; ++k)
                acc = fmaf(hs[ln][k], WtO[k * 16 + c], acc);
            out[(size_t)n * 16 + c] = acc;
        }
        __syncthreads();
    }
}

// ---------------------------------------------------------------------------
extern "C" void kernel_launch(void* const* d_in, const int* in_sizes, int n_in,
                              void* d_out, int out_size, void* d_ws, size_t ws_size,
                              hipStream_t stream) {
    const float* x    = (const float*)d_in[0];
    const void*  ei   = d_in[1];
    const float* W1l  = (const float*)d_in[2];
    const float* b1   = (const float*)d_in[3];
    const float* W1r  = (const float*)d_in[4];
    const float* W2l  = (const float*)d_in[5];
    const float* b2   = (const float*)d_in[6];
    const float* W2r  = (const float*)d_in[7];
    const float* Wlin = (const float*)d_in[8];
    const float* blin = (const float*)d_in[9];
    float* out = (float*)d_out;

    char* w = (char*)d_ws;
    int*   flag    = (int*)w;                                   // 4 B       @ 0
    int*   partial = (int*)(w + (size_t)8 * 1024);              // 4 KB      @ 8K
    int*   pprefix = (int*)(w + (size_t)16 * 1024);             // 4 KB      @ 16K
    int*   deg     = (int*)(w + (size_t)32 * 1024);             // 400 KB    @ 32K
    int*   fill    = (int*)(w + (size_t)512 * 1024);            // 400 KB    @ 512K
    int*   rowptr  = (int*)(w + (size_t)1024 * 1024);           // 400 KB+4  @ 1M
    int*   col     = (int*)(w + (size_t)2 * 1024 * 1024);       // 6.4 MB    @ 2M
    float* agg     = (float*)(w + (size_t)10 * 1024 * 1024);    // 25.6 MB   @ 10M
    float* h1      = (float*)(w + (size_t)36 * 1024 * 1024);    // 25.6 MB   @ 36M

    detect_mode_kernel<<<1, 256, 0, stream>>>((const int*)ei, flag);

    // ---- CSR build (per call; no cached state allowed) ----
    hipMemsetAsync(deg, 0, (size_t)NN * sizeof(int), stream);
    hipMemsetAsync(fill, 0, (size_t)NN * sizeof(int), stream);
    hist_kernel<<<(NE + 255) / 256, 256, 0, stream>>>(ei, flag, deg);
    partial_sum_kernel<<<SCAN_NB, SCAN_BS, 0, stream>>>(deg, partial);
    scan_partials_kernel<<<1, 1024, 0, stream>>>(partial, pprefix, rowptr);
    writeout_kernel<<<SCAN_NB, SCAN_BS, 0, stream>>>(deg, pprefix, rowptr);
    fill_kernel<<<(NE + 255) / 256, 256, 0, stream>>>(ei, flag, rowptr, fill, col);

    const int aggBlocks = (NN * 64 + 255) / 256;   // one wave per node

    // ---- layer 1 ----
    aggregate_kernel<<<aggBlocks, 256, 0, stream>>>(rowptr, col, x, agg);
    sage_node_kernel<<<1024, 256, 0, stream>>>(agg, x, W1l, b1, W1r, h1);

    // ---- layer 2 + output head ----
    aggregate_kernel<<<aggBlocks, 256, 0, stream>>>(rowptr, col, h1, agg);
    sage_node_out_kernel<<<1024, 256, 0, stream>>>(agg, h1, W2l, b2, W2r,
                                                   Wlin, blin, out);
}

// Round 4
// 406.525 us; speedup vs baseline: 7.4882x; 1.3573x over previous
//
#include <hip/hip_runtime.h>

#define NN 100000
#define NE 1600000
// IN_CH = HID = 64, OUT_CH = 16

#define SCAN_BS 128
#define SCAN_NB ((NN + SCAN_BS - 1) / SCAN_BS)   // 782

// ---------------------------------------------------------------------------
// Detect int64 vs int32 edge_index: for int64 (values < 2^31) every odd
// 32-bit word is 0; for int32 the odd words are src values.
__global__ void detect_mode_kernel(const int* ei32, int* flag) {
    __shared__ int any_nonzero;
    if (threadIdx.x == 0) any_nonzero = 0;
    __syncthreads();
    int idx = 1 + 2 * threadIdx.x;
    if (ei32[idx] != 0) atomicOr(&any_nonzero, 1);
    __syncthreads();
    if (threadIdx.x == 0) flag[0] = (any_nonzero == 0) ? 1 : 0;  // 1 => int64
}

__device__ __forceinline__ void load_edge(const void* ei, int is64, int e,
                                          int& s, int& d) {
    if (is64) {
        const long long* p = (const long long*)ei;
        s = (int)p[e];
        d = (int)p[NE + e];
    } else {
        const int* p = (const int*)ei;
        s = p[e];
        d = p[NE + e];
    }
}

// ---------------------------------------------------------------------------
__global__ void hist_kernel(const void* ei, const int* flag, int* deg) {
    const int is64 = *flag;
    int e = blockIdx.x * blockDim.x + threadIdx.x;
    if (e < NE) {
        int s, d;
        load_edge(ei, is64, e, s, d);
        atomicAdd(&deg[d], 1);
    }
}

// Hierarchical exclusive scan: phase A partial sums.
__global__ void partial_sum_kernel(const int* __restrict__ deg,
                                   int* __restrict__ partial) {
    __shared__ int sm[SCAN_BS];
    const int t = threadIdx.x;
    const int idx = blockIdx.x * SCAN_BS + t;
    sm[t] = (idx < NN) ? deg[idx] : 0;
    __syncthreads();
    for (int off = SCAN_BS / 2; off > 0; off >>= 1) {
        if (t < off) sm[t] += sm[t + off];
        __syncthreads();
    }
    if (t == 0) partial[blockIdx.x] = sm[0];
}

// Phase B: single block scans the 782 partials.
__global__ void scan_partials_kernel(const int* __restrict__ partial,
                                     int* __restrict__ pprefix,
                                     int* __restrict__ rowptr) {
    __shared__ int sm[1024];
    const int t = threadIdx.x;
    int v = (t < SCAN_NB) ? partial[t] : 0;
    sm[t] = v;
    __syncthreads();
    for (int off = 1; off < 1024; off <<= 1) {
        int u = (t >= off) ? sm[t - off] : 0;
        __syncthreads();
        sm[t] += u;
        __syncthreads();
    }
    if (t < SCAN_NB) pprefix[t] = sm[t] - v;
    if (t == 0) rowptr[NN] = NE;
}

// Phase C: in-block scan + chunk offset -> rowptr.
__global__ void writeout_kernel(const int* __restrict__ deg,
                                const int* __restrict__ pprefix,
                                int* __restrict__ rowptr) {
    __shared__ int sm[SCAN_BS];
    const int t = threadIdx.x;
    const int idx = blockIdx.x * SCAN_BS + t;
    int v = (idx < NN) ? deg[idx] : 0;
    sm[t] = v;
    __syncthreads();
    for (int off = 1; off < SCAN_BS; off <<= 1) {
        int u = (t >= off) ? sm[t - off] : 0;
        __syncthreads();
        sm[t] += u;
        __syncthreads();
    }
    if (idx < NN) rowptr[idx] = pprefix[blockIdx.x] + sm[t] - v;
}

// ---------------------------------------------------------------------------
__global__ void fill_kernel(const void* ei, const int* flag,
                            const int* __restrict__ rowptr,
                            int* __restrict__ fill, int* __restrict__ col) {
    const int is64 = *flag;
    int e = blockIdx.x * blockDim.x + threadIdx.x;
    if (e < NE) {
        int s, d;
        load_edge(ei, is64, e, s, d);
        int pos = rowptr[d] + atomicAdd(&fill[d], 1);
        col[pos] = s;
    }
}

// ---------------------------------------------------------------------------
// Dense GEMM: [outt | outr] = feat @ [Wl | Wr].T, bias folded into outr half.
// feat [NN][64], Wl/Wr [64][64] row-major W[c][k].
// Block = 256 threads, tile = 64 nodes x 128 channels, thread = 8n x 4c.
// LDS: As[k][n] stride 68 (2-way conflicts = free on compute reads),
//      Bs[k][c] stride 132 (conflict-free b128 compute reads).
// In-place safe: feat rows of this tile are staged to LDS before any store,
// and no other block touches them (outr may alias feat).
__global__ __launch_bounds__(256) void gemm_tr_kernel(
    const float* __restrict__ feat,
    const float* __restrict__ Wl, const float* __restrict__ Wr,
    const float* __restrict__ bias,
    float* __restrict__ outt, float* __restrict__ outr)
{
    __shared__ float As[64][68];
    __shared__ float Bs[64][132];
    const int t = threadIdx.x;

    // ---- load B (weights, transposed to k-major) ----
    {
        int c = t & 127;
        int half = t >> 7;
        const float* Wsrc = (c < 64) ? (Wl + (size_t)c * 64) : (Wr + (size_t)(c - 64) * 64);
        for (int i = 0; i < 8; ++i) {
            int j = half + 2 * i;   // chunk 0..15
            float4 v = *(const float4*)(Wsrc + 4 * j);
            Bs[4 * j + 0][c] = v.x; Bs[4 * j + 1][c] = v.y;
            Bs[4 * j + 2][c] = v.z; Bs[4 * j + 3][c] = v.w;
        }
    }

    // ---- load A tile (64 nodes x 64 k, transposed to k-major) ----
    const int m0 = blockIdx.x * 64;
    {
        int k0 = 4 * (t & 15);
        int nb = t >> 4;          // 0..15
        for (int rep = 0; rep < 4; ++rep) {
            int n = nb + 16 * rep;
            int gn = m0 + n;
            float4 v = (gn < NN) ? *(const float4*)(feat + (size_t)gn * 64 + k0)
                                 : make_float4(0.f, 0.f, 0.f, 0.f);
            As[k0 + 0][n] = v.x; As[k0 + 1][n] = v.y;
            As[k0 + 2][n] = v.z; As[k0 + 3][n] = v.w;
        }
    }
    __syncthreads();

    const int tn = t & 7;     // node-group of 8
    const int tc = t >> 3;    // channel-group of 4, 0..31
    const int c0 = 4 * tc;

    float acc[8][4];
    {
        float b0 = 0.f, b1 = 0.f, b2 = 0.f, b3 = 0.f;
        if (c0 >= 64) {
            b0 = bias[c0 - 64]; b1 = bias[c0 - 63];
            b2 = bias[c0 - 62]; b3 = bias[c0 - 61];
        }
        #pragma unroll
        for (int i = 0; i < 8; ++i) {
            acc[i][0] = b0; acc[i][1] = b1; acc[i][2] = b2; acc[i][3] = b3;
        }
    }

    #pragma unroll 16
    for (int k = 0; k < 64; ++k) {
        float4 a0 = *(const float4*)&As[k][8 * tn];
        float4 a1 = *(const float4*)&As[k][8 * tn + 4];
        float4 b  = *(const float4*)&Bs[k][c0];
        float av[8] = {a0.x, a0.y, a0.z, a0.w, a1.x, a1.y, a1.z, a1.w};
        float bv[4] = {b.x, b.y, b.z, b.w};
        #pragma unroll
        for (int i = 0; i < 8; ++i)
            #pragma unroll
            for (int j = 0; j < 4; ++j)
                acc[i][j] = fmaf(av[i], bv[j], acc[i][j]);
    }

    float* dst = (c0 < 64) ? outt : outr;
    const int cc = (c0 < 64) ? c0 : c0 - 64;
    #pragma unroll
    for (int i = 0; i < 8; ++i) {
        int gn = m0 + 8 * tn + i;
        if (gn < NN)
            *(float4*)(dst + (size_t)gn * 64 + cc) =
                make_float4(acc[i][0], acc[i][1], acc[i][2], acc[i][3]);
    }
}

// ---------------------------------------------------------------------------
// Gather-mean + epilogue: rh[n][c] <- relu( mean_j t[col[j]][c] + rh[n][c] ).
// One wave per node, lane = channel. In-place on rh (read-then-write same
// location by the same thread; no cross-thread hazard).
__global__ void aggregate_relu_kernel(const int* __restrict__ rowptr,
                                      const int* __restrict__ col,
                                      const float* __restrict__ tfeat,
                                      float* rh) {
    const int wid  = (blockIdx.x * blockDim.x + threadIdx.x) >> 6;
    const int lane = threadIdx.x & 63;
    if (wid >= NN) return;
    const int beg = rowptr[wid], end = rowptr[wid + 1];
    float a0 = 0.f, a1 = 0.f, a2 = 0.f, a3 = 0.f;
    int j = beg;
    for (; j + 4 <= end; j += 4) {
        int s0 = col[j], s1 = col[j + 1], s2 = col[j + 2], s3 = col[j + 3];
        a0 += tfeat[(size_t)s0 * 64 + lane];
        a1 += tfeat[(size_t)s1 * 64 + lane];
        a2 += tfeat[(size_t)s2 * 64 + lane];
        a3 += tfeat[(size_t)s3 * 64 + lane];
    }
    for (; j < end; ++j) a0 += tfeat[(size_t)col[j] * 64 + lane];
    float sum = (a0 + a1) + (a2 + a3);
    float inv = 1.0f / fmaxf((float)(end - beg), 1.0f);
    float h = sum * inv + rh[(size_t)wid * 64 + lane];
    rh[(size_t)wid * 64 + lane] = fmaxf(h, 0.0f);
}

// ---------------------------------------------------------------------------
// Head GEMM: out = h @ Wlin.T + blin.  [NN][64] @ [64][16].
// Block = 256, tile = 128 nodes x 16 ch, thread = 4n x 2c.
__global__ __launch_bounds__(256) void head_kernel(
    const float* __restrict__ h,
    const float* __restrict__ Wlin,
    const float* __restrict__ blin,
    float* __restrict__ out)
{
    __shared__ float As[64][132];
    __shared__ float Bs[64][18];
    const int t = threadIdx.x;

    {   // load B: 16 rows x 64
        int c = t & 15, j = t >> 4;    // chunk 0..15
        float4 v = *(const float4*)(Wlin + (size_t)c * 64 + 4 * j);
        Bs[4 * j + 0][c] = v.x; Bs[4 * j + 1][c] = v.y;
        Bs[4 * j + 2][c] = v.z; Bs[4 * j + 3][c] = v.w;
    }
    const int m0 = blockIdx.x * 128;
    {   // load A: 128 nodes x 64
        int k0 = 4 * (t & 15);
        int nb = t >> 4;
        for (int rep = 0; rep < 8; ++rep) {
            int n = nb + 16 * rep;
            int gn = m0 + n;
            float4 v = (gn < NN) ? *(const float4*)(h + (size_t)gn * 64 + k0)
                                 : make_float4(0.f, 0.f, 0.f, 0.f);
            As[k0 + 0][n] = v.x; As[k0 + 1][n] = v.y;
            As[k0 + 2][n] = v.z; As[k0 + 3][n] = v.w;
        }
    }
    __syncthreads();

    const int tn = t & 31;    // node-group of 4
    const int tc = t >> 5;    // 0..7 -> c0 = 2*tc
    const int c0 = 2 * tc;
    float acc[4][2];
    #pragma unroll
    for (int i = 0; i < 4; ++i) { acc[i][0] = blin[c0]; acc[i][1] = blin[c0 + 1]; }

    #pragma unroll 16
    for (int k = 0; k < 64; ++k) {
        float4 a = *(const float4*)&As[k][4 * tn];
        float b0 = Bs[k][c0], b1 = Bs[k][c0 + 1];
        float av[4] = {a.x, a.y, a.z, a.w};
        #pragma unroll
        for (int i = 0; i < 4; ++i) {
            acc[i][0] = fmaf(av[i], b0, acc[i][0]);
            acc[i][1] = fmaf(av[i], b1, acc[i][1]);
        }
    }
    #pragma unroll
    for (int i = 0; i < 4; ++i) {
        int gn = m0 + 4 * tn + i;
        if (gn < NN)
            *(float2*)(out + (size_t)gn * 16 + c0) = make_float2(acc[i][0], acc[i][1]);
    }
}

// ---------------------------------------------------------------------------
extern "C" void kernel_launch(void* const* d_in, const int* in_sizes, int n_in,
                              void* d_out, int out_size, void* d_ws, size_t ws_size,
                              hipStream_t stream) {
    const float* x    = (const float*)d_in[0];
    const void*  ei   = d_in[1];
    const float* W1l  = (const float*)d_in[2];
    const float* b1   = (const float*)d_in[3];
    const float* W1r  = (const float*)d_in[4];
    const float* W2l  = (const float*)d_in[5];
    const float* b2   = (const float*)d_in[6];
    const float* W2r  = (const float*)d_in[7];
    const float* Wlin = (const float*)d_in[8];
    const float* blin = (const float*)d_in[9];
    float* out = (float*)d_out;

    char* w = (char*)d_ws;
    int*   flag    = (int*)w;                                   // @ 0
    int*   partial = (int*)(w + (size_t)8 * 1024);              // @ 8K
    int*   pprefix = (int*)(w + (size_t)16 * 1024);             // @ 16K
    int*   deg     = (int*)(w + (size_t)32 * 1024);             // @ 32K
    int*   fill    = (int*)(w + (size_t)512 * 1024);            // @ 512K
    int*   rowptr  = (int*)(w + (size_t)1024 * 1024);           // @ 1M
    int*   col     = (int*)(w + (size_t)2 * 1024 * 1024);       // @ 2M  (6.4MB)
    float* A       = (float*)(w + (size_t)10 * 1024 * 1024);    // @ 10M (25.6MB) t1/t2
    float* B       = (float*)(w + (size_t)36 * 1024 * 1024);    // @ 36M (25.6MB) r/h

    detect_mode_kernel<<<1, 256, 0, stream>>>((const int*)ei, flag);

    // ---- CSR build ----
    hipMemsetAsync(deg, 0, (size_t)NN * sizeof(int), stream);
    hipMemsetAsync(fill, 0, (size_t)NN * sizeof(int), stream);
    hist_kernel<<<(NE + 255) / 256, 256, 0, stream>>>(ei, flag, deg);
    partial_sum_kernel<<<SCAN_NB, SCAN_BS, 0, stream>>>(deg, partial);
    scan_partials_kernel<<<1, 1024, 0, stream>>>(partial, pprefix, rowptr);
    writeout_kernel<<<SCAN_NB, SCAN_BS, 0, stream>>>(deg, pprefix, rowptr);
    fill_kernel<<<(NE + 255) / 256, 256, 0, stream>>>(ei, flag, rowptr, fill, col);

    const int gemmBlocks = (NN + 63) / 64;     // 1563
    const int aggBlocks  = (NN * 64 + 255) / 256;
    const int headBlocks = (NN + 127) / 128;   // 782

    // ---- layer 1: transform-then-aggregate ----
    gemm_tr_kernel<<<gemmBlocks, 256, 0, stream>>>(x, W1l, W1r, b1, A, B);
    aggregate_relu_kernel<<<aggBlocks, 256, 0, stream>>>(rowptr, col, A, B); // h1 = B

    // ---- layer 2 ----
    gemm_tr_kernel<<<gemmBlocks, 256, 0, stream>>>(B, W2l, W2r, b2, A, B);   // r2 over h1
    aggregate_relu_kernel<<<aggBlocks, 256, 0, stream>>>(rowptr, col, A, B); // h2 = B

    // ---- output head ----
    head_kernel<<<headBlocks, 256, 0, stream>>>(B, Wlin, blin, out);
}

// Round 5
// 275.105 us; speedup vs baseline: 11.0653x; 1.4777x over previous
//
#include <hip/hip_runtime.h>

#define NN 100000
#define NE 1600000
// IN_CH = HID = 64, OUT_CH = 16

// ---- bucketed CSR build geometry ----
#define BSHIFT 9
#define BWIDTH (1 << BSHIFT)                     // 512 nodes per bucket
#define NBUCK ((NN + BWIDTH - 1) >> BSHIFT)      // 196
#define SLOTS 12288                              // capacity per bucket (mean 8163)
#define CHUNK 4096                               // edges per B1 block
#define B1_BLOCKS ((NE + CHUNK - 1) / CHUNK)     // 391

// ---------------------------------------------------------------------------
// Detect int64 vs int32 edge_index: for int64 (values < 2^31) every odd
// 32-bit word is 0; for int32 the odd words are src values.
__global__ void detect_mode_kernel(const int* ei32, int* flag) {
    __shared__ int any_nonzero;
    if (threadIdx.x == 0) any_nonzero = 0;
    __syncthreads();
    int idx = 1 + 2 * threadIdx.x;
    if (ei32[idx] != 0) atomicOr(&any_nonzero, 1);
    __syncthreads();
    if (threadIdx.x == 0) flag[0] = (any_nonzero == 0) ? 1 : 0;  // 1 => int64
}

__device__ __forceinline__ void load_edge(const void* ei, int is64, int e,
                                          int& s, int& d) {
    if (is64) {
        const long long* p = (const long long*)ei;
        s = (int)p[e];
        d = (int)p[NE + e];
    } else {
        const int* p = (const int*)ei;
        s = p[e];
        d = p[NE + e];
    }
}

// ---------------------------------------------------------------------------
// B1: bucket the edges. Each block takes CHUNK edges, LDS-histograms them by
// bucket, reserves global bucket ranges (196 atomics/block), reorders into
// LDS, then flushes coalesced runs of int2{src,dst} to bucket regions.
__global__ __launch_bounds__(256) void bucket_scatter_kernel(
    const void* ei, const int* flag,
    int* __restrict__ bcnt, int2* __restrict__ bpairs)
{
    __shared__ int hist[NBUCK];
    __shared__ int scanb[NBUCK];   // exclusive start of bucket in stage
    __shared__ int gbase[NBUCK];   // reserved global offset within bucket
    __shared__ int lofs[NBUCK];
    __shared__ int sc[256];
    __shared__ int2 stage[CHUNK];            // 32 KB
    __shared__ unsigned short sbuck[CHUNK];  // 8 KB

    const int t = threadIdx.x;
    const int is64 = *flag;
    const int e0 = blockIdx.x * CHUNK;
    const int nE = min(CHUNK, NE - e0);

    for (int i = t; i < NBUCK; i += 256) { hist[i] = 0; lofs[i] = 0; }
    __syncthreads();

    // load up to 16 edges per thread into registers
    int sr[16], dr[16];
    #pragma unroll
    for (int r = 0; r < 16; ++r) {
        int e = e0 + t + 256 * r;
        if (e < NE) load_edge(ei, is64, e, sr[r], dr[r]);
        else dr[r] = -1;
    }
    #pragma unroll
    for (int r = 0; r < 16; ++r)
        if (dr[r] >= 0) atomicAdd(&hist[dr[r] >> BSHIFT], 1);
    __syncthreads();

    // exclusive scan of hist over 256 lanes (NBUCK <= 256)
    int v = (t < NBUCK) ? hist[t] : 0;
    sc[t] = v;
    __syncthreads();
    for (int off = 1; off < 256; off <<= 1) {
        int u = (t >= off) ? sc[t - off] : 0;
        __syncthreads();
        sc[t] += u;
        __syncthreads();
    }
    if (t < NBUCK) {
        scanb[t] = sc[t] - v;
        gbase[t] = atomicAdd(&bcnt[t], v);   // reserve global range
    }
    __syncthreads();

    // reorder into LDS, bucket-major
    #pragma unroll
    for (int r = 0; r < 16; ++r) {
        if (dr[r] >= 0) {
            int b = dr[r] >> BSHIFT;
            int p = scanb[b] + atomicAdd(&lofs[b], 1);
            stage[p] = make_int2(sr[r], dr[r]);
            sbuck[p] = (unsigned short)b;
        }
    }
    __syncthreads();

    // coalesced flush: consecutive slots in one bucket -> consecutive global
    for (int i = t; i < nE; i += 256) {
        int b = sbuck[i];
        int off = gbase[b] + (i - scanb[b]);
        if (off < SLOTS) bpairs[(size_t)b * SLOTS + off] = stage[i];
    }
}

// ---------------------------------------------------------------------------
// B2: exclusive scan of bucket counts -> bucket bases; rowptr[NN] = NE.
__global__ void bucket_prefix_kernel(const int* __restrict__ bcnt,
                                     int* __restrict__ bbase,
                                     int* __restrict__ rowptr) {
    __shared__ int sc[256];
    const int t = threadIdx.x;
    int v = (t < NBUCK) ? bcnt[t] : 0;
    sc[t] = v;
    __syncthreads();
    for (int off = 1; off < 256; off <<= 1) {
        int u = (t >= off) ? sc[t - off] : 0;
        __syncthreads();
        sc[t] += u;
        __syncthreads();
    }
    if (t < NBUCK) bbase[t] = sc[t] - v;
    if (t == 0) rowptr[NN] = NE;
}

// ---------------------------------------------------------------------------
// B3: one block per bucket. LDS degree histogram over the bucket's 512-node
// range, LDS scan -> rowptr (coalesced write), then place col entries with
// LDS counters. Col writes confined to a ~48 KB window -> L2-absorbed.
__global__ __launch_bounds__(256) void bucket_to_csr_kernel(
    const int* __restrict__ bcnt, const int* __restrict__ bbase,
    const int2* __restrict__ bpairs,
    int* __restrict__ rowptr, int* __restrict__ col)
{
    __shared__ int ldeg[BWIDTH];
    __shared__ int lptr[BWIDTH];
    __shared__ int lcnt[BWIDTH];
    __shared__ int sc[256];

    const int t = threadIdx.x;
    const int b = blockIdx.x;
    const int n0 = b << BSHIFT;
    const int cnt = min(bcnt[b], SLOTS);
    const int base = bbase[b];
    const int2* src = bpairs + (size_t)b * SLOTS;

    for (int i = t; i < BWIDTH; i += 256) { ldeg[i] = 0; lcnt[i] = 0; }
    __syncthreads();

    for (int i = t; i < cnt; i += 256)
        atomicAdd(&ldeg[src[i].y - n0], 1);
    __syncthreads();

    // exclusive scan over 512 = 2 per thread
    int a0 = ldeg[2 * t], a1 = ldeg[2 * t + 1];
    int s = a0 + a1;
    sc[t] = s;
    __syncthreads();
    for (int off = 1; off < 256; off <<= 1) {
        int u = (t >= off) ? sc[t - off] : 0;
        __syncthreads();
        sc[t] += u;
        __syncthreads();
    }
    int exc = sc[t] - s;
    lptr[2 * t] = exc;
    lptr[2 * t + 1] = exc + a0;
    __syncthreads();

    for (int i = t; i < BWIDTH; i += 256) {
        int gn = n0 + i;
        if (gn < NN) rowptr[gn] = base + lptr[i];
    }

    for (int i = t; i < cnt; i += 256) {
        int2 p = src[i];
        int li = p.y - n0;
        int pos = lptr[li] + atomicAdd(&lcnt[li], 1);
        col[base + pos] = p.x;
    }
}

// ---------------------------------------------------------------------------
// Dense GEMM: [outt | outr] = feat @ [Wl | Wr].T, bias folded into outr half.
__global__ __launch_bounds__(256) void gemm_tr_kernel(
    const float* __restrict__ feat,
    const float* __restrict__ Wl, const float* __restrict__ Wr,
    const float* __restrict__ bias,
    float* __restrict__ outt, float* __restrict__ outr)
{
    __shared__ float As[64][68];
    __shared__ float Bs[64][132];
    const int t = threadIdx.x;

    {
        int c = t & 127;
        int half = t >> 7;
        const float* Wsrc = (c < 64) ? (Wl + (size_t)c * 64) : (Wr + (size_t)(c - 64) * 64);
        for (int i = 0; i < 8; ++i) {
            int j = half + 2 * i;
            float4 v = *(const float4*)(Wsrc + 4 * j);
            Bs[4 * j + 0][c] = v.x; Bs[4 * j + 1][c] = v.y;
            Bs[4 * j + 2][c] = v.z; Bs[4 * j + 3][c] = v.w;
        }
    }
    const int m0 = blockIdx.x * 64;
    {
        int k0 = 4 * (t & 15);
        int nb = t >> 4;
        for (int rep = 0; rep < 4; ++rep) {
            int n = nb + 16 * rep;
            int gn = m0 + n;
            float4 v = (gn < NN) ? *(const float4*)(feat + (size_t)gn * 64 + k0)
                                 : make_float4(0.f, 0.f, 0.f, 0.f);
            As[k0 + 0][n] = v.x; As[k0 + 1][n] = v.y;
            As[k0 + 2][n] = v.z; As[k0 + 3][n] = v.w;
        }
    }
    __syncthreads();

    const int tn = t & 7;
    const int tc = t >> 3;
    const int c0 = 4 * tc;

    float acc[8][4];
    {
        float b0 = 0.f, b1 = 0.f, b2 = 0.f, b3 = 0.f;
        if (c0 >= 64) {
            b0 = bias[c0 - 64]; b1 = bias[c0 - 63];
            b2 = bias[c0 - 62]; b3 = bias[c0 - 61];
        }
        #pragma unroll
        for (int i = 0; i < 8; ++i) {
            acc[i][0] = b0; acc[i][1] = b1; acc[i][2] = b2; acc[i][3] = b3;
        }
    }

    #pragma unroll 16
    for (int k = 0; k < 64; ++k) {
        float4 a0 = *(const float4*)&As[k][8 * tn];
        float4 a1 = *(const float4*)&As[k][8 * tn + 4];
        float4 b  = *(const float4*)&Bs[k][c0];
        float av[8] = {a0.x, a0.y, a0.z, a0.w, a1.x, a1.y, a1.z, a1.w};
        float bv[4] = {b.x, b.y, b.z, b.w};
        #pragma unroll
        for (int i = 0; i < 8; ++i)
            #pragma unroll
            for (int j = 0; j < 4; ++j)
                acc[i][j] = fmaf(av[i], bv[j], acc[i][j]);
    }

    float* dst = (c0 < 64) ? outt : outr;
    const int cc = (c0 < 64) ? c0 : c0 - 64;
    #pragma unroll
    for (int i = 0; i < 8; ++i) {
        int gn = m0 + 8 * tn + i;
        if (gn < NN)
            *(float4*)(dst + (size_t)gn * 64 + cc) =
                make_float4(acc[i][0], acc[i][1], acc[i][2], acc[i][3]);
    }
}

// ---------------------------------------------------------------------------
// Gather-mean + epilogue: rh[n][c] <- relu( mean_j t[col[j]][c] + rh[n][c] ).
__global__ void aggregate_relu_kernel(const int* __restrict__ rowptr,
                                      const int* __restrict__ col,
                                      const float* __restrict__ tfeat,
                                      float* rh) {
    const int wid  = (blockIdx.x * blockDim.x + threadIdx.x) >> 6;
    const int lane = threadIdx.x & 63;
    if (wid >= NN) return;
    const int beg = rowptr[wid], end = rowptr[wid + 1];
    float a0 = 0.f, a1 = 0.f, a2 = 0.f, a3 = 0.f;
    int j = beg;
    for (; j + 4 <= end; j += 4) {
        int s0 = col[j], s1 = col[j + 1], s2 = col[j + 2], s3 = col[j + 3];
        a0 += tfeat[(size_t)s0 * 64 + lane];
        a1 += tfeat[(size_t)s1 * 64 + lane];
        a2 += tfeat[(size_t)s2 * 64 + lane];
        a3 += tfeat[(size_t)s3 * 64 + lane];
    }
    for (; j < end; ++j) a0 += tfeat[(size_t)col[j] * 64 + lane];
    float sum = (a0 + a1) + (a2 + a3);
    float inv = 1.0f / fmaxf((float)(end - beg), 1.0f);
    float h = sum * inv + rh[(size_t)wid * 64 + lane];
    rh[(size_t)wid * 64 + lane] = fmaxf(h, 0.0f);
}

// ---------------------------------------------------------------------------
// Head GEMM: out = h @ Wlin.T + blin.
__global__ __launch_bounds__(256) void head_kernel(
    const float* __restrict__ h,
    const float* __restrict__ Wlin,
    const float* __restrict__ blin,
    float* __restrict__ out)
{
    __shared__ float As[64][132];
    __shared__ float Bs[64][18];
    const int t = threadIdx.x;

    {
        int c = t & 15, j = t >> 4;
        float4 v = *(const float4*)(Wlin + (size_t)c * 64 + 4 * j);
        Bs[4 * j + 0][c] = v.x; Bs[4 * j + 1][c] = v.y;
        Bs[4 * j + 2][c] = v.z; Bs[4 * j + 3][c] = v.w;
    }
    const int m0 = blockIdx.x * 128;
    {
        int k0 = 4 * (t & 15);
        int nb = t >> 4;
        for (int rep = 0; rep < 8; ++rep) {
            int n = nb + 16 * rep;
            int gn = m0 + n;
            float4 v = (gn < NN) ? *(const float4*)(h + (size_t)gn * 64 + k0)
                                 : make_float4(0.f, 0.f, 0.f, 0.f);
            As[k0 + 0][n] = v.x; As[k0 + 1][n] = v.y;
            As[k0 + 2][n] = v.z; As[k0 + 3][n] = v.w;
        }
    }
    __syncthreads();

    const int tn = t & 31;
    const int tc = t >> 5;
    const int c0 = 2 * tc;
    float acc[4][2];
    #pragma unroll
    for (int i = 0; i < 4; ++i) { acc[i][0] = blin[c0]; acc[i][1] = blin[c0 + 1]; }

    #pragma unroll 16
    for (int k = 0; k < 64; ++k) {
        float4 a = *(const float4*)&As[k][4 * tn];
        float b0 = Bs[k][c0], b1 = Bs[k][c0 + 1];
        float av[4] = {a.x, a.y, a.z, a.w};
        #pragma unroll
        for (int i = 0; i < 4; ++i) {
            acc[i][0] = fmaf(av[i], b0, acc[i][0]);
            acc[i][1] = fmaf(av[i], b1, acc[i][1]);
        }
    }
    #pragma unroll
    for (int i = 0; i < 4; ++i) {
        int gn = m0 + 4 * tn + i;
        if (gn < NN)
            *(float2*)(out + (size_t)gn * 16 + c0) = make_float2(acc[i][0], acc[i][1]);
    }
}

// ---------------------------------------------------------------------------
extern "C" void kernel_launch(void* const* d_in, const int* in_sizes, int n_in,
                              void* d_out, int out_size, void* d_ws, size_t ws_size,
                              hipStream_t stream) {
    const float* x    = (const float*)d_in[0];
    const void*  ei   = d_in[1];
    const float* W1l  = (const float*)d_in[2];
    const float* b1   = (const float*)d_in[3];
    const float* W1r  = (const float*)d_in[4];
    const float* W2l  = (const float*)d_in[5];
    const float* b2   = (const float*)d_in[6];
    const float* W2r  = (const float*)d_in[7];
    const float* Wlin = (const float*)d_in[8];
    const float* blin = (const float*)d_in[9];
    float* out = (float*)d_out;

    char* w = (char*)d_ws;
    int*   flag   = (int*)w;                                   // @ 0
    int*   bcnt   = (int*)(w + (size_t)4 * 1024);              // @ 4K   (784 B)
    int*   bbase  = (int*)(w + (size_t)8 * 1024);              // @ 8K   (788 B)
    int*   rowptr = (int*)(w + (size_t)1024 * 1024);           // @ 1M   (400 KB + 4)
    int*   col    = (int*)(w + (size_t)2 * 1024 * 1024);       // @ 2M   (6.4 MB)
    int2*  bpairs = (int2*)(w + (size_t)10 * 1024 * 1024);     // @ 10M  (19.3 MB, dead after B3)
    float* A      = (float*)(w + (size_t)10 * 1024 * 1024);    // @ 10M  (25.6 MB, aliases bpairs)
    float* B      = (float*)(w + (size_t)36 * 1024 * 1024);    // @ 36M  (25.6 MB)

    detect_mode_kernel<<<1, 256, 0, stream>>>((const int*)ei, flag);

    // ---- bucketed CSR build ----
    hipMemsetAsync(bcnt, 0, NBUCK * sizeof(int), stream);
    bucket_scatter_kernel<<<B1_BLOCKS, 256, 0, stream>>>(ei, flag, bcnt, bpairs);
    bucket_prefix_kernel<<<1, 256, 0, stream>>>(bcnt, bbase, rowptr);
    bucket_to_csr_kernel<<<NBUCK, 256, 0, stream>>>(bcnt, bbase, bpairs, rowptr, col);

    const int gemmBlocks = (NN + 63) / 64;
    const int aggBlocks  = (NN * 64 + 255) / 256;
    const int headBlocks = (NN + 127) / 128;

    // ---- layer 1: transform-then-aggregate (bpairs dead; A may overwrite) ----
    gemm_tr_kernel<<<gemmBlocks, 256, 0, stream>>>(x, W1l, W1r, b1, A, B);
    aggregate_relu_kernel<<<aggBlocks, 256, 0, stream>>>(rowptr, col, A, B); // h1 = B

    // ---- layer 2 ----
    gemm_tr_kernel<<<gemmBlocks, 256, 0, stream>>>(B, W2l, W2r, b2, A, B);
    aggregate_relu_kernel<<<aggBlocks, 256, 0, stream>>>(rowptr, col, A, B); // h2 = B

    // ---- output head ----
    head_kernel<<<headBlocks, 256, 0, stream>>>(B, Wlin, blin, out);
}

// Round 6
// 255.897 us; speedup vs baseline: 11.8959x; 1.0751x over previous
//
#include <hip/hip_runtime.h>

#define NN 100000
#define NE 1600000
// IN_CH = HID = 64, OUT_CH = 16

// ---- bucketed CSR build geometry ----
#define BSHIFT 9
#define BWIDTH (1 << BSHIFT)                     // 512 nodes per bucket
#define NBUCK ((NN + BWIDTH - 1) >> BSHIFT)      // 196
#define SLOTS 12288                              // capacity per bucket (mean 8163)
#define CHUNK 4096                               // edges per B1 block
#define B1_BLOCKS ((NE + CHUNK - 1) / CHUNK)     // 391

// ---- bf16 helpers (RNE pack, exact unpack) ----
__device__ __forceinline__ float u2f(unsigned u) {
    union { unsigned u; float f; } v; v.u = u; return v.f;
}
__device__ __forceinline__ unsigned f2u(float f) {
    union { float f; unsigned u; } v; v.f = f; return v.u;
}
__device__ __forceinline__ unsigned f2bf(float f) {   // returns bf16 in low 16
    unsigned u = f2u(f);
    return (u + 0x7FFFu + ((u >> 16) & 1u)) >> 16;
}

// ---------------------------------------------------------------------------
// Detect int64 vs int32 edge_index: for int64 (values < 2^31) every odd
// 32-bit word is 0; for int32 the odd words are src values.
__global__ void detect_mode_kernel(const int* ei32, int* flag) {
    __shared__ int any_nonzero;
    if (threadIdx.x == 0) any_nonzero = 0;
    __syncthreads();
    int idx = 1 + 2 * threadIdx.x;
    if (ei32[idx] != 0) atomicOr(&any_nonzero, 1);
    __syncthreads();
    if (threadIdx.x == 0) flag[0] = (any_nonzero == 0) ? 1 : 0;  // 1 => int64
}

__device__ __forceinline__ void load_edge(const void* ei, int is64, int e,
                                          int& s, int& d) {
    if (is64) {
        const long long* p = (const long long*)ei;
        s = (int)p[e];
        d = (int)p[NE + e];
    } else {
        const int* p = (const int*)ei;
        s = p[e];
        d = p[NE + e];
    }
}

// ---------------------------------------------------------------------------
// B1: bucket the edges (LDS histogram + reorder + coalesced flush).
__global__ __launch_bounds__(256) void bucket_scatter_kernel(
    const void* ei, const int* flag,
    int* __restrict__ bcnt, int2* __restrict__ bpairs)
{
    __shared__ int hist[NBUCK];
    __shared__ int scanb[NBUCK];
    __shared__ int gbase[NBUCK];
    __shared__ int lofs[NBUCK];
    __shared__ int sc[256];
    __shared__ int2 stage[CHUNK];
    __shared__ unsigned short sbuck[CHUNK];

    const int t = threadIdx.x;
    const int is64 = *flag;
    const int e0 = blockIdx.x * CHUNK;
    const int nE = min(CHUNK, NE - e0);

    for (int i = t; i < NBUCK; i += 256) { hist[i] = 0; lofs[i] = 0; }
    __syncthreads();

    int sr[16], dr[16];
    #pragma unroll
    for (int r = 0; r < 16; ++r) {
        int e = e0 + t + 256 * r;
        if (e < NE) load_edge(ei, is64, e, sr[r], dr[r]);
        else dr[r] = -1;
    }
    #pragma unroll
    for (int r = 0; r < 16; ++r)
        if (dr[r] >= 0) atomicAdd(&hist[dr[r] >> BSHIFT], 1);
    __syncthreads();

    int v = (t < NBUCK) ? hist[t] : 0;
    sc[t] = v;
    __syncthreads();
    for (int off = 1; off < 256; off <<= 1) {
        int u = (t >= off) ? sc[t - off] : 0;
        __syncthreads();
        sc[t] += u;
        __syncthreads();
    }
    if (t < NBUCK) {
        scanb[t] = sc[t] - v;
        gbase[t] = atomicAdd(&bcnt[t], v);
    }
    __syncthreads();

    #pragma unroll
    for (int r = 0; r < 16; ++r) {
        if (dr[r] >= 0) {
            int b = dr[r] >> BSHIFT;
            int p = scanb[b] + atomicAdd(&lofs[b], 1);
            stage[p] = make_int2(sr[r], dr[r]);
            sbuck[p] = (unsigned short)b;
        }
    }
    __syncthreads();

    for (int i = t; i < nE; i += 256) {
        int b = sbuck[i];
        int off = gbase[b] + (i - scanb[b]);
        if (off < SLOTS) bpairs[(size_t)b * SLOTS + off] = stage[i];
    }
}

// ---------------------------------------------------------------------------
// B2: exclusive scan of bucket counts -> bucket bases; rowptr[NN] = NE.
__global__ void bucket_prefix_kernel(const int* __restrict__ bcnt,
                                     int* __restrict__ bbase,
                                     int* __restrict__ rowptr) {
    __shared__ int sc[256];
    const int t = threadIdx.x;
    int v = (t < NBUCK) ? bcnt[t] : 0;
    sc[t] = v;
    __syncthreads();
    for (int off = 1; off < 256; off <<= 1) {
        int u = (t >= off) ? sc[t - off] : 0;
        __syncthreads();
        sc[t] += u;
        __syncthreads();
    }
    if (t < NBUCK) bbase[t] = sc[t] - v;
    if (t == 0) rowptr[NN] = NE;
}

// ---------------------------------------------------------------------------
// B3: one block per bucket -> rowptr + col.
__global__ __launch_bounds__(256) void bucket_to_csr_kernel(
    const int* __restrict__ bcnt, const int* __restrict__ bbase,
    const int2* __restrict__ bpairs,
    int* __restrict__ rowptr, int* __restrict__ col)
{
    __shared__ int ldeg[BWIDTH];
    __shared__ int lptr[BWIDTH];
    __shared__ int lcnt[BWIDTH];
    __shared__ int sc[256];

    const int t = threadIdx.x;
    const int b = blockIdx.x;
    const int n0 = b << BSHIFT;
    const int cnt = min(bcnt[b], SLOTS);
    const int base = bbase[b];
    const int2* src = bpairs + (size_t)b * SLOTS;

    for (int i = t; i < BWIDTH; i += 256) { ldeg[i] = 0; lcnt[i] = 0; }
    __syncthreads();

    for (int i = t; i < cnt; i += 256)
        atomicAdd(&ldeg[src[i].y - n0], 1);
    __syncthreads();

    int a0 = ldeg[2 * t], a1 = ldeg[2 * t + 1];
    int s = a0 + a1;
    sc[t] = s;
    __syncthreads();
    for (int off = 1; off < 256; off <<= 1) {
        int u = (t >= off) ? sc[t - off] : 0;
        __syncthreads();
        sc[t] += u;
        __syncthreads();
    }
    int exc = sc[t] - s;
    lptr[2 * t] = exc;
    lptr[2 * t + 1] = exc + a0;
    __syncthreads();

    for (int i = t; i < BWIDTH; i += 256) {
        int gn = n0 + i;
        if (gn < NN) rowptr[gn] = base + lptr[i];
    }

    for (int i = t; i < cnt; i += 256) {
        int2 p = src[i];
        int li = p.y - n0;
        int pos = lptr[li] + atomicAdd(&lcnt[li], 1);
        col[base + pos] = p.x;
    }
}

// ---------------------------------------------------------------------------
// Dense GEMM: t (bf16-packed) = feat @ Wl.T ; r (f32, bias folded) = feat @ Wr.T.
// tile = 64 nodes x 128 channels, thread = 8n x 4c.
__global__ __launch_bounds__(256) void gemm_tr_kernel(
    const float* __restrict__ feat,
    const float* __restrict__ Wl, const float* __restrict__ Wr,
    const float* __restrict__ bias,
    unsigned* __restrict__ outt,          // bf16x2-packed, NN x 32 uints
    float* __restrict__ outr)
{
    __shared__ float As[64][68];
    __shared__ float Bs[64][132];
    const int t = threadIdx.x;

    {
        int c = t & 127;
        int half = t >> 7;
        const float* Wsrc = (c < 64) ? (Wl + (size_t)c * 64) : (Wr + (size_t)(c - 64) * 64);
        for (int i = 0; i < 8; ++i) {
            int j = half + 2 * i;
            float4 v = *(const float4*)(Wsrc + 4 * j);
            Bs[4 * j + 0][c] = v.x; Bs[4 * j + 1][c] = v.y;
            Bs[4 * j + 2][c] = v.z; Bs[4 * j + 3][c] = v.w;
        }
    }
    const int m0 = blockIdx.x * 64;
    {
        int k0 = 4 * (t & 15);
        int nb = t >> 4;
        for (int rep = 0; rep < 4; ++rep) {
            int n = nb + 16 * rep;
            int gn = m0 + n;
            float4 v = (gn < NN) ? *(const float4*)(feat + (size_t)gn * 64 + k0)
                                 : make_float4(0.f, 0.f, 0.f, 0.f);
            As[k0 + 0][n] = v.x; As[k0 + 1][n] = v.y;
            As[k0 + 2][n] = v.z; As[k0 + 3][n] = v.w;
        }
    }
    __syncthreads();

    const int tn = t & 7;
    const int tc = t >> 3;
    const int c0 = 4 * tc;

    float acc[8][4];
    {
        float b0 = 0.f, b1 = 0.f, b2 = 0.f, b3 = 0.f;
        if (c0 >= 64) {
            b0 = bias[c0 - 64]; b1 = bias[c0 - 63];
            b2 = bias[c0 - 62]; b3 = bias[c0 - 61];
        }
        #pragma unroll
        for (int i = 0; i < 8; ++i) {
            acc[i][0] = b0; acc[i][1] = b1; acc[i][2] = b2; acc[i][3] = b3;
        }
    }

    #pragma unroll 16
    for (int k = 0; k < 64; ++k) {
        float4 a0 = *(const float4*)&As[k][8 * tn];
        float4 a1 = *(const float4*)&As[k][8 * tn + 4];
        float4 b  = *(const float4*)&Bs[k][c0];
        float av[8] = {a0.x, a0.y, a0.z, a0.w, a1.x, a1.y, a1.z, a1.w};
        float bv[4] = {b.x, b.y, b.z, b.w};
        #pragma unroll
        for (int i = 0; i < 8; ++i)
            #pragma unroll
            for (int j = 0; j < 4; ++j)
                acc[i][j] = fmaf(av[i], bv[j], acc[i][j]);
    }

    if (c0 < 64) {
        // t-half: pack 4 channels -> 2 uints (bf16 RNE)
        #pragma unroll
        for (int i = 0; i < 8; ++i) {
            int gn = m0 + 8 * tn + i;
            if (gn < NN) {
                uint2 p;
                p.x = f2bf(acc[i][0]) | (f2bf(acc[i][1]) << 16);
                p.y = f2bf(acc[i][2]) | (f2bf(acc[i][3]) << 16);
                *(uint2*)(outt + (size_t)gn * 32 + (c0 >> 1)) = p;
            }
        }
    } else {
        const int cc = c0 - 64;
        #pragma unroll
        for (int i = 0; i < 8; ++i) {
            int gn = m0 + 8 * tn + i;
            if (gn < NN)
                *(float4*)(outr + (size_t)gn * 64 + cc) =
                    make_float4(acc[i][0], acc[i][1], acc[i][2], acc[i][3]);
        }
    }
}

// ---------------------------------------------------------------------------
// Gather-mean (bf16 table) + epilogue: rh <- relu(mean + rh).
// One wave per dst node; 2 edges in flight (half-wave each, lane = ch-pair),
// unrolled x2 pairs. f32 accumulation; halves merged via shfl_xor(32).
__global__ void aggregate_relu_kernel(const int* __restrict__ rowptr,
                                      const int* __restrict__ col,
                                      const unsigned* __restrict__ tt,  // NN x 32
                                      float* rh) {
    const int wid  = (blockIdx.x * blockDim.x + threadIdx.x) >> 6;
    const int lane = threadIdx.x & 63;
    if (wid >= NN) return;
    const int half = lane >> 5;      // which edge of the pair
    const int c2   = lane & 31;      // channel-pair index
    const int beg = rowptr[wid], end = rowptr[wid + 1];

    float s0 = 0.f, s1 = 0.f, t0 = 0.f, t1 = 0.f;
    int j = beg;
    for (; j + 4 <= end; j += 4) {
        int eA = col[j + half];
        int eB = col[j + 2 + half];
        unsigned uA = tt[(size_t)eA * 32 + c2];
        unsigned uB = tt[(size_t)eB * 32 + c2];
        s0 += u2f(uA << 16); s1 += u2f(uA & 0xFFFF0000u);
        t0 += u2f(uB << 16); t1 += u2f(uB & 0xFFFF0000u);
    }
    for (; j < end; j += 2) {
        int jj = j + half;
        if (jj < end) {
            unsigned u = tt[(size_t)col[jj] * 32 + c2];
            s0 += u2f(u << 16); s1 += u2f(u & 0xFFFF0000u);
        }
    }
    s0 += t0; s1 += t1;
    s0 += __shfl_xor(s0, 32);
    s1 += __shfl_xor(s1, 32);

    if (half == 0) {
        float inv = 1.0f / fmaxf((float)(end - beg), 1.0f);
        float2 r = *(float2*)(rh + (size_t)wid * 64 + 2 * c2);
        r.x = fmaxf(s0 * inv + r.x, 0.0f);
        r.y = fmaxf(s1 * inv + r.y, 0.0f);
        *(float2*)(rh + (size_t)wid * 64 + 2 * c2) = r;
    }
}

// ---------------------------------------------------------------------------
// Head GEMM: out = h @ Wlin.T + blin.
__global__ __launch_bounds__(256) void head_kernel(
    const float* __restrict__ h,
    const float* __restrict__ Wlin,
    const float* __restrict__ blin,
    float* __restrict__ out)
{
    __shared__ float As[64][132];
    __shared__ float Bs[64][18];
    const int t = threadIdx.x;

    {
        int c = t & 15, j = t >> 4;
        float4 v = *(const float4*)(Wlin + (size_t)c * 64 + 4 * j);
        Bs[4 * j + 0][c] = v.x; Bs[4 * j + 1][c] = v.y;
        Bs[4 * j + 2][c] = v.z; Bs[4 * j + 3][c] = v.w;
    }
    const int m0 = blockIdx.x * 128;
    {
        int k0 = 4 * (t & 15);
        int nb = t >> 4;
        for (int rep = 0; rep < 8; ++rep) {
            int n = nb + 16 * rep;
            int gn = m0 + n;
            float4 v = (gn < NN) ? *(const float4*)(h + (size_t)gn * 64 + k0)
                                 : make_float4(0.f, 0.f, 0.f, 0.f);
            As[k0 + 0][n] = v.x; As[k0 + 1][n] = v.y;
            As[k0 + 2][n] = v.z; As[k0 + 3][n] = v.w;
        }
    }
    __syncthreads();

    const int tn = t & 31;
    const int tc = t >> 5;
    const int c0 = 2 * tc;
    float acc[4][2];
    #pragma unroll
    for (int i = 0; i < 4; ++i) { acc[i][0] = blin[c0]; acc[i][1] = blin[c0 + 1]; }

    #pragma unroll 16
    for (int k = 0; k < 64; ++k) {
        float4 a = *(const float4*)&As[k][4 * tn];
        float b0 = Bs[k][c0], b1 = Bs[k][c0 + 1];
        float av[4] = {a.x, a.y, a.z, a.w};
        #pragma unroll
        for (int i = 0; i < 4; ++i) {
            acc[i][0] = fmaf(av[i], b0, acc[i][0]);
            acc[i][1] = fmaf(av[i], b1, acc[i][1]);
        }
    }
    #pragma unroll
    for (int i = 0; i < 4; ++i) {
        int gn = m0 + 4 * tn + i;
        if (gn < NN)
            *(float2*)(out + (size_t)gn * 16 + c0) = make_float2(acc[i][0], acc[i][1]);
    }
}

// ---------------------------------------------------------------------------
extern "C" void kernel_launch(void* const* d_in, const int* in_sizes, int n_in,
                              void* d_out, int out_size, void* d_ws, size_t ws_size,
                              hipStream_t stream) {
    const float* x    = (const float*)d_in[0];
    const void*  ei   = d_in[1];
    const float* W1l  = (const float*)d_in[2];
    const float* b1   = (const float*)d_in[3];
    const float* W1r  = (const float*)d_in[4];
    const float* W2l  = (const float*)d_in[5];
    const float* b2   = (const float*)d_in[6];
    const float* W2r  = (const float*)d_in[7];
    const float* Wlin = (const float*)d_in[8];
    const float* blin = (const float*)d_in[9];
    float* out = (float*)d_out;

    char* w = (char*)d_ws;
    int*      flag   = (int*)w;                                // @ 0
    int*      bcnt   = (int*)(w + (size_t)4 * 1024);           // @ 4K
    int*      bbase  = (int*)(w + (size_t)8 * 1024);           // @ 8K
    int*      rowptr = (int*)(w + (size_t)1024 * 1024);        // @ 1M
    int*      col    = (int*)(w + (size_t)2 * 1024 * 1024);    // @ 2M  (6.4 MB)
    int2*     bpairs = (int2*)(w + (size_t)10 * 1024 * 1024);  // @ 10M (19.3 MB, dead after B3)
    unsigned* T      = (unsigned*)(w + (size_t)10 * 1024 * 1024); // @ 10M (12.8 MB bf16 table, aliases bpairs)
    float*    B      = (float*)(w + (size_t)36 * 1024 * 1024); // @ 36M (25.6 MB r/h)

    detect_mode_kernel<<<1, 256, 0, stream>>>((const int*)ei, flag);

    // ---- bucketed CSR build ----
    hipMemsetAsync(bcnt, 0, NBUCK * sizeof(int), stream);
    bucket_scatter_kernel<<<B1_BLOCKS, 256, 0, stream>>>(ei, flag, bcnt, bpairs);
    bucket_prefix_kernel<<<1, 256, 0, stream>>>(bcnt, bbase, rowptr);
    bucket_to_csr_kernel<<<NBUCK, 256, 0, stream>>>(bcnt, bbase, bpairs, rowptr, col);

    const int gemmBlocks = (NN + 63) / 64;
    const int aggBlocks  = (NN * 64 + 255) / 256;
    const int headBlocks = (NN + 127) / 128;

    // ---- layer 1: transform-then-aggregate (bpairs dead; T may overwrite) ----
    gemm_tr_kernel<<<gemmBlocks, 256, 0, stream>>>(x, W1l, W1r, b1, T, B);
    aggregate_relu_kernel<<<aggBlocks, 256, 0, stream>>>(rowptr, col, T, B); // h1 = B

    // ---- layer 2 ----
    gemm_tr_kernel<<<gemmBlocks, 256, 0, stream>>>(B, W2l, W2r, b2, T, B);
    aggregate_relu_kernel<<<aggBlocks, 256, 0, stream>>>(rowptr, col, T, B); // h2 = B

    // ---- output head ----
    head_kernel<<<headBlocks, 256, 0, stream>>>(B, Wlin, blin, out);
}

// Round 7
// 226.204 us; speedup vs baseline: 13.4574x; 1.1313x over previous
//
#include <hip/hip_runtime.h>

#define NN 100000
#define NE 1600000
// IN_CH = HID = 64, OUT_CH = 16

// ---- bucketed CSR build geometry ----
#define BSHIFT 9
#define BWIDTH (1 << BSHIFT)                     // 512 nodes per bucket
#define NBUCK ((NN + BWIDTH - 1) >> BSHIFT)      // 196
#define SLOTS 12288                              // capacity per bucket (mean 8163)
#define CHUNK 4096                               // edges per B1 block
#define B1_BLOCKS ((NE + CHUNK - 1) / CHUNK)     // 391

// ---- bf16 helpers (RNE pack, exact unpack) ----
__device__ __forceinline__ float u2f(unsigned u) {
    union { unsigned u; float f; } v; v.u = u; return v.f;
}
__device__ __forceinline__ unsigned f2u(float f) {
    union { float f; unsigned u; } v; v.f = f; return v.u;
}
__device__ __forceinline__ unsigned f2bf(float f) {   // returns bf16 in low 16
    unsigned u = f2u(f);
    return (u + 0x7FFFu + ((u >> 16) & 1u)) >> 16;
}

// ---------------------------------------------------------------------------
// Detect int64 vs int32 edge_index: for int64 (values < 2^31) every odd
// 32-bit word is 0; for int32 the odd words are src values.
__global__ void detect_mode_kernel(const int* ei32, int* flag) {
    __shared__ int any_nonzero;
    if (threadIdx.x == 0) any_nonzero = 0;
    __syncthreads();
    int idx = 1 + 2 * threadIdx.x;
    if (ei32[idx] != 0) atomicOr(&any_nonzero, 1);
    __syncthreads();
    if (threadIdx.x == 0) flag[0] = (any_nonzero == 0) ? 1 : 0;  // 1 => int64
}

__device__ __forceinline__ void load_edge(const void* ei, int is64, int e,
                                          int& s, int& d) {
    if (is64) {
        const long long* p = (const long long*)ei;
        s = (int)p[e];
        d = (int)p[NE + e];
    } else {
        const int* p = (const int*)ei;
        s = p[e];
        d = p[NE + e];
    }
}

// ---------------------------------------------------------------------------
// B1: bucket the edges (LDS histogram + reorder + coalesced flush).
__global__ __launch_bounds__(256) void bucket_scatter_kernel(
    const void* ei, const int* flag,
    int* __restrict__ bcnt, int2* __restrict__ bpairs)
{
    __shared__ int hist[NBUCK];
    __shared__ int scanb[NBUCK];
    __shared__ int gbase[NBUCK];
    __shared__ int lofs[NBUCK];
    __shared__ int sc[256];
    __shared__ int2 stage[CHUNK];
    __shared__ unsigned short sbuck[CHUNK];

    const int t = threadIdx.x;
    const int is64 = *flag;
    const int e0 = blockIdx.x * CHUNK;
    const int nE = min(CHUNK, NE - e0);

    for (int i = t; i < NBUCK; i += 256) { hist[i] = 0; lofs[i] = 0; }
    __syncthreads();

    int sr[16], dr[16];
    #pragma unroll
    for (int r = 0; r < 16; ++r) {
        int e = e0 + t + 256 * r;
        if (e < NE) load_edge(ei, is64, e, sr[r], dr[r]);
        else dr[r] = -1;
    }
    #pragma unroll
    for (int r = 0; r < 16; ++r)
        if (dr[r] >= 0) atomicAdd(&hist[dr[r] >> BSHIFT], 1);
    __syncthreads();

    int v = (t < NBUCK) ? hist[t] : 0;
    sc[t] = v;
    __syncthreads();
    for (int off = 1; off < 256; off <<= 1) {
        int u = (t >= off) ? sc[t - off] : 0;
        __syncthreads();
        sc[t] += u;
        __syncthreads();
    }
    if (t < NBUCK) {
        scanb[t] = sc[t] - v;
        gbase[t] = atomicAdd(&bcnt[t], v);
    }
    __syncthreads();

    #pragma unroll
    for (int r = 0; r < 16; ++r) {
        if (dr[r] >= 0) {
            int b = dr[r] >> BSHIFT;
            int p = scanb[b] + atomicAdd(&lofs[b], 1);
            stage[p] = make_int2(sr[r], dr[r]);
            sbuck[p] = (unsigned short)b;
        }
    }
    __syncthreads();

    for (int i = t; i < nE; i += 256) {
        int b = sbuck[i];
        int off = gbase[b] + (i - scanb[b]);
        if (off < SLOTS) bpairs[(size_t)b * SLOTS + off] = stage[i];
    }
}

// ---------------------------------------------------------------------------
// B2: exclusive scan of bucket counts -> bucket bases; rowptr[NN] = NE.
__global__ void bucket_prefix_kernel(const int* __restrict__ bcnt,
                                     int* __restrict__ bbase,
                                     int* __restrict__ rowptr) {
    __shared__ int sc[256];
    const int t = threadIdx.x;
    int v = (t < NBUCK) ? bcnt[t] : 0;
    sc[t] = v;
    __syncthreads();
    for (int off = 1; off < 256; off <<= 1) {
        int u = (t >= off) ? sc[t - off] : 0;
        __syncthreads();
        sc[t] += u;
        __syncthreads();
    }
    if (t < NBUCK) bbase[t] = sc[t] - v;
    if (t == 0) rowptr[NN] = NE;
}

// ---------------------------------------------------------------------------
// B3: one block per bucket -> rowptr + col.
__global__ __launch_bounds__(256) void bucket_to_csr_kernel(
    const int* __restrict__ bcnt, const int* __restrict__ bbase,
    const int2* __restrict__ bpairs,
    int* __restrict__ rowptr, int* __restrict__ col)
{
    __shared__ int ldeg[BWIDTH];
    __shared__ int lptr[BWIDTH];
    __shared__ int lcnt[BWIDTH];
    __shared__ int sc[256];

    const int t = threadIdx.x;
    const int b = blockIdx.x;
    const int n0 = b << BSHIFT;
    const int cnt = min(bcnt[b], SLOTS);
    const int base = bbase[b];
    const int2* src = bpairs + (size_t)b * SLOTS;

    for (int i = t; i < BWIDTH; i += 256) { ldeg[i] = 0; lcnt[i] = 0; }
    __syncthreads();

    for (int i = t; i < cnt; i += 256)
        atomicAdd(&ldeg[src[i].y - n0], 1);
    __syncthreads();

    int a0 = ldeg[2 * t], a1 = ldeg[2 * t + 1];
    int s = a0 + a1;
    sc[t] = s;
    __syncthreads();
    for (int off = 1; off < 256; off <<= 1) {
        int u = (t >= off) ? sc[t - off] : 0;
        __syncthreads();
        sc[t] += u;
        __syncthreads();
    }
    int exc = sc[t] - s;
    lptr[2 * t] = exc;
    lptr[2 * t + 1] = exc + a0;
    __syncthreads();

    for (int i = t; i < BWIDTH; i += 256) {
        int gn = n0 + i;
        if (gn < NN) rowptr[gn] = base + lptr[i];
    }

    for (int i = t; i < cnt; i += 256) {
        int2 p = src[i];
        int li = p.y - n0;
        int pos = lptr[li] + atomicAdd(&lcnt[li], 1);
        col[base + pos] = p.x;
    }
}

// ---------------------------------------------------------------------------
// Dense GEMM: t (bf16-packed) = feat @ Wl.T ; r (f32, bias folded) = feat @ Wr.T.
// tile = 64 nodes x 128 channels, thread = 8n x 4c.
__global__ __launch_bounds__(256) void gemm_tr_kernel(
    const float* __restrict__ feat,
    const float* __restrict__ Wl, const float* __restrict__ Wr,
    const float* __restrict__ bias,
    unsigned* __restrict__ outt,          // bf16x2-packed, NN x 32 uints
    float* __restrict__ outr)
{
    __shared__ float As[64][68];
    __shared__ float Bs[64][132];
    const int t = threadIdx.x;

    {
        int c = t & 127;
        int half = t >> 7;
        const float* Wsrc = (c < 64) ? (Wl + (size_t)c * 64) : (Wr + (size_t)(c - 64) * 64);
        for (int i = 0; i < 8; ++i) {
            int j = half + 2 * i;
            float4 v = *(const float4*)(Wsrc + 4 * j);
            Bs[4 * j + 0][c] = v.x; Bs[4 * j + 1][c] = v.y;
            Bs[4 * j + 2][c] = v.z; Bs[4 * j + 3][c] = v.w;
        }
    }
    const int m0 = blockIdx.x * 64;
    {
        int k0 = 4 * (t & 15);
        int nb = t >> 4;
        for (int rep = 0; rep < 4; ++rep) {
            int n = nb + 16 * rep;
            int gn = m0 + n;
            float4 v = (gn < NN) ? *(const float4*)(feat + (size_t)gn * 64 + k0)
                                 : make_float4(0.f, 0.f, 0.f, 0.f);
            As[k0 + 0][n] = v.x; As[k0 + 1][n] = v.y;
            As[k0 + 2][n] = v.z; As[k0 + 3][n] = v.w;
        }
    }
    __syncthreads();

    const int tn = t & 7;
    const int tc = t >> 3;
    const int c0 = 4 * tc;

    float acc[8][4];
    {
        float b0 = 0.f, b1 = 0.f, b2 = 0.f, b3 = 0.f;
        if (c0 >= 64) {
            b0 = bias[c0 - 64]; b1 = bias[c0 - 63];
            b2 = bias[c0 - 62]; b3 = bias[c0 - 61];
        }
        #pragma unroll
        for (int i = 0; i < 8; ++i) {
            acc[i][0] = b0; acc[i][1] = b1; acc[i][2] = b2; acc[i][3] = b3;
        }
    }

    #pragma unroll 16
    for (int k = 0; k < 64; ++k) {
        float4 a0 = *(const float4*)&As[k][8 * tn];
        float4 a1 = *(const float4*)&As[k][8 * tn + 4];
        float4 b  = *(const float4*)&Bs[k][c0];
        float av[8] = {a0.x, a0.y, a0.z, a0.w, a1.x, a1.y, a1.z, a1.w};
        float bv[4] = {b.x, b.y, b.z, b.w};
        #pragma unroll
        for (int i = 0; i < 8; ++i)
            #pragma unroll
            for (int j = 0; j < 4; ++j)
                acc[i][j] = fmaf(av[i], bv[j], acc[i][j]);
    }

    if (c0 < 64) {
        // t-half: pack 4 channels -> 2 uints (bf16 RNE)
        #pragma unroll
        for (int i = 0; i < 8; ++i) {
            int gn = m0 + 8 * tn + i;
            if (gn < NN) {
                uint2 p;
                p.x = f2bf(acc[i][0]) | (f2bf(acc[i][1]) << 16);
                p.y = f2bf(acc[i][2]) | (f2bf(acc[i][3]) << 16);
                *(uint2*)(outt + (size_t)gn * 32 + (c0 >> 1)) = p;
            }
        }
    } else {
        const int cc = c0 - 64;
        #pragma unroll
        for (int i = 0; i < 8; ++i) {
            int gn = m0 + 8 * tn + i;
            if (gn < NN)
                *(float4*)(outr + (size_t)gn * 64 + cc) =
                    make_float4(acc[i][0], acc[i][1], acc[i][2], acc[i][3]);
        }
    }
}

// ---------------------------------------------------------------------------
// Gather-mean (bf16 table) + epilogue: rh <- relu(mean + rh).
// One wave per dst node; 8 edges in flight. lane = (slot 0..7) x (c8 0..7);
// each lane gathers uint4 = 8 bf16 channels -> 1024 B per wave-instruction.
// Tail edges masked to zero. Cross-slot reduce via 3 shfl_xor at the end.
__global__ void aggregate_relu_kernel(const int* __restrict__ rowptr,
                                      const int* __restrict__ col,
                                      const unsigned* __restrict__ tt,  // NN x 32
                                      float* rh) {
    const int wid  = (blockIdx.x * blockDim.x + threadIdx.x) >> 6;
    const int lane = threadIdx.x & 63;
    if (wid >= NN) return;
    const int slot = lane >> 3;      // edge slot 0..7
    const int c8   = lane & 7;       // channel-octet: channels 8*c8 .. 8*c8+7
    const int beg = rowptr[wid], end = rowptr[wid + 1];

    float acc[8];
    #pragma unroll
    for (int k = 0; k < 8; ++k) acc[k] = 0.f;

    for (int j = beg; j < end; j += 8) {
        int jj = j + slot;
        bool valid = jj < end;
        int e = col[valid ? jj : end - 1];
        uint4 u = *(const uint4*)(tt + (size_t)e * 32 + 4 * c8);
        if (!valid) u = make_uint4(0u, 0u, 0u, 0u);   // bf16 zeros
        acc[0] += u2f(u.x << 16); acc[1] += u2f(u.x & 0xFFFF0000u);
        acc[2] += u2f(u.y << 16); acc[3] += u2f(u.y & 0xFFFF0000u);
        acc[4] += u2f(u.z << 16); acc[5] += u2f(u.z & 0xFFFF0000u);
        acc[6] += u2f(u.w << 16); acc[7] += u2f(u.w & 0xFFFF0000u);
    }

    #pragma unroll
    for (int k = 0; k < 8; ++k) {
        acc[k] += __shfl_xor(acc[k], 8);
        acc[k] += __shfl_xor(acc[k], 16);
        acc[k] += __shfl_xor(acc[k], 32);
    }

    if (slot == 0) {
        float inv = 1.0f / fmaxf((float)(end - beg), 1.0f);
        float* p = rh + (size_t)wid * 64 + 8 * c8;
        float4 r0 = *(float4*)p;
        float4 r1 = *(float4*)(p + 4);
        r0.x = fmaxf(acc[0] * inv + r0.x, 0.0f);
        r0.y = fmaxf(acc[1] * inv + r0.y, 0.0f);
        r0.z = fmaxf(acc[2] * inv + r0.z, 0.0f);
        r0.w = fmaxf(acc[3] * inv + r0.w, 0.0f);
        r1.x = fmaxf(acc[4] * inv + r1.x, 0.0f);
        r1.y = fmaxf(acc[5] * inv + r1.y, 0.0f);
        r1.z = fmaxf(acc[6] * inv + r1.z, 0.0f);
        r1.w = fmaxf(acc[7] * inv + r1.w, 0.0f);
        *(float4*)p = r0;
        *(float4*)(p + 4) = r1;
    }
}

// ---------------------------------------------------------------------------
// Head GEMM: out = h @ Wlin.T + blin.
__global__ __launch_bounds__(256) void head_kernel(
    const float* __restrict__ h,
    const float* __restrict__ Wlin,
    const float* __restrict__ blin,
    float* __restrict__ out)
{
    __shared__ float As[64][132];
    __shared__ float Bs[64][18];
    const int t = threadIdx.x;

    {
        int c = t & 15, j = t >> 4;
        float4 v = *(const float4*)(Wlin + (size_t)c * 64 + 4 * j);
        Bs[4 * j + 0][c] = v.x; Bs[4 * j + 1][c] = v.y;
        Bs[4 * j + 2][c] = v.z; Bs[4 * j + 3][c] = v.w;
    }
    const int m0 = blockIdx.x * 128;
    {
        int k0 = 4 * (t & 15);
        int nb = t >> 4;
        for (int rep = 0; rep < 8; ++rep) {
            int n = nb + 16 * rep;
            int gn = m0 + n;
            float4 v = (gn < NN) ? *(const float4*)(h + (size_t)gn * 64 + k0)
                                 : make_float4(0.f, 0.f, 0.f, 0.f);
            As[k0 + 0][n] = v.x; As[k0 + 1][n] = v.y;
            As[k0 + 2][n] = v.z; As[k0 + 3][n] = v.w;
        }
    }
    __syncthreads();

    const int tn = t & 31;
    const int tc = t >> 5;
    const int c0 = 2 * tc;
    float acc[4][2];
    #pragma unroll
    for (int i = 0; i < 4; ++i) { acc[i][0] = blin[c0]; acc[i][1] = blin[c0 + 1]; }

    #pragma unroll 16
    for (int k = 0; k < 64; ++k) {
        float4 a = *(const float4*)&As[k][4 * tn];
        float b0 = Bs[k][c0], b1 = Bs[k][c0 + 1];
        float av[4] = {a.x, a.y, a.z, a.w};
        #pragma unroll
        for (int i = 0; i < 4; ++i) {
            acc[i][0] = fmaf(av[i], b0, acc[i][0]);
            acc[i][1] = fmaf(av[i], b1, acc[i][1]);
        }
    }
    #pragma unroll
    for (int i = 0; i < 4; ++i) {
        int gn = m0 + 4 * tn + i;
        if (gn < NN)
            *(float2*)(out + (size_t)gn * 16 + c0) = make_float2(acc[i][0], acc[i][1]);
    }
}

// ---------------------------------------------------------------------------
extern "C" void kernel_launch(void* const* d_in, const int* in_sizes, int n_in,
                              void* d_out, int out_size, void* d_ws, size_t ws_size,
                              hipStream_t stream) {
    const float* x    = (const float*)d_in[0];
    const void*  ei   = d_in[1];
    const float* W1l  = (const float*)d_in[2];
    const float* b1   = (const float*)d_in[3];
    const float* W1r  = (const float*)d_in[4];
    const float* W2l  = (const float*)d_in[5];
    const float* b2   = (const float*)d_in[6];
    const float* W2r  = (const float*)d_in[7];
    const float* Wlin = (const float*)d_in[8];
    const float* blin = (const float*)d_in[9];
    float* out = (float*)d_out;

    char* w = (char*)d_ws;
    int*      flag   = (int*)w;                                // @ 0
    int*      bcnt   = (int*)(w + (size_t)4 * 1024);           // @ 4K
    int*      bbase  = (int*)(w + (size_t)8 * 1024);           // @ 8K
    int*      rowptr = (int*)(w + (size_t)1024 * 1024);        // @ 1M
    int*      col    = (int*)(w + (size_t)2 * 1024 * 1024);    // @ 2M  (6.4 MB)
    int2*     bpairs = (int2*)(w + (size_t)10 * 1024 * 1024);  // @ 10M (19.3 MB, dead after B3)
    unsigned* T      = (unsigned*)(w + (size_t)10 * 1024 * 1024); // @ 10M (12.8 MB bf16 table, aliases bpairs)
    float*    B      = (float*)(w + (size_t)36 * 1024 * 1024); // @ 36M (25.6 MB r/h)

    detect_mode_kernel<<<1, 256, 0, stream>>>((const int*)ei, flag);

    // ---- bucketed CSR build ----
    hipMemsetAsync(bcnt, 0, NBUCK * sizeof(int), stream);
    bucket_scatter_kernel<<<B1_BLOCKS, 256, 0, stream>>>(ei, flag, bcnt, bpairs);
    bucket_prefix_kernel<<<1, 256, 0, stream>>>(bcnt, bbase, rowptr);
    bucket_to_csr_kernel<<<NBUCK, 256, 0, stream>>>(bcnt, bbase, bpairs, rowptr, col);

    const int gemmBlocks = (NN + 63) / 64;
    const int aggBlocks  = (NN * 64 + 255) / 256;
    const int headBlocks = (NN + 127) / 128;

    // ---- layer 1: transform-then-aggregate (bpairs dead; T may overwrite) ----
    gemm_tr_kernel<<<gemmBlocks, 256, 0, stream>>>(x, W1l, W1r, b1, T, B);
    aggregate_relu_kernel<<<aggBlocks, 256, 0, stream>>>(rowptr, col, T, B); // h1 = B

    // ---- layer 2 ----
    gemm_tr_kernel<<<gemmBlocks, 256, 0, stream>>>(B, W2l, W2r, b2, T, B);
    aggregate_relu_kernel<<<aggBlocks, 256, 0, stream>>>(rowptr, col, T, B); // h2 = B

    // ---- output head ----
    head_kernel<<<headBlocks, 256, 0, stream>>>(B, Wlin, blin, out);
}

// Round 8
// 211.870 us; speedup vs baseline: 14.3679x; 1.0677x over previous
//
#include <hip/hip_runtime.h>

#define NN 100000
#define NE 1600000
// IN_CH = HID = 64, OUT_CH = 16

// ---- bucketed CSR build geometry ----
#define BSHIFT 9
#define BWIDTH (1 << BSHIFT)                     // 512 nodes per bucket
#define NBUCK ((NN + BWIDTH - 1) >> BSHIFT)      // 196
#define SLOTS 12288                              // capacity per bucket (mean 8163)
#define CHUNK 4096                               // edges per B1 block
#define B1_BLOCKS ((NE + CHUNK - 1) / CHUNK)     // 391

typedef float    v2f __attribute__((ext_vector_type(2)));
typedef unsigned v2u __attribute__((ext_vector_type(2)));

// ---- bf16 helpers (RNE pack, exact unpack) ----
__device__ __forceinline__ float u2f(unsigned u) {
    union { unsigned u; float f; } v; v.u = u; return v.f;
}
__device__ __forceinline__ unsigned f2u(float f) {
    union { float f; unsigned u; } v; v.f = f; return v.u;
}
__device__ __forceinline__ unsigned f2bf(float f) {   // returns bf16 in low 16
    unsigned u = f2u(f);
    return (u + 0x7FFFu + ((u >> 16) & 1u)) >> 16;
}
// unpack bf16x2 word -> packed float2 (lo, hi); adds should emit v_pk_add_f32
__device__ __forceinline__ v2f unpk(unsigned x) {
    v2u w; w[0] = x << 16; w[1] = x & 0xFFFF0000u;
    union { v2u u; v2f f; } c; c.u = w; return c.f;
}

// ---------------------------------------------------------------------------
// Detect int64 vs int32 edge_index: for int64 (values < 2^31) every odd
// 32-bit word is 0; for int32 the odd words are src values.
__global__ void detect_mode_kernel(const int* ei32, int* flag) {
    __shared__ int any_nonzero;
    if (threadIdx.x == 0) any_nonzero = 0;
    __syncthreads();
    int idx = 1 + 2 * threadIdx.x;
    if (ei32[idx] != 0) atomicOr(&any_nonzero, 1);
    __syncthreads();
    if (threadIdx.x == 0) flag[0] = (any_nonzero == 0) ? 1 : 0;  // 1 => int64
}

__device__ __forceinline__ void load_edge(const void* ei, int is64, int e,
                                          int& s, int& d) {
    if (is64) {
        const long long* p = (const long long*)ei;
        s = (int)p[e];
        d = (int)p[NE + e];
    } else {
        const int* p = (const int*)ei;
        s = p[e];
        d = p[NE + e];
    }
}

// ---------------------------------------------------------------------------
// B1: bucket the edges (LDS histogram + reorder + coalesced flush).
__global__ __launch_bounds__(256) void bucket_scatter_kernel(
    const void* ei, const int* flag,
    int* __restrict__ bcnt, int2* __restrict__ bpairs)
{
    __shared__ int hist[NBUCK];
    __shared__ int scanb[NBUCK];
    __shared__ int gbase[NBUCK];
    __shared__ int lofs[NBUCK];
    __shared__ int sc[256];
    __shared__ int2 stage[CHUNK];
    __shared__ unsigned short sbuck[CHUNK];

    const int t = threadIdx.x;
    const int is64 = *flag;
    const int e0 = blockIdx.x * CHUNK;
    const int nE = min(CHUNK, NE - e0);

    for (int i = t; i < NBUCK; i += 256) { hist[i] = 0; lofs[i] = 0; }
    __syncthreads();

    int sr[16], dr[16];
    #pragma unroll
    for (int r = 0; r < 16; ++r) {
        int e = e0 + t + 256 * r;
        if (e < NE) load_edge(ei, is64, e, sr[r], dr[r]);
        else dr[r] = -1;
    }
    #pragma unroll
    for (int r = 0; r < 16; ++r)
        if (dr[r] >= 0) atomicAdd(&hist[dr[r] >> BSHIFT], 1);
    __syncthreads();

    int v = (t < NBUCK) ? hist[t] : 0;
    sc[t] = v;
    __syncthreads();
    for (int off = 1; off < 256; off <<= 1) {
        int u = (t >= off) ? sc[t - off] : 0;
        __syncthreads();
        sc[t] += u;
        __syncthreads();
    }
    if (t < NBUCK) {
        scanb[t] = sc[t] - v;
        gbase[t] = atomicAdd(&bcnt[t], v);
    }
    __syncthreads();

    #pragma unroll
    for (int r = 0; r < 16; ++r) {
        if (dr[r] >= 0) {
            int b = dr[r] >> BSHIFT;
            int p = scanb[b] + atomicAdd(&lofs[b], 1);
            stage[p] = make_int2(sr[r], dr[r]);
            sbuck[p] = (unsigned short)b;
        }
    }
    __syncthreads();

    for (int i = t; i < nE; i += 256) {
        int b = sbuck[i];
        int off = gbase[b] + (i - scanb[b]);
        if (off < SLOTS) bpairs[(size_t)b * SLOTS + off] = stage[i];
    }
}

// ---------------------------------------------------------------------------
// B2: exclusive scan of bucket counts -> bucket bases; rowptr[NN] = NE.
__global__ void bucket_prefix_kernel(const int* __restrict__ bcnt,
                                     int* __restrict__ bbase,
                                     int* __restrict__ rowptr) {
    __shared__ int sc[256];
    const int t = threadIdx.x;
    int v = (t < NBUCK) ? bcnt[t] : 0;
    sc[t] = v;
    __syncthreads();
    for (int off = 1; off < 256; off <<= 1) {
        int u = (t >= off) ? sc[t - off] : 0;
        __syncthreads();
        sc[t] += u;
        __syncthreads();
    }
    if (t < NBUCK) bbase[t] = sc[t] - v;
    if (t == 0) rowptr[NN] = NE;
}

// ---------------------------------------------------------------------------
// B3: one block per bucket -> rowptr + col (col stored as BYTE offsets,
// src*128, so the aggregate skips the shift).
__global__ __launch_bounds__(256) void bucket_to_csr_kernel(
    const int* __restrict__ bcnt, const int* __restrict__ bbase,
    const int2* __restrict__ bpairs,
    int* __restrict__ rowptr, int* __restrict__ colb)
{
    __shared__ int ldeg[BWIDTH];
    __shared__ int lptr[BWIDTH];
    __shared__ int lcnt[BWIDTH];
    __shared__ int sc[256];

    const int t = threadIdx.x;
    const int b = blockIdx.x;
    const int n0 = b << BSHIFT;
    const int cnt = min(bcnt[b], SLOTS);
    const int base = bbase[b];
    const int2* src = bpairs + (size_t)b * SLOTS;

    for (int i = t; i < BWIDTH; i += 256) { ldeg[i] = 0; lcnt[i] = 0; }
    __syncthreads();

    for (int i = t; i < cnt; i += 256)
        atomicAdd(&ldeg[src[i].y - n0], 1);
    __syncthreads();

    int a0 = ldeg[2 * t], a1 = ldeg[2 * t + 1];
    int s = a0 + a1;
    sc[t] = s;
    __syncthreads();
    for (int off = 1; off < 256; off <<= 1) {
        int u = (t >= off) ? sc[t - off] : 0;
        __syncthreads();
        sc[t] += u;
        __syncthreads();
    }
    int exc = sc[t] - s;
    lptr[2 * t] = exc;
    lptr[2 * t + 1] = exc + a0;
    __syncthreads();

    for (int i = t; i < BWIDTH; i += 256) {
        int gn = n0 + i;
        if (gn < NN) rowptr[gn] = base + lptr[i];
    }

    for (int i = t; i < cnt; i += 256) {
        int2 p = src[i];
        int li = p.y - n0;
        int pos = lptr[li] + atomicAdd(&lcnt[li], 1);
        colb[base + pos] = p.x << 7;   // byte offset into bf16 table
    }
}

// ---------------------------------------------------------------------------
// Dense GEMM: t (bf16-packed) = feat @ Wl.T ; r (f32, bias folded) = feat @ Wr.T.
// tile = 64 nodes x 128 channels, thread = 8n x 4c.
__global__ __launch_bounds__(256) void gemm_tr_kernel(
    const float* __restrict__ feat,
    const float* __restrict__ Wl, const float* __restrict__ Wr,
    const float* __restrict__ bias,
    unsigned* __restrict__ outt,          // bf16x2-packed, (NN+1) x 32 uints
    float* __restrict__ outr)
{
    __shared__ float As[64][68];
    __shared__ float Bs[64][132];
    const int t = threadIdx.x;

    {
        int c = t & 127;
        int half = t >> 7;
        const float* Wsrc = (c < 64) ? (Wl + (size_t)c * 64) : (Wr + (size_t)(c - 64) * 64);
        for (int i = 0; i < 8; ++i) {
            int j = half + 2 * i;
            float4 v = *(const float4*)(Wsrc + 4 * j);
            Bs[4 * j + 0][c] = v.x; Bs[4 * j + 1][c] = v.y;
            Bs[4 * j + 2][c] = v.z; Bs[4 * j + 3][c] = v.w;
        }
    }
    const int m0 = blockIdx.x * 64;
    {
        int k0 = 4 * (t & 15);
        int nb = t >> 4;
        for (int rep = 0; rep < 4; ++rep) {
            int n = nb + 16 * rep;
            int gn = m0 + n;
            float4 v = (gn < NN) ? *(const float4*)(feat + (size_t)gn * 64 + k0)
                                 : make_float4(0.f, 0.f, 0.f, 0.f);
            As[k0 + 0][n] = v.x; As[k0 + 1][n] = v.y;
            As[k0 + 2][n] = v.z; As[k0 + 3][n] = v.w;
        }
    }
    __syncthreads();

    const int tn = t & 7;
    const int tc = t >> 3;
    const int c0 = 4 * tc;

    float acc[8][4];
    {
        float b0 = 0.f, b1 = 0.f, b2 = 0.f, b3 = 0.f;
        if (c0 >= 64) {
            b0 = bias[c0 - 64]; b1 = bias[c0 - 63];
            b2 = bias[c0 - 62]; b3 = bias[c0 - 61];
        }
        #pragma unroll
        for (int i = 0; i < 8; ++i) {
            acc[i][0] = b0; acc[i][1] = b1; acc[i][2] = b2; acc[i][3] = b3;
        }
    }

    #pragma unroll 16
    for (int k = 0; k < 64; ++k) {
        float4 a0 = *(const float4*)&As[k][8 * tn];
        float4 a1 = *(const float4*)&As[k][8 * tn + 4];
        float4 b  = *(const float4*)&Bs[k][c0];
        float av[8] = {a0.x, a0.y, a0.z, a0.w, a1.x, a1.y, a1.z, a1.w};
        float bv[4] = {b.x, b.y, b.z, b.w};
        #pragma unroll
        for (int i = 0; i < 8; ++i)
            #pragma unroll
            for (int j = 0; j < 4; ++j)
                acc[i][j] = fmaf(av[i], bv[j], acc[i][j]);
    }

    if (c0 < 64) {
        #pragma unroll
        for (int i = 0; i < 8; ++i) {
            int gn = m0 + 8 * tn + i;
            if (gn < NN) {
                uint2 p;
                p.x = f2bf(acc[i][0]) | (f2bf(acc[i][1]) << 16);
                p.y = f2bf(acc[i][2]) | (f2bf(acc[i][3]) << 16);
                *(uint2*)(outt + (size_t)gn * 32 + (c0 >> 1)) = p;
            }
        }
    } else {
        const int cc = c0 - 64;
        #pragma unroll
        for (int i = 0; i < 8; ++i) {
            int gn = m0 + 8 * tn + i;
            if (gn < NN)
                *(float4*)(outr + (size_t)gn * 64 + cc) =
                    make_float4(acc[i][0], acc[i][1], acc[i][2], acc[i][3]);
        }
    }
}

// ---------------------------------------------------------------------------
// Gather-mean (bf16 table) + epilogue: rh <- relu(mean + rh).
// 2 nodes per wave (half-wave each); lane = half(1) x slot(2) x c8(3).
// Each lane gathers uint4 = 8 bf16 channels. Invalid slots read table row NN
// (all zeros) via one offset cndmask -- no data masking. Wave-uniform loop
// count = max over the two halves. Packed float2 accumulation (v_pk_add_f32).
__global__ void aggregate_relu_kernel(const int* __restrict__ rowptr,
                                      const int* __restrict__ colb,
                                      const unsigned* __restrict__ tt,  // (NN+1) x 32
                                      float* rh) {
    const int wv   = (blockIdx.x * blockDim.x + threadIdx.x) >> 6;
    const int lane = threadIdx.x & 63;
    const int half = lane >> 5;
    const int slot = (lane >> 3) & 3;
    const int c8   = lane & 7;
    const int node = 2 * wv + half;
    if (node >= NN) return;

    const int beg = rowptr[node], end = rowptr[node + 1];
    const int deg = end - beg;
    int niter = (deg + 3) >> 2;
    niter = max(niter, __shfl_xor(niter, 32));   // wave-uniform

    const char* tb = (const char*)tt;
    const int zoff = NN * 128;                   // zero row (byte offset)
    v2f a0 = {0.f, 0.f}, a1 = {0.f, 0.f}, a2 = {0.f, 0.f}, a3 = {0.f, 0.f};

    int jj = beg + slot;
    for (int it = 0; it < niter; ++it, jj += 4) {
        int jc = min(jj, end - 1);               // clamped col index (safe read)
        int off = colb[jc];
        off = (jj < end) ? off : zoff;           // invalid slot -> zero row
        uint4 u = *(const uint4*)(tb + (size_t)(unsigned)off + 16 * c8);
        a0 += unpk(u.x);
        a1 += unpk(u.y);
        a2 += unpk(u.z);
        a3 += unpk(u.w);
    }

    // cross-slot reduce within each 32-lane half (slots differ in bits 3..4)
    a0[0] += __shfl_xor(a0[0], 8);  a0[1] += __shfl_xor(a0[1], 8);
    a1[0] += __shfl_xor(a1[0], 8);  a1[1] += __shfl_xor(a1[1], 8);
    a2[0] += __shfl_xor(a2[0], 8);  a2[1] += __shfl_xor(a2[1], 8);
    a3[0] += __shfl_xor(a3[0], 8);  a3[1] += __shfl_xor(a3[1], 8);
    a0[0] += __shfl_xor(a0[0], 16); a0[1] += __shfl_xor(a0[1], 16);
    a1[0] += __shfl_xor(a1[0], 16); a1[1] += __shfl_xor(a1[1], 16);
    a2[0] += __shfl_xor(a2[0], 16); a2[1] += __shfl_xor(a2[1], 16);
    a3[0] += __shfl_xor(a3[0], 16); a3[1] += __shfl_xor(a3[1], 16);

    if (slot == 0) {
        float inv = 1.0f / fmaxf((float)deg, 1.0f);
        float* p = rh + (size_t)node * 64 + 8 * c8;
        float4 r0 = *(float4*)p;
        float4 r1 = *(float4*)(p + 4);
        r0.x = fmaxf(fmaf(a0[0], inv, r0.x), 0.0f);
        r0.y = fmaxf(fmaf(a0[1], inv, r0.y), 0.0f);
        r0.z = fmaxf(fmaf(a1[0], inv, r0.z), 0.0f);
        r0.w = fmaxf(fmaf(a1[1], inv, r0.w), 0.0f);
        r1.x = fmaxf(fmaf(a2[0], inv, r1.x), 0.0f);
        r1.y = fmaxf(fmaf(a2[1], inv, r1.y), 0.0f);
        r1.z = fmaxf(fmaf(a3[0], inv, r1.z), 0.0f);
        r1.w = fmaxf(fmaf(a3[1], inv, r1.w), 0.0f);
        *(float4*)p = r0;
        *(float4*)(p + 4) = r1;
    }
}

// ---------------------------------------------------------------------------
// Head GEMM: out = h @ Wlin.T + blin.
__global__ __launch_bounds__(256) void head_kernel(
    const float* __restrict__ h,
    const float* __restrict__ Wlin,
    const float* __restrict__ blin,
    float* __restrict__ out)
{
    __shared__ float As[64][132];
    __shared__ float Bs[64][18];
    const int t = threadIdx.x;

    {
        int c = t & 15, j = t >> 4;
        float4 v = *(const float4*)(Wlin + (size_t)c * 64 + 4 * j);
        Bs[4 * j + 0][c] = v.x; Bs[4 * j + 1][c] = v.y;
        Bs[4 * j + 2][c] = v.z; Bs[4 * j + 3][c] = v.w;
    }
    const int m0 = blockIdx.x * 128;
    {
        int k0 = 4 * (t & 15);
        int nb = t >> 4;
        for (int rep = 0; rep < 8; ++rep) {
            int n = nb + 16 * rep;
            int gn = m0 + n;
            float4 v = (gn < NN) ? *(const float4*)(h + (size_t)gn * 64 + k0)
                                 : make_float4(0.f, 0.f, 0.f, 0.f);
            As[k0 + 0][n] = v.x; As[k0 + 1][n] = v.y;
            As[k0 + 2][n] = v.z; As[k0 + 3][n] = v.w;
        }
    }
    __syncthreads();

    const int tn = t & 31;
    const int tc = t >> 5;
    const int c0 = 2 * tc;
    float acc[4][2];
    #pragma unroll
    for (int i = 0; i < 4; ++i) { acc[i][0] = blin[c0]; acc[i][1] = blin[c0 + 1]; }

    #pragma unroll 16
    for (int k = 0; k < 64; ++k) {
        float4 a = *(const float4*)&As[k][4 * tn];
        float b0 = Bs[k][c0], b1 = Bs[k][c0 + 1];
        float av[4] = {a.x, a.y, a.z, a.w};
        #pragma unroll
        for (int i = 0; i < 4; ++i) {
            acc[i][0] = fmaf(av[i], b0, acc[i][0]);
            acc[i][1] = fmaf(av[i], b1, acc[i][1]);
        }
    }
    #pragma unroll
    for (int i = 0; i < 4; ++i) {
        int gn = m0 + 4 * tn + i;
        if (gn < NN)
            *(float2*)(out + (size_t)gn * 16 + c0) = make_float2(acc[i][0], acc[i][1]);
    }
}

// ---------------------------------------------------------------------------
extern "C" void kernel_launch(void* const* d_in, const int* in_sizes, int n_in,
                              void* d_out, int out_size, void* d_ws, size_t ws_size,
                              hipStream_t stream) {
    const float* x    = (const float*)d_in[0];
    const void*  ei   = d_in[1];
    const float* W1l  = (const float*)d_in[2];
    const float* b1   = (const float*)d_in[3];
    const float* W1r  = (const float*)d_in[4];
    const float* W2l  = (const float*)d_in[5];
    const float* b2   = (const float*)d_in[6];
    const float* W2r  = (const float*)d_in[7];
    const float* Wlin = (const float*)d_in[8];
    const float* blin = (const float*)d_in[9];
    float* out = (float*)d_out;

    char* w = (char*)d_ws;
    int*      flag   = (int*)w;                                // @ 0
    int*      bcnt   = (int*)(w + (size_t)4 * 1024);           // @ 4K
    int*      bbase  = (int*)(w + (size_t)8 * 1024);           // @ 8K
    int*      rowptr = (int*)(w + (size_t)1024 * 1024);        // @ 1M
    int*      colb   = (int*)(w + (size_t)2 * 1024 * 1024);    // @ 2M  (6.4 MB)
    int2*     bpairs = (int2*)(w + (size_t)10 * 1024 * 1024);  // @ 10M (19.3 MB, dead after B3)
    unsigned* T      = (unsigned*)(w + (size_t)10 * 1024 * 1024); // @ 10M (12.8 MB + zero row, aliases bpairs)
    float*    B      = (float*)(w + (size_t)36 * 1024 * 1024); // @ 36M (25.6 MB r/h)

    detect_mode_kernel<<<1, 256, 0, stream>>>((const int*)ei, flag);

    // ---- bucketed CSR build ----
    hipMemsetAsync(bcnt, 0, NBUCK * sizeof(int), stream);
    bucket_scatter_kernel<<<B1_BLOCKS, 256, 0, stream>>>(ei, flag, bcnt, bpairs);
    bucket_prefix_kernel<<<1, 256, 0, stream>>>(bcnt, bbase, rowptr);
    bucket_to_csr_kernel<<<NBUCK, 256, 0, stream>>>(bcnt, bbase, bpairs, rowptr, colb);

    // zero row NN of the table (must be AFTER B3: T aliases bpairs)
    hipMemsetAsync(T + (size_t)NN * 32, 0, 128, stream);

    const int gemmBlocks = (NN + 63) / 64;
    const int aggWaves   = (NN + 1) / 2;                      // 2 nodes per wave
    const int aggBlocks  = (aggWaves * 64 + 255) / 256;
    const int headBlocks = (NN + 127) / 128;

    // ---- layer 1: transform-then-aggregate (bpairs dead; T may overwrite) ----
    gemm_tr_kernel<<<gemmBlocks, 256, 0, stream>>>(x, W1l, W1r, b1, T, B);
    aggregate_relu_kernel<<<aggBlocks, 256, 0, stream>>>(rowptr, colb, T, B); // h1 = B

    // ---- layer 2 ----
    gemm_tr_kernel<<<gemmBlocks, 256, 0, stream>>>(B, W2l, W2r, b2, T, B);
    aggregate_relu_kernel<<<aggBlocks, 256, 0, stream>>>(rowptr, colb, T, B); // h2 = B

    // ---- output head ----
    head_kernel<<<headBlocks, 256, 0, stream>>>(B, Wlin, blin, out);
}

// Round 9
// 205.317 us; speedup vs baseline: 14.8265x; 1.0319x over previous
//
#include <hip/hip_runtime.h>

#define NN 100000
#define NE 1600000
// IN_CH = HID = 64, OUT_CH = 16

// ---- bucketed CSR build geometry ----
#define BSHIFT 9
#define BWIDTH (1 << BSHIFT)                     // 512 nodes per bucket
#define NBUCK ((NN + BWIDTH - 1) >> BSHIFT)      // 196
#define SLOTS 12288                              // capacity per bucket (mean 8163)
#define CHUNK 4096                               // edges per B1 block
#define B1_BLOCKS ((NE + CHUNK - 1) / CHUNK)     // 391

typedef float    v2f __attribute__((ext_vector_type(2)));
typedef unsigned v2u __attribute__((ext_vector_type(2)));

// ---- bf16 helpers (RNE pack, exact unpack) ----
__device__ __forceinline__ float u2f(unsigned u) {
    union { unsigned u; float f; } v; v.u = u; return v.f;
}
__device__ __forceinline__ unsigned f2u(float f) {
    union { float f; unsigned u; } v; v.f = f; return v.u;
}
__device__ __forceinline__ unsigned f2bf(float f) {   // returns bf16 in low 16
    unsigned u = f2u(f);
    return (u + 0x7FFFu + ((u >> 16) & 1u)) >> 16;
}
// unpack bf16x2 word -> packed float2 (lo, hi); adds should emit v_pk_add_f32
__device__ __forceinline__ v2f unpk(unsigned x) {
    v2u w; w[0] = x << 16; w[1] = x & 0xFFFF0000u;
    union { v2u u; v2f f; } c; c.u = w; return c.f;
}

// ---------------------------------------------------------------------------
// Detect int64 vs int32 edge_index: for int64 (values < 2^31) every odd
// 32-bit word is 0; for int32 the odd words are src values.
__global__ void detect_mode_kernel(const int* ei32, int* flag) {
    __shared__ int any_nonzero;
    if (threadIdx.x == 0) any_nonzero = 0;
    __syncthreads();
    int idx = 1 + 2 * threadIdx.x;
    if (ei32[idx] != 0) atomicOr(&any_nonzero, 1);
    __syncthreads();
    if (threadIdx.x == 0) flag[0] = (any_nonzero == 0) ? 1 : 0;  // 1 => int64
}

__device__ __forceinline__ void load_edge(const void* ei, int is64, int e,
                                          int& s, int& d) {
    if (is64) {
        const long long* p = (const long long*)ei;
        s = (int)p[e];
        d = (int)p[NE + e];
    } else {
        const int* p = (const int*)ei;
        s = p[e];
        d = p[NE + e];
    }
}

// ---------------------------------------------------------------------------
// B1: bucket the edges (LDS histogram + reorder + coalesced flush).
__global__ __launch_bounds__(256) void bucket_scatter_kernel(
    const void* ei, const int* flag,
    int* __restrict__ bcnt, int2* __restrict__ bpairs)
{
    __shared__ int hist[NBUCK];
    __shared__ int scanb[NBUCK];
    __shared__ int gbase[NBUCK];
    __shared__ int lofs[NBUCK];
    __shared__ int sc[256];
    __shared__ int2 stage[CHUNK];
    __shared__ unsigned short sbuck[CHUNK];

    const int t = threadIdx.x;
    const int is64 = *flag;
    const int e0 = blockIdx.x * CHUNK;
    const int nE = min(CHUNK, NE - e0);

    for (int i = t; i < NBUCK; i += 256) { hist[i] = 0; lofs[i] = 0; }
    __syncthreads();

    int sr[16], dr[16];
    #pragma unroll
    for (int r = 0; r < 16; ++r) {
        int e = e0 + t + 256 * r;
        if (e < NE) load_edge(ei, is64, e, sr[r], dr[r]);
        else dr[r] = -1;
    }
    #pragma unroll
    for (int r = 0; r < 16; ++r)
        if (dr[r] >= 0) atomicAdd(&hist[dr[r] >> BSHIFT], 1);
    __syncthreads();

    int v = (t < NBUCK) ? hist[t] : 0;
    sc[t] = v;
    __syncthreads();
    for (int off = 1; off < 256; off <<= 1) {
        int u = (t >= off) ? sc[t - off] : 0;
        __syncthreads();
        sc[t] += u;
        __syncthreads();
    }
    if (t < NBUCK) {
        scanb[t] = sc[t] - v;
        gbase[t] = atomicAdd(&bcnt[t], v);
    }
    __syncthreads();

    #pragma unroll
    for (int r = 0; r < 16; ++r) {
        if (dr[r] >= 0) {
            int b = dr[r] >> BSHIFT;
            int p = scanb[b] + atomicAdd(&lofs[b], 1);
            stage[p] = make_int2(sr[r], dr[r]);
            sbuck[p] = (unsigned short)b;
        }
    }
    __syncthreads();

    for (int i = t; i < nE; i += 256) {
        int b = sbuck[i];
        int off = gbase[b] + (i - scanb[b]);
        if (off < SLOTS) bpairs[(size_t)b * SLOTS + off] = stage[i];
    }
}

// ---------------------------------------------------------------------------
// B2: exclusive scan of bucket counts -> bucket bases; rowptr[NN] = NE.
__global__ void bucket_prefix_kernel(const int* __restrict__ bcnt,
                                     int* __restrict__ bbase,
                                     int* __restrict__ rowptr) {
    __shared__ int sc[256];
    const int t = threadIdx.x;
    int v = (t < NBUCK) ? bcnt[t] : 0;
    sc[t] = v;
    __syncthreads();
    for (int off = 1; off < 256; off <<= 1) {
        int u = (t >= off) ? sc[t - off] : 0;
        __syncthreads();
        sc[t] += u;
        __syncthreads();
    }
    if (t < NBUCK) bbase[t] = sc[t] - v;
    if (t == 0) rowptr[NN] = NE;
}

// ---------------------------------------------------------------------------
// B3: one block per bucket -> rowptr + col (col stored as BYTE offsets,
// src*128, so the aggregate skips the shift).
__global__ __launch_bounds__(256) void bucket_to_csr_kernel(
    const int* __restrict__ bcnt, const int* __restrict__ bbase,
    const int2* __restrict__ bpairs,
    int* __restrict__ rowptr, int* __restrict__ colb)
{
    __shared__ int ldeg[BWIDTH];
    __shared__ int lptr[BWIDTH];
    __shared__ int lcnt[BWIDTH];
    __shared__ int sc[256];

    const int t = threadIdx.x;
    const int b = blockIdx.x;
    const int n0 = b << BSHIFT;
    const int cnt = min(bcnt[b], SLOTS);
    const int base = bbase[b];
    const int2* src = bpairs + (size_t)b * SLOTS;

    for (int i = t; i < BWIDTH; i += 256) { ldeg[i] = 0; lcnt[i] = 0; }
    __syncthreads();

    for (int i = t; i < cnt; i += 256)
        atomicAdd(&ldeg[src[i].y - n0], 1);
    __syncthreads();

    int a0 = ldeg[2 * t], a1 = ldeg[2 * t + 1];
    int s = a0 + a1;
    sc[t] = s;
    __syncthreads();
    for (int off = 1; off < 256; off <<= 1) {
        int u = (t >= off) ? sc[t - off] : 0;
        __syncthreads();
        sc[t] += u;
        __syncthreads();
    }
    int exc = sc[t] - s;
    lptr[2 * t] = exc;
    lptr[2 * t + 1] = exc + a0;
    __syncthreads();

    for (int i = t; i < BWIDTH; i += 256) {
        int gn = n0 + i;
        if (gn < NN) rowptr[gn] = base + lptr[i];
    }

    for (int i = t; i < cnt; i += 256) {
        int2 p = src[i];
        int li = p.y - n0;
        int pos = lptr[li] + atomicAdd(&lcnt[li], 1);
        colb[base + pos] = p.x << 7;   // byte offset into bf16 table
    }
}

// ---------------------------------------------------------------------------
// Dense GEMM: t (bf16-packed) = feat @ Wl.T ; r (f32, bias folded) = feat @ Wr.T.
// tile = 64 nodes x 128 channels, thread = 8n x 4c.
// K staged in TWO 32-wide phases -> LDS 25.6 KB (was 51.2) -> ~5 blocks/CU
// resident instead of ~1: latency hiding via co-resident blocks.
__global__ __launch_bounds__(256) void gemm_tr_kernel(
    const float* __restrict__ feat,
    const float* __restrict__ Wl, const float* __restrict__ Wr,
    const float* __restrict__ bias,
    unsigned* __restrict__ outt,          // bf16x2-packed, (NN+1) x 32 uints
    float* __restrict__ outr)
{
    __shared__ float As[32][68];
    __shared__ float Bs[32][132];
    const int t = threadIdx.x;
    const int m0 = blockIdx.x * 64;

    const int tn = t & 7;
    const int tc = t >> 3;
    const int c0 = 4 * tc;

    float acc[8][4];
    {
        float b0 = 0.f, b1 = 0.f, b2 = 0.f, b3 = 0.f;
        if (c0 >= 64) {
            b0 = bias[c0 - 64]; b1 = bias[c0 - 63];
            b2 = bias[c0 - 62]; b3 = bias[c0 - 61];
        }
        #pragma unroll
        for (int i = 0; i < 8; ++i) {
            acc[i][0] = b0; acc[i][1] = b1; acc[i][2] = b2; acc[i][3] = b3;
        }
    }

    // B-staging identity: c = t & 127, half = t >> 7
    const int cw   = t & 127;
    const int half = t >> 7;
    const float* Wsrc = (cw < 64) ? (Wl + (size_t)cw * 64)
                                  : (Wr + (size_t)(cw - 64) * 64);
    // A-staging identity: k0 = 4*(t&7), nb = t>>3
    const int k0 = 4 * (t & 7);
    const int nb = t >> 3;

    for (int kp = 0; kp < 2; ++kp) {
        if (kp) __syncthreads();   // protect LDS reuse across phases

        // ---- stage B (k rows 32*kp .. 32*kp+31) ----
        #pragma unroll
        for (int i = 0; i < 4; ++i) {
            int jl = half + 2 * i;              // local chunk 0..7
            float4 v = *(const float4*)(Wsrc + 4 * (8 * kp + jl));
            Bs[4 * jl + 0][cw] = v.x; Bs[4 * jl + 1][cw] = v.y;
            Bs[4 * jl + 2][cw] = v.z; Bs[4 * jl + 3][cw] = v.w;
        }
        // ---- stage A (64 nodes x 32 k, transposed) ----
        #pragma unroll
        for (int rep = 0; rep < 2; ++rep) {
            int n = nb + 32 * rep;
            int gn = m0 + n;
            float4 v = (gn < NN)
                ? *(const float4*)(feat + (size_t)gn * 64 + 32 * kp + k0)
                : make_float4(0.f, 0.f, 0.f, 0.f);
            As[k0 + 0][n] = v.x; As[k0 + 1][n] = v.y;
            As[k0 + 2][n] = v.z; As[k0 + 3][n] = v.w;
        }
        __syncthreads();

        #pragma unroll 16
        for (int k = 0; k < 32; ++k) {
            float4 a0 = *(const float4*)&As[k][8 * tn];
            float4 a1 = *(const float4*)&As[k][8 * tn + 4];
            float4 b  = *(const float4*)&Bs[k][c0];
            float av[8] = {a0.x, a0.y, a0.z, a0.w, a1.x, a1.y, a1.z, a1.w};
            float bv[4] = {b.x, b.y, b.z, b.w};
            #pragma unroll
            for (int i = 0; i < 8; ++i)
                #pragma unroll
                for (int j = 0; j < 4; ++j)
                    acc[i][j] = fmaf(av[i], bv[j], acc[i][j]);
        }
    }

    if (c0 < 64) {
        #pragma unroll
        for (int i = 0; i < 8; ++i) {
            int gn = m0 + 8 * tn + i;
            if (gn < NN) {
                uint2 p;
                p.x = f2bf(acc[i][0]) | (f2bf(acc[i][1]) << 16);
                p.y = f2bf(acc[i][2]) | (f2bf(acc[i][3]) << 16);
                *(uint2*)(outt + (size_t)gn * 32 + (c0 >> 1)) = p;
            }
        }
    } else {
        const int cc = c0 - 64;
        #pragma unroll
        for (int i = 0; i < 8; ++i) {
            int gn = m0 + 8 * tn + i;
            if (gn < NN)
                *(float4*)(outr + (size_t)gn * 64 + cc) =
                    make_float4(acc[i][0], acc[i][1], acc[i][2], acc[i][3]);
        }
    }
}

// ---------------------------------------------------------------------------
// Gather-mean (bf16 table) + epilogue: rh <- relu(mean + rh).
// 2 nodes per wave (half-wave each); lane = half(1) x slot(2) x c8(3).
__global__ void aggregate_relu_kernel(const int* __restrict__ rowptr,
                                      const int* __restrict__ colb,
                                      const unsigned* __restrict__ tt,  // (NN+1) x 32
                                      float* rh) {
    const int wv   = (blockIdx.x * blockDim.x + threadIdx.x) >> 6;
    const int lane = threadIdx.x & 63;
    const int half = lane >> 5;
    const int slot = (lane >> 3) & 3;
    const int c8   = lane & 7;
    const int node = 2 * wv + half;
    if (node >= NN) return;

    const int beg = rowptr[node], end = rowptr[node + 1];
    const int deg = end - beg;
    int niter = (deg + 3) >> 2;
    niter = max(niter, __shfl_xor(niter, 32));   // wave-uniform

    const char* tb = (const char*)tt;
    const int zoff = NN * 128;                   // zero row (byte offset)
    v2f a0 = {0.f, 0.f}, a1 = {0.f, 0.f}, a2 = {0.f, 0.f}, a3 = {0.f, 0.f};

    int jj = beg + slot;
    for (int it = 0; it < niter; ++it, jj += 4) {
        int jc = min(jj, end - 1);               // clamped col index (safe read)
        int off = colb[jc];
        off = (jj < end) ? off : zoff;           // invalid slot -> zero row
        uint4 u = *(const uint4*)(tb + (size_t)(unsigned)off + 16 * c8);
        a0 += unpk(u.x);
        a1 += unpk(u.y);
        a2 += unpk(u.z);
        a3 += unpk(u.w);
    }

    a0[0] += __shfl_xor(a0[0], 8);  a0[1] += __shfl_xor(a0[1], 8);
    a1[0] += __shfl_xor(a1[0], 8);  a1[1] += __shfl_xor(a1[1], 8);
    a2[0] += __shfl_xor(a2[0], 8);  a2[1] += __shfl_xor(a2[1], 8);
    a3[0] += __shfl_xor(a3[0], 8);  a3[1] += __shfl_xor(a3[1], 8);
    a0[0] += __shfl_xor(a0[0], 16); a0[1] += __shfl_xor(a0[1], 16);
    a1[0] += __shfl_xor(a1[0], 16); a1[1] += __shfl_xor(a1[1], 16);
    a2[0] += __shfl_xor(a2[0], 16); a2[1] += __shfl_xor(a2[1], 16);
    a3[0] += __shfl_xor(a3[0], 16); a3[1] += __shfl_xor(a3[1], 16);

    if (slot == 0) {
        float inv = 1.0f / fmaxf((float)deg, 1.0f);
        float* p = rh + (size_t)node * 64 + 8 * c8;
        float4 r0 = *(float4*)p;
        float4 r1 = *(float4*)(p + 4);
        r0.x = fmaxf(fmaf(a0[0], inv, r0.x), 0.0f);
        r0.y = fmaxf(fmaf(a0[1], inv, r0.y), 0.0f);
        r0.z = fmaxf(fmaf(a1[0], inv, r0.z), 0.0f);
        r0.w = fmaxf(fmaf(a1[1], inv, r0.w), 0.0f);
        r1.x = fmaxf(fmaf(a2[0], inv, r1.x), 0.0f);
        r1.y = fmaxf(fmaf(a2[1], inv, r1.y), 0.0f);
        r1.z = fmaxf(fmaf(a3[0], inv, r1.z), 0.0f);
        r1.w = fmaxf(fmaf(a3[1], inv, r1.w), 0.0f);
        *(float4*)p = r0;
        *(float4*)(p + 4) = r1;
    }
}

// ---------------------------------------------------------------------------
// Head GEMM: out = h @ Wlin.T + blin.
__global__ __launch_bounds__(256) void head_kernel(
    const float* __restrict__ h,
    const float* __restrict__ Wlin,
    const float* __restrict__ blin,
    float* __restrict__ out)
{
    __shared__ float As[64][132];
    __shared__ float Bs[64][18];
    const int t = threadIdx.x;

    {
        int c = t & 15, j = t >> 4;
        float4 v = *(const float4*)(Wlin + (size_t)c * 64 + 4 * j);
        Bs[4 * j + 0][c] = v.x; Bs[4 * j + 1][c] = v.y;
        Bs[4 * j + 2][c] = v.z; Bs[4 * j + 3][c] = v.w;
    }
    const int m0 = blockIdx.x * 128;
    {
        int k0 = 4 * (t & 15);
        int nb = t >> 4;
        for (int rep = 0; rep < 8; ++rep) {
            int n = nb + 16 * rep;
            int gn = m0 + n;
            float4 v = (gn < NN) ? *(const float4*)(h + (size_t)gn * 64 + k0)
                                 : make_float4(0.f, 0.f, 0.f, 0.f);
            As[k0 + 0][n] = v.x; As[k0 + 1][n] = v.y;
            As[k0 + 2][n] = v.z; As[k0 + 3][n] = v.w;
        }
    }
    __syncthreads();

    const int tn = t & 31;
    const int tc = t >> 5;
    const int c0 = 2 * tc;
    float acc[4][2];
    #pragma unroll
    for (int i = 0; i < 4; ++i) { acc[i][0] = blin[c0]; acc[i][1] = blin[c0 + 1]; }

    #pragma unroll 16
    for (int k = 0; k < 64; ++k) {
        float4 a = *(const float4*)&As[k][4 * tn];
        float b0 = Bs[k][c0], b1 = Bs[k][c0 + 1];
        float av[4] = {a.x, a.y, a.z, a.w};
        #pragma unroll
        for (int i = 0; i < 4; ++i) {
            acc[i][0] = fmaf(av[i], b0, acc[i][0]);
            acc[i][1] = fmaf(av[i], b1, acc[i][1]);
        }
    }
    #pragma unroll
    for (int i = 0; i < 4; ++i) {
        int gn = m0 + 4 * tn + i;
        if (gn < NN)
            *(float2*)(out + (size_t)gn * 16 + c0) = make_float2(acc[i][0], acc[i][1]);
    }
}

// ---------------------------------------------------------------------------
extern "C" void kernel_launch(void* const* d_in, const int* in_sizes, int n_in,
                              void* d_out, int out_size, void* d_ws, size_t ws_size,
                              hipStream_t stream) {
    const float* x    = (const float*)d_in[0];
    const void*  ei   = d_in[1];
    const float* W1l  = (const float*)d_in[2];
    const float* b1   = (const float*)d_in[3];
    const float* W1r  = (const float*)d_in[4];
    const float* W2l  = (const float*)d_in[5];
    const float* b2   = (const float*)d_in[6];
    const float* W2r  = (const float*)d_in[7];
    const float* Wlin = (const float*)d_in[8];
    const float* blin = (const float*)d_in[9];
    float* out = (float*)d_out;

    char* w = (char*)d_ws;
    int*      flag   = (int*)w;                                // @ 0
    int*      bcnt   = (int*)(w + (size_t)4 * 1024);           // @ 4K
    int*      bbase  = (int*)(w + (size_t)8 * 1024);           // @ 8K
    int*      rowptr = (int*)(w + (size_t)1024 * 1024);        // @ 1M
    int*      colb   = (int*)(w + (size_t)2 * 1024 * 1024);    // @ 2M  (6.4 MB)
    int2*     bpairs = (int2*)(w + (size_t)10 * 1024 * 1024);  // @ 10M (19.3 MB, dead after B3)
    unsigned* T      = (unsigned*)(w + (size_t)10 * 1024 * 1024); // @ 10M (12.8 MB + zero row, aliases bpairs)
    float*    B      = (float*)(w + (size_t)36 * 1024 * 1024); // @ 36M (25.6 MB r/h)

    detect_mode_kernel<<<1, 256, 0, stream>>>((const int*)ei, flag);

    // ---- bucketed CSR build ----
    hipMemsetAsync(bcnt, 0, NBUCK * sizeof(int), stream);
    bucket_scatter_kernel<<<B1_BLOCKS, 256, 0, stream>>>(ei, flag, bcnt, bpairs);
    bucket_prefix_kernel<<<1, 256, 0, stream>>>(bcnt, bbase, rowptr);
    bucket_to_csr_kernel<<<NBUCK, 256, 0, stream>>>(bcnt, bbase, bpairs, rowptr, colb);

    // zero row NN of the table (must be AFTER B3: T aliases bpairs)
    hipMemsetAsync(T + (size_t)NN * 32, 0, 128, stream);

    const int gemmBlocks = (NN + 63) / 64;
    const int aggWaves   = (NN + 1) / 2;                      // 2 nodes per wave
    const int aggBlocks  = (aggWaves * 64 + 255) / 256;
    const int headBlocks = (NN + 127) / 128;

    // ---- layer 1: transform-then-aggregate (bpairs dead; T may overwrite) ----
    gemm_tr_kernel<<<gemmBlocks, 256, 0, stream>>>(x, W1l, W1r, b1, T, B);
    aggregate_relu_kernel<<<aggBlocks, 256, 0, stream>>>(rowptr, colb, T, B); // h1 = B

    // ---- layer 2 ----
    gemm_tr_kernel<<<gemmBlocks, 256, 0, stream>>>(B, W2l, W2r, b2, T, B);
    aggregate_relu_kernel<<<aggBlocks, 256, 0, stream>>>(rowptr, colb, T, B); // h2 = B

    // ---- output head ----
    head_kernel<<<headBlocks, 256, 0, stream>>>(B, Wlin, blin, out);
}

// Round 10
// 190.343 us; speedup vs baseline: 15.9928x; 1.0787x over previous
//
#include <hip/hip_runtime.h>

#define NN 100000
#define NE 1600000
// IN_CH = HID = 64, OUT_CH = 16

// ---- bucketed CSR build geometry ----
#define BSHIFT 9
#define BWIDTH (1 << BSHIFT)                     // 512 nodes per bucket
#define NBUCK ((NN + BWIDTH - 1) >> BSHIFT)      // 196
#define SLOTS 12288                              // capacity per bucket (mean 8163)
#define CHUNK 4096                               // edges per B1 block
#define B1_BLOCKS ((NE + CHUNK - 1) / CHUNK)     // 391

typedef float    v2f __attribute__((ext_vector_type(2)));
typedef unsigned v2u __attribute__((ext_vector_type(2)));

// ---- bf16 helpers (RNE pack, exact unpack) ----
__device__ __forceinline__ float u2f(unsigned u) {
    union { unsigned u; float f; } v; v.u = u; return v.f;
}
__device__ __forceinline__ unsigned f2u(float f) {
    union { float f; unsigned u; } v; v.f = f; return v.u;
}
__device__ __forceinline__ unsigned f2bf(float f) {   // returns bf16 in low 16
    unsigned u = f2u(f);
    return (u + 0x7FFFu + ((u >> 16) & 1u)) >> 16;
}
// unpack bf16x2 word -> packed float2 (lo, hi); adds should emit v_pk_add_f32
__device__ __forceinline__ v2f unpk(unsigned x) {
    v2u w; w[0] = x << 16; w[1] = x & 0xFFFF0000u;
    union { v2u u; v2f f; } c; c.u = w; return c.f;
}

// ---------------------------------------------------------------------------
// Detect int64 vs int32 edge_index; also zeroes bcnt (replaces a memset).
__global__ void detect_mode_kernel(const int* ei32, int* flag, int* bcnt) {
    __shared__ int any_nonzero;
    if (threadIdx.x == 0) any_nonzero = 0;
    if (threadIdx.x < NBUCK) bcnt[threadIdx.x] = 0;
    __syncthreads();
    int idx = 1 + 2 * threadIdx.x;
    if (ei32[idx] != 0) atomicOr(&any_nonzero, 1);
    __syncthreads();
    if (threadIdx.x == 0) flag[0] = (any_nonzero == 0) ? 1 : 0;  // 1 => int64
}

__device__ __forceinline__ void load_edge(const void* ei, int is64, int e,
                                          int& s, int& d) {
    if (is64) {
        const long long* p = (const long long*)ei;
        s = (int)p[e];
        d = (int)p[NE + e];
    } else {
        const int* p = (const int*)ei;
        s = p[e];
        d = p[NE + e];
    }
}

// ---------------------------------------------------------------------------
// B1: bucket the edges (LDS histogram + reorder + coalesced flush).
__global__ __launch_bounds__(256) void bucket_scatter_kernel(
    const void* ei, const int* flag,
    int* __restrict__ bcnt, int2* __restrict__ bpairs)
{
    __shared__ int hist[NBUCK];
    __shared__ int scanb[NBUCK];
    __shared__ int gbase[NBUCK];
    __shared__ int lofs[NBUCK];
    __shared__ int sc[256];
    __shared__ int2 stage[CHUNK];
    __shared__ unsigned short sbuck[CHUNK];

    const int t = threadIdx.x;
    const int is64 = *flag;
    const int e0 = blockIdx.x * CHUNK;
    const int nE = min(CHUNK, NE - e0);

    for (int i = t; i < NBUCK; i += 256) { hist[i] = 0; lofs[i] = 0; }
    __syncthreads();

    int sr[16], dr[16];
    #pragma unroll
    for (int r = 0; r < 16; ++r) {
        int e = e0 + t + 256 * r;
        if (e < NE) load_edge(ei, is64, e, sr[r], dr[r]);
        else dr[r] = -1;
    }
    #pragma unroll
    for (int r = 0; r < 16; ++r)
        if (dr[r] >= 0) atomicAdd(&hist[dr[r] >> BSHIFT], 1);
    __syncthreads();

    int v = (t < NBUCK) ? hist[t] : 0;
    sc[t] = v;
    __syncthreads();
    for (int off = 1; off < 256; off <<= 1) {
        int u = (t >= off) ? sc[t - off] : 0;
        __syncthreads();
        sc[t] += u;
        __syncthreads();
    }
    if (t < NBUCK) {
        scanb[t] = sc[t] - v;
        gbase[t] = atomicAdd(&bcnt[t], v);
    }
    __syncthreads();

    #pragma unroll
    for (int r = 0; r < 16; ++r) {
        if (dr[r] >= 0) {
            int b = dr[r] >> BSHIFT;
            int p = scanb[b] + atomicAdd(&lofs[b], 1);
            stage[p] = make_int2(sr[r], dr[r]);
            sbuck[p] = (unsigned short)b;
        }
    }
    __syncthreads();

    for (int i = t; i < nE; i += 256) {
        int b = sbuck[i];
        int off = gbase[b] + (i - scanb[b]);
        if (off < SLOTS) bpairs[(size_t)b * SLOTS + off] = stage[i];
    }
}

// ---------------------------------------------------------------------------
// B2: exclusive scan of bucket counts -> bucket bases; rowptr[NN] = NE.
__global__ void bucket_prefix_kernel(const int* __restrict__ bcnt,
                                     int* __restrict__ bbase,
                                     int* __restrict__ rowptr) {
    __shared__ int sc[256];
    const int t = threadIdx.x;
    int v = (t < NBUCK) ? bcnt[t] : 0;
    sc[t] = v;
    __syncthreads();
    for (int off = 1; off < 256; off <<= 1) {
        int u = (t >= off) ? sc[t - off] : 0;
        __syncthreads();
        sc[t] += u;
        __syncthreads();
    }
    if (t < NBUCK) bbase[t] = sc[t] - v;
    if (t == 0) rowptr[NN] = NE;
}

// ---------------------------------------------------------------------------
// B3: one block per bucket -> rowptr + col (col stored as BYTE offsets,
// src*128, so the aggregate skips the shift).
__global__ __launch_bounds__(256) void bucket_to_csr_kernel(
    const int* __restrict__ bcnt, const int* __restrict__ bbase,
    const int2* __restrict__ bpairs,
    int* __restrict__ rowptr, int* __restrict__ colb)
{
    __shared__ int ldeg[BWIDTH];
    __shared__ int lptr[BWIDTH];
    __shared__ int lcnt[BWIDTH];
    __shared__ int sc[256];

    const int t = threadIdx.x;
    const int b = blockIdx.x;
    const int n0 = b << BSHIFT;
    const int cnt = min(bcnt[b], SLOTS);
    const int base = bbase[b];
    const int2* src = bpairs + (size_t)b * SLOTS;

    for (int i = t; i < BWIDTH; i += 256) { ldeg[i] = 0; lcnt[i] = 0; }
    __syncthreads();

    for (int i = t; i < cnt; i += 256)
        atomicAdd(&ldeg[src[i].y - n0], 1);
    __syncthreads();

    int a0 = ldeg[2 * t], a1 = ldeg[2 * t + 1];
    int s = a0 + a1;
    sc[t] = s;
    __syncthreads();
    for (int off = 1; off < 256; off <<= 1) {
        int u = (t >= off) ? sc[t - off] : 0;
        __syncthreads();
        sc[t] += u;
        __syncthreads();
    }
    int exc = sc[t] - s;
    lptr[2 * t] = exc;
    lptr[2 * t + 1] = exc + a0;
    __syncthreads();

    for (int i = t; i < BWIDTH; i += 256) {
        int gn = n0 + i;
        if (gn < NN) rowptr[gn] = base + lptr[i];
    }

    for (int i = t; i < cnt; i += 256) {
        int2 p = src[i];
        int li = p.y - n0;
        int pos = lptr[li] + atomicAdd(&lcnt[li], 1);
        colb[base + pos] = p.x << 7;   // byte offset into bf16 table
    }
}

// ---------------------------------------------------------------------------
// Dense GEMM: t (bf16-packed) = feat @ Wl.T ; r (f32, bias folded) = feat @ Wr.T.
// tile = 64 nodes x 128 channels, thread = 8n x 4c, K staged in two 32-phases
// (25.6 KB LDS -> multiple blocks/CU resident). Block 0 also zeroes table
// row NN (the aggregate's zero row) -- replaces a 128 B memset launch.
__global__ __launch_bounds__(256) void gemm_tr_kernel(
    const float* __restrict__ feat,
    const float* __restrict__ Wl, const float* __restrict__ Wr,
    const float* __restrict__ bias,
    unsigned* __restrict__ outt,          // bf16x2-packed, (NN+1) x 32 uints
    float* __restrict__ outr)
{
    __shared__ float As[32][68];
    __shared__ float Bs[32][132];
    const int t = threadIdx.x;
    const int m0 = blockIdx.x * 64;

    if (blockIdx.x == 0 && t < 32) outt[(size_t)NN * 32 + t] = 0u;  // zero row

    const int tn = t & 7;
    const int tc = t >> 3;
    const int c0 = 4 * tc;

    float acc[8][4];
    {
        float b0 = 0.f, b1 = 0.f, b2 = 0.f, b3 = 0.f;
        if (c0 >= 64) {
            b0 = bias[c0 - 64]; b1 = bias[c0 - 63];
            b2 = bias[c0 - 62]; b3 = bias[c0 - 61];
        }
        #pragma unroll
        for (int i = 0; i < 8; ++i) {
            acc[i][0] = b0; acc[i][1] = b1; acc[i][2] = b2; acc[i][3] = b3;
        }
    }

    const int cw   = t & 127;
    const int half = t >> 7;
    const float* Wsrc = (cw < 64) ? (Wl + (size_t)cw * 64)
                                  : (Wr + (size_t)(cw - 64) * 64);
    const int k0 = 4 * (t & 7);
    const int nb = t >> 3;

    for (int kp = 0; kp < 2; ++kp) {
        if (kp) __syncthreads();   // protect LDS reuse across phases

        #pragma unroll
        for (int i = 0; i < 4; ++i) {
            int jl = half + 2 * i;              // local chunk 0..7
            float4 v = *(const float4*)(Wsrc + 4 * (8 * kp + jl));
            Bs[4 * jl + 0][cw] = v.x; Bs[4 * jl + 1][cw] = v.y;
            Bs[4 * jl + 2][cw] = v.z; Bs[4 * jl + 3][cw] = v.w;
        }
        #pragma unroll
        for (int rep = 0; rep < 2; ++rep) {
            int n = nb + 32 * rep;
            int gn = m0 + n;
            float4 v = (gn < NN)
                ? *(const float4*)(feat + (size_t)gn * 64 + 32 * kp + k0)
                : make_float4(0.f, 0.f, 0.f, 0.f);
            As[k0 + 0][n] = v.x; As[k0 + 1][n] = v.y;
            As[k0 + 2][n] = v.z; As[k0 + 3][n] = v.w;
        }
        __syncthreads();

        #pragma unroll 16
        for (int k = 0; k < 32; ++k) {
            float4 a0 = *(const float4*)&As[k][8 * tn];
            float4 a1 = *(const float4*)&As[k][8 * tn + 4];
            float4 b  = *(const float4*)&Bs[k][c0];
            float av[8] = {a0.x, a0.y, a0.z, a0.w, a1.x, a1.y, a1.z, a1.w};
            float bv[4] = {b.x, b.y, b.z, b.w};
            #pragma unroll
            for (int i = 0; i < 8; ++i)
                #pragma unroll
                for (int j = 0; j < 4; ++j)
                    acc[i][j] = fmaf(av[i], bv[j], acc[i][j]);
        }
    }

    if (c0 < 64) {
        #pragma unroll
        for (int i = 0; i < 8; ++i) {
            int gn = m0 + 8 * tn + i;
            if (gn < NN) {
                uint2 p;
                p.x = f2bf(acc[i][0]) | (f2bf(acc[i][1]) << 16);
                p.y = f2bf(acc[i][2]) | (f2bf(acc[i][3]) << 16);
                *(uint2*)(outt + (size_t)gn * 32 + (c0 >> 1)) = p;
            }
        }
    } else {
        const int cc = c0 - 64;
        #pragma unroll
        for (int i = 0; i < 8; ++i) {
            int gn = m0 + 8 * tn + i;
            if (gn < NN)
                *(float4*)(outr + (size_t)gn * 64 + cc) =
                    make_float4(acc[i][0], acc[i][1], acc[i][2], acc[i][3]);
        }
    }
}

// ---------------------------------------------------------------------------
// Gather-mean (bf16 table) + epilogue: rh <- relu(mean + rh).
// 2 nodes per wave; lane = half(1) x slot(2) x c8(3). 2-deep software
// pipeline: two col loads then two gathers in flight per step (dual
// accumulator banks) -> halves exposed dependent-chain latency.
__global__ void aggregate_relu_kernel(const int* __restrict__ rowptr,
                                      const int* __restrict__ colb,
                                      const unsigned* __restrict__ tt,  // (NN+1) x 32
                                      float* rh) {
    const int wv   = (blockIdx.x * blockDim.x + threadIdx.x) >> 6;
    const int lane = threadIdx.x & 63;
    const int half = lane >> 5;
    const int slot = (lane >> 3) & 3;
    const int c8   = lane & 7;
    const int node = 2 * wv + half;
    if (node >= NN) return;

    const int beg = rowptr[node], end = rowptr[node + 1];
    const int deg = end - beg;
    int niter = (deg + 3) >> 2;
    niter = max(niter, __shfl_xor(niter, 32));   // wave-uniform

    const char* tb = (const char*)tt;
    const int zoff = NN * 128;                   // zero row (byte offset)
    v2f a0 = {0.f, 0.f}, a1 = {0.f, 0.f}, a2 = {0.f, 0.f}, a3 = {0.f, 0.f};
    v2f b0 = {0.f, 0.f}, b1 = {0.f, 0.f}, b2 = {0.f, 0.f}, b3 = {0.f, 0.f};

    int jj = beg + slot;
    int it = 0;
    for (; it + 2 <= niter; it += 2, jj += 8) {
        int jc0 = min(jj, end - 1);
        int jc1 = min(jj + 4, end - 1);
        int o0 = colb[jc0];
        int o1 = colb[jc1];
        o0 = (jj < end) ? o0 : zoff;
        o1 = (jj + 4 < end) ? o1 : zoff;
        uint4 u0 = *(const uint4*)(tb + (size_t)(unsigned)o0 + 16 * c8);
        uint4 u1 = *(const uint4*)(tb + (size_t)(unsigned)o1 + 16 * c8);
        a0 += unpk(u0.x); a1 += unpk(u0.y); a2 += unpk(u0.z); a3 += unpk(u0.w);
        b0 += unpk(u1.x); b1 += unpk(u1.y); b2 += unpk(u1.z); b3 += unpk(u1.w);
    }
    if (it < niter) {
        int jc0 = min(jj, end - 1);
        int o0 = colb[jc0];
        o0 = (jj < end) ? o0 : zoff;
        uint4 u0 = *(const uint4*)(tb + (size_t)(unsigned)o0 + 16 * c8);
        a0 += unpk(u0.x); a1 += unpk(u0.y); a2 += unpk(u0.z); a3 += unpk(u0.w);
    }
    a0 += b0; a1 += b1; a2 += b2; a3 += b3;

    // cross-slot reduce within each 32-lane half (slots differ in bits 3..4)
    a0[0] += __shfl_xor(a0[0], 8);  a0[1] += __shfl_xor(a0[1], 8);
    a1[0] += __shfl_xor(a1[0], 8);  a1[1] += __shfl_xor(a1[1], 8);
    a2[0] += __shfl_xor(a2[0], 8);  a2[1] += __shfl_xor(a2[1], 8);
    a3[0] += __shfl_xor(a3[0], 8);  a3[1] += __shfl_xor(a3[1], 8);
    a0[0] += __shfl_xor(a0[0], 16); a0[1] += __shfl_xor(a0[1], 16);
    a1[0] += __shfl_xor(a1[0], 16); a1[1] += __shfl_xor(a1[1], 16);
    a2[0] += __shfl_xor(a2[0], 16); a2[1] += __shfl_xor(a2[1], 16);
    a3[0] += __shfl_xor(a3[0], 16); a3[1] += __shfl_xor(a3[1], 16);

    if (slot == 0) {
        float inv = 1.0f / fmaxf((float)deg, 1.0f);
        float* p = rh + (size_t)node * 64 + 8 * c8;
        float4 r0 = *(float4*)p;
        float4 r1 = *(float4*)(p + 4);
        r0.x = fmaxf(fmaf(a0[0], inv, r0.x), 0.0f);
        r0.y = fmaxf(fmaf(a0[1], inv, r0.y), 0.0f);
        r0.z = fmaxf(fmaf(a1[0], inv, r0.z), 0.0f);
        r0.w = fmaxf(fmaf(a1[1], inv, r0.w), 0.0f);
        r1.x = fmaxf(fmaf(a2[0], inv, r1.x), 0.0f);
        r1.y = fmaxf(fmaf(a2[1], inv, r1.y), 0.0f);
        r1.z = fmaxf(fmaf(a3[0], inv, r1.z), 0.0f);
        r1.w = fmaxf(fmaf(a3[1], inv, r1.w), 0.0f);
        *(float4*)p = r0;
        *(float4*)(p + 4) = r1;
    }
}

// ---------------------------------------------------------------------------
// Head GEMM: out = h @ Wlin.T + blin.
__global__ __launch_bounds__(256) void head_kernel(
    const float* __restrict__ h,
    const float* __restrict__ Wlin,
    const float* __restrict__ blin,
    float* __restrict__ out)
{
    __shared__ float As[64][132];
    __shared__ float Bs[64][18];
    const int t = threadIdx.x;

    {
        int c = t & 15, j = t >> 4;
        float4 v = *(const float4*)(Wlin + (size_t)c * 64 + 4 * j);
        Bs[4 * j + 0][c] = v.x; Bs[4 * j + 1][c] = v.y;
        Bs[4 * j + 2][c] = v.z; Bs[4 * j + 3][c] = v.w;
    }
    const int m0 = blockIdx.x * 128;
    {
        int k0 = 4 * (t & 15);
        int nb = t >> 4;
        for (int rep = 0; rep < 8; ++rep) {
            int n = nb + 16 * rep;
            int gn = m0 + n;
            float4 v = (gn < NN) ? *(const float4*)(h + (size_t)gn * 64 + k0)
                                 : make_float4(0.f, 0.f, 0.f, 0.f);
            As[k0 + 0][n] = v.x; As[k0 + 1][n] = v.y;
            As[k0 + 2][n] = v.z; As[k0 + 3][n] = v.w;
        }
    }
    __syncthreads();

    const int tn = t & 31;
    const int tc = t >> 5;
    const int c0 = 2 * tc;
    float acc[4][2];
    #pragma unroll
    for (int i = 0; i < 4; ++i) { acc[i][0] = blin[c0]; acc[i][1] = blin[c0 + 1]; }

    #pragma unroll 16
    for (int k = 0; k < 64; ++k) {
        float4 a = *(const float4*)&As[k][4 * tn];
        float b0 = Bs[k][c0], b1 = Bs[k][c0 + 1];
        float av[4] = {a.x, a.y, a.z, a.w};
        #pragma unroll
        for (int i = 0; i < 4; ++i) {
            acc[i][0] = fmaf(av[i], b0, acc[i][0]);
            acc[i][1] = fmaf(av[i], b1, acc[i][1]);
        }
    }
    #pragma unroll
    for (int i = 0; i < 4; ++i) {
        int gn = m0 + 4 * tn + i;
        if (gn < NN)
            *(float2*)(out + (size_t)gn * 16 + c0) = make_float2(acc[i][0], acc[i][1]);
    }
}

// ---------------------------------------------------------------------------
extern "C" void kernel_launch(void* const* d_in, const int* in_sizes, int n_in,
                              void* d_out, int out_size, void* d_ws, size_t ws_size,
                              hipStream_t stream) {
    const float* x    = (const float*)d_in[0];
    const void*  ei   = d_in[1];
    const float* W1l  = (const float*)d_in[2];
    const float* b1   = (const float*)d_in[3];
    const float* W1r  = (const float*)d_in[4];
    const float* W2l  = (const float*)d_in[5];
    const float* b2   = (const float*)d_in[6];
    const float* W2r  = (const float*)d_in[7];
    const float* Wlin = (const float*)d_in[8];
    const float* blin = (const float*)d_in[9];
    float* out = (float*)d_out;

    char* w = (char*)d_ws;
    int*      flag   = (int*)w;                                // @ 0
    int*      bcnt   = (int*)(w + (size_t)4 * 1024);           // @ 4K
    int*      bbase  = (int*)(w + (size_t)8 * 1024);           // @ 8K
    int*      rowptr = (int*)(w + (size_t)1024 * 1024);        // @ 1M
    int*      colb   = (int*)(w + (size_t)2 * 1024 * 1024);    // @ 2M  (6.4 MB)
    int2*     bpairs = (int2*)(w + (size_t)10 * 1024 * 1024);  // @ 10M (19.3 MB, dead after B3)
    unsigned* T      = (unsigned*)(w + (size_t)10 * 1024 * 1024); // @ 10M (12.8 MB + zero row, aliases bpairs)
    float*    B      = (float*)(w + (size_t)36 * 1024 * 1024); // @ 36M (25.6 MB r/h)

    // ---- bucketed CSR build (detect also zeroes bcnt) ----
    detect_mode_kernel<<<1, 256, 0, stream>>>((const int*)ei, flag, bcnt);
    bucket_scatter_kernel<<<B1_BLOCKS, 256, 0, stream>>>(ei, flag, bcnt, bpairs);
    bucket_prefix_kernel<<<1, 256, 0, stream>>>(bcnt, bbase, rowptr);
    bucket_to_csr_kernel<<<NBUCK, 256, 0, stream>>>(bcnt, bbase, bpairs, rowptr, colb);

    const int gemmBlocks = (NN + 63) / 64;
    const int aggWaves   = (NN + 1) / 2;                      // 2 nodes per wave
    const int aggBlocks  = (aggWaves * 64 + 255) / 256;
    const int headBlocks = (NN + 127) / 128;

    // ---- layer 1 (gemm block 0 zeroes table row NN; bpairs dead by now) ----
    gemm_tr_kernel<<<gemmBlocks, 256, 0, stream>>>(x, W1l, W1r, b1, T, B);
    aggregate_relu_kernel<<<aggBlocks, 256, 0, stream>>>(rowptr, colb, T, B); // h1 = B

    // ---- layer 2 ----
    gemm_tr_kernel<<<gemmBlocks, 256, 0, stream>>>(B, W2l, W2r, b2, T, B);
    aggregate_relu_kernel<<<aggBlocks, 256, 0, stream>>>(rowptr, colb, T, B); // h2 = B

    // ---- output head ----
    head_kernel<<<headBlocks, 256, 0, stream>>>(B, Wlin, blin, out);
}

// Round 11
// 189.037 us; speedup vs baseline: 16.1033x; 1.0069x over previous
//
#include <hip/hip_runtime.h>

#define NN 100000
#define NE 1600000
// IN_CH = HID = 64, OUT_CH = 16

// ---- bucketed CSR build geometry ----
#define BSHIFT 9
#define BWIDTH (1 << BSHIFT)                     // 512 nodes per bucket
#define NBUCK ((NN + BWIDTH - 1) >> BSHIFT)      // 196
#define SLOTS 12288                              // capacity per bucket (mean 8163)
#define CHUNK 4096                               // edges per B1 block
#define B1_BLOCKS ((NE + CHUNK - 1) / CHUNK)     // 391

typedef float    v2f __attribute__((ext_vector_type(2)));
typedef unsigned v2u __attribute__((ext_vector_type(2)));

// ---- bf16 helpers (RNE pack, exact unpack) ----
__device__ __forceinline__ float u2f(unsigned u) {
    union { unsigned u; float f; } v; v.u = u; return v.f;
}
__device__ __forceinline__ unsigned f2u(float f) {
    union { float f; unsigned u; } v; v.f = f; return v.u;
}
__device__ __forceinline__ unsigned f2bf(float f) {   // returns bf16 in low 16
    unsigned u = f2u(f);
    return (u + 0x7FFFu + ((u >> 16) & 1u)) >> 16;
}
__device__ __forceinline__ v2f unpk(unsigned x) {
    v2u w; w[0] = x << 16; w[1] = x & 0xFFFF0000u;
    union { v2u u; v2f f; } c; c.u = w; return c.f;
}

// ---------------------------------------------------------------------------
// Detect int64 vs int32 edge_index; also zeroes bcnt (replaces a memset).
__global__ void detect_mode_kernel(const int* ei32, int* flag, int* bcnt) {
    __shared__ int any_nonzero;
    if (threadIdx.x == 0) any_nonzero = 0;
    if (threadIdx.x < NBUCK) bcnt[threadIdx.x] = 0;
    __syncthreads();
    int idx = 1 + 2 * threadIdx.x;
    if (ei32[idx] != 0) atomicOr(&any_nonzero, 1);
    __syncthreads();
    if (threadIdx.x == 0) flag[0] = (any_nonzero == 0) ? 1 : 0;  // 1 => int64
}

__device__ __forceinline__ void load_edge(const void* ei, int is64, int e,
                                          int& s, int& d) {
    if (is64) {
        const long long* p = (const long long*)ei;
        s = (int)p[e];
        d = (int)p[NE + e];
    } else {
        const int* p = (const int*)ei;
        s = p[e];
        d = p[NE + e];
    }
}

// ---------------------------------------------------------------------------
// B1: bucket the edges (LDS histogram + reorder + coalesced flush).
__global__ __launch_bounds__(256) void bucket_scatter_kernel(
    const void* ei, const int* flag,
    int* __restrict__ bcnt, int2* __restrict__ bpairs)
{
    __shared__ int hist[NBUCK];
    __shared__ int scanb[NBUCK];
    __shared__ int gbase[NBUCK];
    __shared__ int lofs[NBUCK];
    __shared__ int sc[256];
    __shared__ int2 stage[CHUNK];
    __shared__ unsigned short sbuck[CHUNK];

    const int t = threadIdx.x;
    const int is64 = *flag;
    const int e0 = blockIdx.x * CHUNK;
    const int nE = min(CHUNK, NE - e0);

    for (int i = t; i < NBUCK; i += 256) { hist[i] = 0; lofs[i] = 0; }
    __syncthreads();

    int sr[16], dr[16];
    #pragma unroll
    for (int r = 0; r < 16; ++r) {
        int e = e0 + t + 256 * r;
        if (e < NE) load_edge(ei, is64, e, sr[r], dr[r]);
        else dr[r] = -1;
    }
    #pragma unroll
    for (int r = 0; r < 16; ++r)
        if (dr[r] >= 0) atomicAdd(&hist[dr[r] >> BSHIFT], 1);
    __syncthreads();

    int v = (t < NBUCK) ? hist[t] : 0;
    sc[t] = v;
    __syncthreads();
    for (int off = 1; off < 256; off <<= 1) {
        int u = (t >= off) ? sc[t - off] : 0;
        __syncthreads();
        sc[t] += u;
        __syncthreads();
    }
    if (t < NBUCK) {
        scanb[t] = sc[t] - v;
        gbase[t] = atomicAdd(&bcnt[t], v);
    }
    __syncthreads();

    #pragma unroll
    for (int r = 0; r < 16; ++r) {
        if (dr[r] >= 0) {
            int b = dr[r] >> BSHIFT;
            int p = scanb[b] + atomicAdd(&lofs[b], 1);
            stage[p] = make_int2(sr[r], dr[r]);
            sbuck[p] = (unsigned short)b;
        }
    }
    __syncthreads();

    for (int i = t; i < nE; i += 256) {
        int b = sbuck[i];
        int off = gbase[b] + (i - scanb[b]);
        if (off < SLOTS) bpairs[(size_t)b * SLOTS + off] = stage[i];
    }
}

// ---------------------------------------------------------------------------
// B2: exclusive scan of bucket counts -> bucket bases; rowptr[NN] = NE.
__global__ void bucket_prefix_kernel(const int* __restrict__ bcnt,
                                     int* __restrict__ bbase,
                                     int* __restrict__ rowptr) {
    __shared__ int sc[256];
    const int t = threadIdx.x;
    int v = (t < NBUCK) ? bcnt[t] : 0;
    sc[t] = v;
    __syncthreads();
    for (int off = 1; off < 256; off <<= 1) {
        int u = (t >= off) ? sc[t - off] : 0;
        __syncthreads();
        sc[t] += u;
        __syncthreads();
    }
    if (t < NBUCK) bbase[t] = sc[t] - v;
    if (t == 0) rowptr[NN] = NE;
}

// ---------------------------------------------------------------------------
// B3: one block per bucket -> rowptr + col (col stored as BYTE offsets).
__global__ __launch_bounds__(256) void bucket_to_csr_kernel(
    const int* __restrict__ bcnt, const int* __restrict__ bbase,
    const int2* __restrict__ bpairs,
    int* __restrict__ rowptr, int* __restrict__ colb)
{
    __shared__ int ldeg[BWIDTH];
    __shared__ int lptr[BWIDTH];
    __shared__ int lcnt[BWIDTH];
    __shared__ int sc[256];

    const int t = threadIdx.x;
    const int b = blockIdx.x;
    const int n0 = b << BSHIFT;
    const int cnt = min(bcnt[b], SLOTS);
    const int base = bbase[b];
    const int2* src = bpairs + (size_t)b * SLOTS;

    for (int i = t; i < BWIDTH; i += 256) { ldeg[i] = 0; lcnt[i] = 0; }
    __syncthreads();

    for (int i = t; i < cnt; i += 256)
        atomicAdd(&ldeg[src[i].y - n0], 1);
    __syncthreads();

    int a0 = ldeg[2 * t], a1 = ldeg[2 * t + 1];
    int s = a0 + a1;
    sc[t] = s;
    __syncthreads();
    for (int off = 1; off < 256; off <<= 1) {
        int u = (t >= off) ? sc[t - off] : 0;
        __syncthreads();
        sc[t] += u;
        __syncthreads();
    }
    int exc = sc[t] - s;
    lptr[2 * t] = exc;
    lptr[2 * t + 1] = exc + a0;
    __syncthreads();

    for (int i = t; i < BWIDTH; i += 256) {
        int gn = n0 + i;
        if (gn < NN) rowptr[gn] = base + lptr[i];
    }

    for (int i = t; i < cnt; i += 256) {
        int2 p = src[i];
        int li = p.y - n0;
        int pos = lptr[li] + atomicAdd(&lcnt[li], 1);
        colb[base + pos] = p.x << 7;   // byte offset into bf16 table
    }
}

// ---------------------------------------------------------------------------
// Dense GEMM: t (bf16) = feat @ Wl.T ; r (bf16, bias folded) = feat @ Wr.T.
// tile = 64n x 128c, thread = 8n x 4c, K in two 32-phases (25.6 KB LDS).
// T14 async-stage: phase-1 global loads issue into registers before phase-0
// compute; LDS write happens after the barrier -> HBM latency hidden.
// BF16IN selects f32 (layer 1) vs bf16-packed (layer 2) input features.
template<int BF16IN>
__global__ __launch_bounds__(256) void gemm_tr_kernel(
    const void* __restrict__ featv,
    const float* __restrict__ Wl, const float* __restrict__ Wr,
    const float* __restrict__ bias,
    unsigned* __restrict__ outt,          // bf16x2-packed, (NN+1) x 32 uints
    unsigned* __restrict__ outr)          // bf16x2-packed, NN x 32 uints
{
    __shared__ float As[32][68];
    __shared__ float Bs[32][132];
    const int t = threadIdx.x;
    const int m0 = blockIdx.x * 64;

    if (blockIdx.x == 0 && t < 32) outt[(size_t)NN * 32 + t] = 0u;  // zero row

    const int tn = t & 7;
    const int tc = t >> 3;
    const int c0 = 4 * tc;

    float acc[8][4];
    {
        float b0 = 0.f, b1 = 0.f, b2 = 0.f, b3 = 0.f;
        if (c0 >= 64) {
            b0 = bias[c0 - 64]; b1 = bias[c0 - 63];
            b2 = bias[c0 - 62]; b3 = bias[c0 - 61];
        }
        #pragma unroll
        for (int i = 0; i < 8; ++i) {
            acc[i][0] = b0; acc[i][1] = b1; acc[i][2] = b2; acc[i][3] = b3;
        }
    }

    // B-staging identity
    const int cw   = t & 127;
    const int half = t >> 7;
    const float* Wsrc = (cw < 64) ? (Wl + (size_t)cw * 64)
                                  : (Wr + (size_t)(cw - 64) * 64);
    // A-staging identities
    const float*    featf = (const float*)featv;
    const unsigned* featu = (const unsigned*)featv;
    const int k0f = 4 * (t & 7);   // f32 path:  k group
    const int nbf = t >> 3;        // f32 path:  node
    const int kqb = t & 3;         // bf16 path: uint4 index (k = 8*kqb..+7)
    const int nbb = t >> 2;        // bf16 path: node 0..63

    // ================= phase 0: load -> LDS =================
    float4 bv[4];
    #pragma unroll
    for (int i = 0; i < 4; ++i)
        bv[i] = *(const float4*)(Wsrc + 4 * (half + 2 * i));

    float4 av[2]; uint4 au;
    if (BF16IN) {
        int gn = m0 + nbb;
        au = (gn < NN) ? *(const uint4*)(featu + (size_t)gn * 32 + 4 * kqb)
                       : make_uint4(0u, 0u, 0u, 0u);
    } else {
        #pragma unroll
        for (int rep = 0; rep < 2; ++rep) {
            int gn = m0 + nbf + 32 * rep;
            av[rep] = (gn < NN)
                ? *(const float4*)(featf + (size_t)gn * 64 + k0f)
                : make_float4(0.f, 0.f, 0.f, 0.f);
        }
    }

    #pragma unroll
    for (int i = 0; i < 4; ++i) {
        int jl = half + 2 * i;
        Bs[4 * jl + 0][cw] = bv[i].x; Bs[4 * jl + 1][cw] = bv[i].y;
        Bs[4 * jl + 2][cw] = bv[i].z; Bs[4 * jl + 3][cw] = bv[i].w;
    }
    if (BF16IN) {
        int kk = 8 * kqb;
        As[kk + 0][nbb] = u2f(au.x << 16); As[kk + 1][nbb] = u2f(au.x & 0xFFFF0000u);
        As[kk + 2][nbb] = u2f(au.y << 16); As[kk + 3][nbb] = u2f(au.y & 0xFFFF0000u);
        As[kk + 4][nbb] = u2f(au.z << 16); As[kk + 5][nbb] = u2f(au.z & 0xFFFF0000u);
        As[kk + 6][nbb] = u2f(au.w << 16); As[kk + 7][nbb] = u2f(au.w & 0xFFFF0000u);
    } else {
        #pragma unroll
        for (int rep = 0; rep < 2; ++rep) {
            int n = nbf + 32 * rep;
            As[k0f + 0][n] = av[rep].x; As[k0f + 1][n] = av[rep].y;
            As[k0f + 2][n] = av[rep].z; As[k0f + 3][n] = av[rep].w;
        }
    }
    __syncthreads();

    // ================= issue phase-1 loads (hide under compute) =========
    float4 bv1[4];
    #pragma unroll
    for (int i = 0; i < 4; ++i)
        bv1[i] = *(const float4*)(Wsrc + 4 * (8 + half + 2 * i));
    float4 av1[2]; uint4 au1;
    if (BF16IN) {
        int gn = m0 + nbb;
        au1 = (gn < NN) ? *(const uint4*)(featu + (size_t)gn * 32 + 16 + 4 * kqb)
                        : make_uint4(0u, 0u, 0u, 0u);
    } else {
        #pragma unroll
        for (int rep = 0; rep < 2; ++rep) {
            int gn = m0 + nbf + 32 * rep;
            av1[rep] = (gn < NN)
                ? *(const float4*)(featf + (size_t)gn * 64 + 32 + k0f)
                : make_float4(0.f, 0.f, 0.f, 0.f);
        }
    }

    // ================= compute phase 0 =================
    #pragma unroll 16
    for (int k = 0; k < 32; ++k) {
        float4 a0 = *(const float4*)&As[k][8 * tn];
        float4 a1 = *(const float4*)&As[k][8 * tn + 4];
        float4 b  = *(const float4*)&Bs[k][c0];
        float avv[8] = {a0.x, a0.y, a0.z, a0.w, a1.x, a1.y, a1.z, a1.w};
        float bvv[4] = {b.x, b.y, b.z, b.w};
        #pragma unroll
        for (int i = 0; i < 8; ++i)
            #pragma unroll
            for (int j = 0; j < 4; ++j)
                acc[i][j] = fmaf(avv[i], bvv[j], acc[i][j]);
    }
    __syncthreads();

    // ================= write phase 1 to LDS =================
    #pragma unroll
    for (int i = 0; i < 4; ++i) {
        int jl = half + 2 * i;
        Bs[4 * jl + 0][cw] = bv1[i].x; Bs[4 * jl + 1][cw] = bv1[i].y;
        Bs[4 * jl + 2][cw] = bv1[i].z; Bs[4 * jl + 3][cw] = bv1[i].w;
    }
    if (BF16IN) {
        int kk = 8 * kqb;
        As[kk + 0][nbb] = u2f(au1.x << 16); As[kk + 1][nbb] = u2f(au1.x & 0xFFFF0000u);
        As[kk + 2][nbb] = u2f(au1.y << 16); As[kk + 3][nbb] = u2f(au1.y & 0xFFFF0000u);
        As[kk + 4][nbb] = u2f(au1.z << 16); As[kk + 5][nbb] = u2f(au1.z & 0xFFFF0000u);
        As[kk + 6][nbb] = u2f(au1.w << 16); As[kk + 7][nbb] = u2f(au1.w & 0xFFFF0000u);
    } else {
        #pragma unroll
        for (int rep = 0; rep < 2; ++rep) {
            int n = nbf + 32 * rep;
            As[k0f + 0][n] = av1[rep].x; As[k0f + 1][n] = av1[rep].y;
            As[k0f + 2][n] = av1[rep].z; As[k0f + 3][n] = av1[rep].w;
        }
    }
    __syncthreads();

    // ================= compute phase 1 =================
    #pragma unroll 16
    for (int k = 0; k < 32; ++k) {
        float4 a0 = *(const float4*)&As[k][8 * tn];
        float4 a1 = *(const float4*)&As[k][8 * tn + 4];
        float4 b  = *(const float4*)&Bs[k][c0];
        float avv[8] = {a0.x, a0.y, a0.z, a0.w, a1.x, a1.y, a1.z, a1.w};
        float bvv[4] = {b.x, b.y, b.z, b.w};
        #pragma unroll
        for (int i = 0; i < 8; ++i)
            #pragma unroll
            for (int j = 0; j < 4; ++j)
                acc[i][j] = fmaf(avv[i], bvv[j], acc[i][j]);
    }

    // ---- epilogue: pack bf16, both halves ----
    unsigned* dst = (c0 < 64) ? outt : outr;
    const int cc = (c0 < 64) ? c0 : c0 - 64;
    #pragma unroll
    for (int i = 0; i < 8; ++i) {
        int gn = m0 + 8 * tn + i;
        if (gn < NN) {
            uint2 p;
            p.x = f2bf(acc[i][0]) | (f2bf(acc[i][1]) << 16);
            p.y = f2bf(acc[i][2]) | (f2bf(acc[i][3]) << 16);
            *(uint2*)(dst + (size_t)gn * 32 + (cc >> 1)) = p;
        }
    }
}

// ---------------------------------------------------------------------------
// Gather-mean (bf16 table) + epilogue: rh(bf16) <- relu(mean + rh).
// 2 nodes per wave; lane = half(1) x slot(2) x c8(3); 2-deep pipeline.
__global__ void aggregate_relu_kernel(const int* __restrict__ rowptr,
                                      const int* __restrict__ colb,
                                      const unsigned* __restrict__ tt,  // (NN+1) x 32
                                      unsigned* rh) {                   // NN x 32
    const int wv   = (blockIdx.x * blockDim.x + threadIdx.x) >> 6;
    const int lane = threadIdx.x & 63;
    const int half = lane >> 5;
    const int slot = (lane >> 3) & 3;
    const int c8   = lane & 7;
    const int node = 2 * wv + half;
    if (node >= NN) return;

    const int beg = rowptr[node], end = rowptr[node + 1];
    const int deg = end - beg;
    int niter = (deg + 3) >> 2;
    niter = max(niter, __shfl_xor(niter, 32));   // wave-uniform

    const char* tb = (const char*)tt;
    const int zoff = NN * 128;                   // zero row (byte offset)
    v2f a0 = {0.f, 0.f}, a1 = {0.f, 0.f}, a2 = {0.f, 0.f}, a3 = {0.f, 0.f};
    v2f b0 = {0.f, 0.f}, b1 = {0.f, 0.f}, b2 = {0.f, 0.f}, b3 = {0.f, 0.f};

    int jj = beg + slot;
    int it = 0;
    for (; it + 2 <= niter; it += 2, jj += 8) {
        int jc0 = min(jj, end - 1);
        int jc1 = min(jj + 4, end - 1);
        int o0 = colb[jc0];
        int o1 = colb[jc1];
        o0 = (jj < end) ? o0 : zoff;
        o1 = (jj + 4 < end) ? o1 : zoff;
        uint4 u0 = *(const uint4*)(tb + (size_t)(unsigned)o0 + 16 * c8);
        uint4 u1 = *(const uint4*)(tb + (size_t)(unsigned)o1 + 16 * c8);
        a0 += unpk(u0.x); a1 += unpk(u0.y); a2 += unpk(u0.z); a3 += unpk(u0.w);
        b0 += unpk(u1.x); b1 += unpk(u1.y); b2 += unpk(u1.z); b3 += unpk(u1.w);
    }
    if (it < niter) {
        int jc0 = min(jj, end - 1);
        int o0 = colb[jc0];
        o0 = (jj < end) ? o0 : zoff;
        uint4 u0 = *(const uint4*)(tb + (size_t)(unsigned)o0 + 16 * c8);
        a0 += unpk(u0.x); a1 += unpk(u0.y); a2 += unpk(u0.z); a3 += unpk(u0.w);
    }
    a0 += b0; a1 += b1; a2 += b2; a3 += b3;

    a0[0] += __shfl_xor(a0[0], 8);  a0[1] += __shfl_xor(a0[1], 8);
    a1[0] += __shfl_xor(a1[0], 8);  a1[1] += __shfl_xor(a1[1], 8);
    a2[0] += __shfl_xor(a2[0], 8);  a2[1] += __shfl_xor(a2[1], 8);
    a3[0] += __shfl_xor(a3[0], 8);  a3[1] += __shfl_xor(a3[1], 8);
    a0[0] += __shfl_xor(a0[0], 16); a0[1] += __shfl_xor(a0[1], 16);
    a1[0] += __shfl_xor(a1[0], 16); a1[1] += __shfl_xor(a1[1], 16);
    a2[0] += __shfl_xor(a2[0], 16); a2[1] += __shfl_xor(a2[1], 16);
    a3[0] += __shfl_xor(a3[0], 16); a3[1] += __shfl_xor(a3[1], 16);

    if (slot == 0) {
        float inv = 1.0f / fmaxf((float)deg, 1.0f);
        unsigned* p = rh + (size_t)node * 32 + 4 * c8;
        uint4 rr = *(const uint4*)p;
        v2f q0 = unpk(rr.x), q1 = unpk(rr.y), q2 = unpk(rr.z), q3 = unpk(rr.w);
        float h0 = fmaxf(fmaf(a0[0], inv, q0[0]), 0.0f);
        float h1 = fmaxf(fmaf(a0[1], inv, q0[1]), 0.0f);
        float h2 = fmaxf(fmaf(a1[0], inv, q1[0]), 0.0f);
        float h3 = fmaxf(fmaf(a1[1], inv, q1[1]), 0.0f);
        float h4 = fmaxf(fmaf(a2[0], inv, q2[0]), 0.0f);
        float h5 = fmaxf(fmaf(a2[1], inv, q2[1]), 0.0f);
        float h6 = fmaxf(fmaf(a3[0], inv, q3[0]), 0.0f);
        float h7 = fmaxf(fmaf(a3[1], inv, q3[1]), 0.0f);
        uint4 wv4;
        wv4.x = f2bf(h0) | (f2bf(h1) << 16);
        wv4.y = f2bf(h2) | (f2bf(h3) << 16);
        wv4.z = f2bf(h4) | (f2bf(h5) << 16);
        wv4.w = f2bf(h6) | (f2bf(h7) << 16);
        *(uint4*)p = wv4;
    }
}

// ---------------------------------------------------------------------------
// Head GEMM: out = h(bf16) @ Wlin.T + blin.
__global__ __launch_bounds__(256) void head_kernel(
    const unsigned* __restrict__ hu,      // NN x 32 bf16x2
    const float* __restrict__ Wlin,
    const float* __restrict__ blin,
    float* __restrict__ out)
{
    __shared__ float As[64][132];
    __shared__ float Bs[64][18];
    const int t = threadIdx.x;

    {
        int c = t & 15, j = t >> 4;
        float4 v = *(const float4*)(Wlin + (size_t)c * 64 + 4 * j);
        Bs[4 * j + 0][c] = v.x; Bs[4 * j + 1][c] = v.y;
        Bs[4 * j + 2][c] = v.z; Bs[4 * j + 3][c] = v.w;
    }
    const int m0 = blockIdx.x * 128;
    {
        int kq = t & 7;          // k = 8*kq .. 8*kq+7
        int nb = t >> 3;         // 0..31
        for (int rep = 0; rep < 4; ++rep) {
            int n = nb + 32 * rep;
            int gn = m0 + n;
            uint4 u = (gn < NN) ? *(const uint4*)(hu + (size_t)gn * 32 + 4 * kq)
                                : make_uint4(0u, 0u, 0u, 0u);
            int kk = 8 * kq;
            As[kk + 0][n] = u2f(u.x << 16); As[kk + 1][n] = u2f(u.x & 0xFFFF0000u);
            As[kk + 2][n] = u2f(u.y << 16); As[kk + 3][n] = u2f(u.y & 0xFFFF0000u);
            As[kk + 4][n] = u2f(u.z << 16); As[kk + 5][n] = u2f(u.z & 0xFFFF0000u);
            As[kk + 6][n] = u2f(u.w << 16); As[kk + 7][n] = u2f(u.w & 0xFFFF0000u);
        }
    }
    __syncthreads();

    const int tn = t & 31;
    const int tc = t >> 5;
    const int c0 = 2 * tc;
    float acc[4][2];
    #pragma unroll
    for (int i = 0; i < 4; ++i) { acc[i][0] = blin[c0]; acc[i][1] = blin[c0 + 1]; }

    #pragma unroll 16
    for (int k = 0; k < 64; ++k) {
        float4 a = *(const float4*)&As[k][4 * tn];
        float b0 = Bs[k][c0], b1 = Bs[k][c0 + 1];
        float av[4] = {a.x, a.y, a.z, a.w};
        #pragma unroll
        for (int i = 0; i < 4; ++i) {
            acc[i][0] = fmaf(av[i], b0, acc[i][0]);
            acc[i][1] = fmaf(av[i], b1, acc[i][1]);
        }
    }
    #pragma unroll
    for (int i = 0; i < 4; ++i) {
        int gn = m0 + 4 * tn + i;
        if (gn < NN)
            *(float2*)(out + (size_t)gn * 16 + c0) = make_float2(acc[i][0], acc[i][1]);
    }
}

// ---------------------------------------------------------------------------
extern "C" void kernel_launch(void* const* d_in, const int* in_sizes, int n_in,
                              void* d_out, int out_size, void* d_ws, size_t ws_size,
                              hipStream_t stream) {
    const float* x    = (const float*)d_in[0];
    const void*  ei   = d_in[1];
    const float* W1l  = (const float*)d_in[2];
    const float* b1   = (const float*)d_in[3];
    const float* W1r  = (const float*)d_in[4];
    const float* W2l  = (const float*)d_in[5];
    const float* b2   = (const float*)d_in[6];
    const float* W2r  = (const float*)d_in[7];
    const float* Wlin = (const float*)d_in[8];
    const float* blin = (const float*)d_in[9];
    float* out = (float*)d_out;

    char* w = (char*)d_ws;
    int*      flag   = (int*)w;                                // @ 0
    int*      bcnt   = (int*)(w + (size_t)4 * 1024);           // @ 4K
    int*      bbase  = (int*)(w + (size_t)8 * 1024);           // @ 8K
    int*      rowptr = (int*)(w + (size_t)1024 * 1024);        // @ 1M
    int*      colb   = (int*)(w + (size_t)2 * 1024 * 1024);    // @ 2M  (6.4 MB)
    int2*     bpairs = (int2*)(w + (size_t)10 * 1024 * 1024);  // @ 10M (19.3 MB, dead after B3)
    unsigned* T      = (unsigned*)(w + (size_t)10 * 1024 * 1024); // @ 10M (12.8 MB + row, aliases bpairs)
    unsigned* R      = (unsigned*)(w + (size_t)36 * 1024 * 1024); // @ 36M (12.8 MB bf16 r/h)

    // ---- bucketed CSR build (detect also zeroes bcnt) ----
    detect_mode_kernel<<<1, 256, 0, stream>>>((const int*)ei, flag, bcnt);
    bucket_scatter_kernel<<<B1_BLOCKS, 256, 0, stream>>>(ei, flag, bcnt, bpairs);
    bucket_prefix_kernel<<<1, 256, 0, stream>>>(bcnt, bbase, rowptr);
    bucket_to_csr_kernel<<<NBUCK, 256, 0, stream>>>(bcnt, bbase, bpairs, rowptr, colb);

    const int gemmBlocks = (NN + 63) / 64;
    const int aggWaves   = (NN + 1) / 2;                      // 2 nodes per wave
    const int aggBlocks  = (aggWaves * 64 + 255) / 256;
    const int headBlocks = (NN + 127) / 128;

    // ---- layer 1 (gemm block 0 zeroes table row NN; bpairs dead by now) ----
    gemm_tr_kernel<0><<<gemmBlocks, 256, 0, stream>>>(x, W1l, W1r, b1, T, R);
    aggregate_relu_kernel<<<aggBlocks, 256, 0, stream>>>(rowptr, colb, T, R); // h1 in R

    // ---- layer 2 (reads R bf16, in-place safe per-tile) ----
    gemm_tr_kernel<1><<<gemmBlocks, 256, 0, stream>>>(R, W2l, W2r, b2, T, R);
    aggregate_relu_kernel<<<aggBlocks, 256, 0, stream>>>(rowptr, colb, T, R); // h2 in R

    // ---- output head ----
    head_kernel<<<headBlocks, 256, 0, stream>>>(R, Wlin, blin, out);
}

// Round 12
// 162.970 us; speedup vs baseline: 18.6791x; 1.1600x over previous
//
#include <hip/hip_runtime.h>

#define NN 100000
#define NE 1600000
// IN_CH = HID = 64, OUT_CH = 16

// ---- bucketed CSR build geometry ----
#define BSHIFT 9
#define BWIDTH (1 << BSHIFT)                     // 512 nodes per bucket
#define NBUCK ((NN + BWIDTH - 1) >> BSHIFT)      // 196
#define SLOTS 12288                              // capacity per bucket (mean 8163)
#define CHUNK 4096                               // edges per B1 block
#define B1_BLOCKS ((NE + CHUNK - 1) / CHUNK)     // 391
#define GEMM_BLOCKS ((NN + 63) / 64)             // 1563

typedef float    v2f __attribute__((ext_vector_type(2)));
typedef unsigned v2u __attribute__((ext_vector_type(2)));

// ---- bf16 helpers (RNE pack, exact unpack) ----
__device__ __forceinline__ float u2f(unsigned u) {
    union { unsigned u; float f; } v; v.u = u; return v.f;
}
__device__ __forceinline__ unsigned f2u(float f) {
    union { float f; unsigned u; } v; v.f = f; return v.u;
}
__device__ __forceinline__ unsigned f2bf(float f) {   // returns bf16 in low 16
    unsigned u = f2u(f);
    return (u + 0x7FFFu + ((u >> 16) & 1u)) >> 16;
}
__device__ __forceinline__ v2f unpk(unsigned x) {
    v2u w; w[0] = x << 16; w[1] = x & 0xFFFF0000u;
    union { v2u u; v2f f; } c; c.u = w; return c.f;
}

// ---------------------------------------------------------------------------
// Detect int64 vs int32 edge_index; also zeroes bcnt (replaces a memset).
__global__ void detect_mode_kernel(const int* ei32, int* flag, int* bcnt) {
    __shared__ int any_nonzero;
    if (threadIdx.x == 0) any_nonzero = 0;
    if (threadIdx.x < NBUCK) bcnt[threadIdx.x] = 0;
    __syncthreads();
    int idx = 1 + 2 * threadIdx.x;
    if (ei32[idx] != 0) atomicOr(&any_nonzero, 1);
    __syncthreads();
    if (threadIdx.x == 0) flag[0] = (any_nonzero == 0) ? 1 : 0;  // 1 => int64
}

__device__ __forceinline__ void load_edge(const void* ei, int is64, int e,
                                          int& s, int& d) {
    if (is64) {
        const long long* p = (const long long*)ei;
        s = (int)p[e];
        d = (int)p[NE + e];
    } else {
        const int* p = (const int*)ei;
        s = p[e];
        d = p[NE + e];
    }
}

// ---------------------------------------------------------------------------
// B1: bucket the edges (LDS histogram + reorder + coalesced flush).
__global__ __launch_bounds__(256) void bucket_scatter_kernel(
    const void* ei, const int* flag,
    int* __restrict__ bcnt, int2* __restrict__ bpairs)
{
    __shared__ int hist[NBUCK];
    __shared__ int scanb[NBUCK];
    __shared__ int gbase[NBUCK];
    __shared__ int lofs[NBUCK];
    __shared__ int sc[256];
    __shared__ int2 stage[CHUNK];
    __shared__ unsigned short sbuck[CHUNK];

    const int t = threadIdx.x;
    const int is64 = *flag;
    const int e0 = blockIdx.x * CHUNK;
    const int nE = min(CHUNK, NE - e0);

    for (int i = t; i < NBUCK; i += 256) { hist[i] = 0; lofs[i] = 0; }
    __syncthreads();

    int sr[16], dr[16];
    #pragma unroll
    for (int r = 0; r < 16; ++r) {
        int e = e0 + t + 256 * r;
        if (e < NE) load_edge(ei, is64, e, sr[r], dr[r]);
        else dr[r] = -1;
    }
    #pragma unroll
    for (int r = 0; r < 16; ++r)
        if (dr[r] >= 0) atomicAdd(&hist[dr[r] >> BSHIFT], 1);
    __syncthreads();

    int v = (t < NBUCK) ? hist[t] : 0;
    sc[t] = v;
    __syncthreads();
    for (int off = 1; off < 256; off <<= 1) {
        int u = (t >= off) ? sc[t - off] : 0;
        __syncthreads();
        sc[t] += u;
        __syncthreads();
    }
    if (t < NBUCK) {
        scanb[t] = sc[t] - v;
        gbase[t] = atomicAdd(&bcnt[t], v);
    }
    __syncthreads();

    #pragma unroll
    for (int r = 0; r < 16; ++r) {
        if (dr[r] >= 0) {
            int b = dr[r] >> BSHIFT;
            int p = scanb[b] + atomicAdd(&lofs[b], 1);
            stage[p] = make_int2(sr[r], dr[r]);
            sbuck[p] = (unsigned short)b;
        }
    }
    __syncthreads();

    for (int i = t; i < nE; i += 256) {
        int b = sbuck[i];
        int off = gbase[b] + (i - scanb[b]);
        if (off < SLOTS) bpairs[(size_t)b * SLOTS + off] = stage[i];
    }
}

// ---------------------------------------------------------------------------
// GEMM body: t (bf16) = feat @ Wl.T ; r (bf16, bias folded) = feat @ Wr.T.
// tile = 64n x 128c, thread = 8n x 4c, K in two 32-phases with register
// prefetch of phase 1 (HBM latency hidden under phase-0 compute).
// Uses 25600 B of provided shared memory.
template<int BF16IN>
__device__ __forceinline__ void gemm_body(
    char* smem,
    const void* __restrict__ featv,
    const float* __restrict__ Wl, const float* __restrict__ Wr,
    const float* __restrict__ bias,
    unsigned* __restrict__ outt, unsigned* __restrict__ outr,
    int tile, int t)
{
    float (*As)[68]  = (float(*)[68])smem;                 // 8704 B
    float (*Bs)[132] = (float(*)[132])(smem + 32 * 68 * 4); // 16896 B
    const int m0 = tile * 64;

    const int tn = t & 7;
    const int tc = t >> 3;
    const int c0 = 4 * tc;

    float acc[8][4];
    {
        float b0 = 0.f, b1 = 0.f, b2 = 0.f, b3 = 0.f;
        if (c0 >= 64) {
            b0 = bias[c0 - 64]; b1 = bias[c0 - 63];
            b2 = bias[c0 - 62]; b3 = bias[c0 - 61];
        }
        #pragma unroll
        for (int i = 0; i < 8; ++i) {
            acc[i][0] = b0; acc[i][1] = b1; acc[i][2] = b2; acc[i][3] = b3;
        }
    }

    const int cw   = t & 127;
    const int half = t >> 7;
    const float* Wsrc = (cw < 64) ? (Wl + (size_t)cw * 64)
                                  : (Wr + (size_t)(cw - 64) * 64);
    const float*    featf = (const float*)featv;
    const unsigned* featu = (const unsigned*)featv;
    const int k0f = 4 * (t & 7);
    const int nbf = t >> 3;
    const int kqb = t & 3;
    const int nbb = t >> 2;

    // ---- phase 0 load -> LDS ----
    float4 bv[4];
    #pragma unroll
    for (int i = 0; i < 4; ++i)
        bv[i] = *(const float4*)(Wsrc + 4 * (half + 2 * i));
    float4 av[2]; uint4 au;
    if (BF16IN) {
        int gn = m0 + nbb;
        au = (gn < NN) ? *(const uint4*)(featu + (size_t)gn * 32 + 4 * kqb)
                       : make_uint4(0u, 0u, 0u, 0u);
    } else {
        #pragma unroll
        for (int rep = 0; rep < 2; ++rep) {
            int gn = m0 + nbf + 32 * rep;
            av[rep] = (gn < NN)
                ? *(const float4*)(featf + (size_t)gn * 64 + k0f)
                : make_float4(0.f, 0.f, 0.f, 0.f);
        }
    }
    #pragma unroll
    for (int i = 0; i < 4; ++i) {
        int jl = half + 2 * i;
        Bs[4 * jl + 0][cw] = bv[i].x; Bs[4 * jl + 1][cw] = bv[i].y;
        Bs[4 * jl + 2][cw] = bv[i].z; Bs[4 * jl + 3][cw] = bv[i].w;
    }
    if (BF16IN) {
        int kk = 8 * kqb;
        As[kk + 0][nbb] = u2f(au.x << 16); As[kk + 1][nbb] = u2f(au.x & 0xFFFF0000u);
        As[kk + 2][nbb] = u2f(au.y << 16); As[kk + 3][nbb] = u2f(au.y & 0xFFFF0000u);
        As[kk + 4][nbb] = u2f(au.z << 16); As[kk + 5][nbb] = u2f(au.z & 0xFFFF0000u);
        As[kk + 6][nbb] = u2f(au.w << 16); As[kk + 7][nbb] = u2f(au.w & 0xFFFF0000u);
    } else {
        #pragma unroll
        for (int rep = 0; rep < 2; ++rep) {
            int n = nbf + 32 * rep;
            As[k0f + 0][n] = av[rep].x; As[k0f + 1][n] = av[rep].y;
            As[k0f + 2][n] = av[rep].z; As[k0f + 3][n] = av[rep].w;
        }
    }
    __syncthreads();

    // ---- issue phase-1 loads ----
    float4 bv1[4];
    #pragma unroll
    for (int i = 0; i < 4; ++i)
        bv1[i] = *(const float4*)(Wsrc + 4 * (8 + half + 2 * i));
    float4 av1[2]; uint4 au1;
    if (BF16IN) {
        int gn = m0 + nbb;
        au1 = (gn < NN) ? *(const uint4*)(featu + (size_t)gn * 32 + 16 + 4 * kqb)
                        : make_uint4(0u, 0u, 0u, 0u);
    } else {
        #pragma unroll
        for (int rep = 0; rep < 2; ++rep) {
            int gn = m0 + nbf + 32 * rep;
            av1[rep] = (gn < NN)
                ? *(const float4*)(featf + (size_t)gn * 64 + 32 + k0f)
                : make_float4(0.f, 0.f, 0.f, 0.f);
        }
    }

    // ---- compute phase 0 ----
    #pragma unroll 16
    for (int k = 0; k < 32; ++k) {
        float4 a0 = *(const float4*)&As[k][8 * tn];
        float4 a1 = *(const float4*)&As[k][8 * tn + 4];
        float4 b  = *(const float4*)&Bs[k][c0];
        float avv[8] = {a0.x, a0.y, a0.z, a0.w, a1.x, a1.y, a1.z, a1.w};
        float bvv[4] = {b.x, b.y, b.z, b.w};
        #pragma unroll
        for (int i = 0; i < 8; ++i)
            #pragma unroll
            for (int j = 0; j < 4; ++j)
                acc[i][j] = fmaf(avv[i], bvv[j], acc[i][j]);
    }
    __syncthreads();

    // ---- write phase 1 to LDS ----
    #pragma unroll
    for (int i = 0; i < 4; ++i) {
        int jl = half + 2 * i;
        Bs[4 * jl + 0][cw] = bv1[i].x; Bs[4 * jl + 1][cw] = bv1[i].y;
        Bs[4 * jl + 2][cw] = bv1[i].z; Bs[4 * jl + 3][cw] = bv1[i].w;
    }
    if (BF16IN) {
        int kk = 8 * kqb;
        As[kk + 0][nbb] = u2f(au1.x << 16); As[kk + 1][nbb] = u2f(au1.x & 0xFFFF0000u);
        As[kk + 2][nbb] = u2f(au1.y << 16); As[kk + 3][nbb] = u2f(au1.y & 0xFFFF0000u);
        As[kk + 4][nbb] = u2f(au1.z << 16); As[kk + 5][nbb] = u2f(au1.z & 0xFFFF0000u);
        As[kk + 6][nbb] = u2f(au1.w << 16); As[kk + 7][nbb] = u2f(au1.w & 0xFFFF0000u);
    } else {
        #pragma unroll
        for (int rep = 0; rep < 2; ++rep) {
            int n = nbf + 32 * rep;
            As[k0f + 0][n] = av1[rep].x; As[k0f + 1][n] = av1[rep].y;
            As[k0f + 2][n] = av1[rep].z; As[k0f + 3][n] = av1[rep].w;
        }
    }
    __syncthreads();

    // ---- compute phase 1 ----
    #pragma unroll 16
    for (int k = 0; k < 32; ++k) {
        float4 a0 = *(const float4*)&As[k][8 * tn];
        float4 a1 = *(const float4*)&As[k][8 * tn + 4];
        float4 b  = *(const float4*)&Bs[k][c0];
        float avv[8] = {a0.x, a0.y, a0.z, a0.w, a1.x, a1.y, a1.z, a1.w};
        float bvv[4] = {b.x, b.y, b.z, b.w};
        #pragma unroll
        for (int i = 0; i < 8; ++i)
            #pragma unroll
            for (int j = 0; j < 4; ++j)
                acc[i][j] = fmaf(avv[i], bvv[j], acc[i][j]);
    }

    // ---- epilogue: pack bf16 ----
    unsigned* dst = (c0 < 64) ? outt : outr;
    const int cc = (c0 < 64) ? c0 : c0 - 64;
    #pragma unroll
    for (int i = 0; i < 8; ++i) {
        int gn = m0 + 8 * tn + i;
        if (gn < NN) {
            uint2 p;
            p.x = f2bf(acc[i][0]) | (f2bf(acc[i][1]) << 16);
            p.y = f2bf(acc[i][2]) | (f2bf(acc[i][3]) << 16);
            *(uint2*)(dst + (size_t)gn * 32 + (cc >> 1)) = p;
        }
    }
}

// ---------------------------------------------------------------------------
// FUSED kernel: blocks 0..NBUCK-1 run B3 (bucket -> rowptr+colb, with the
// bucket prefix computed in-block, replacing the old B2 launch); blocks
// NBUCK.. run gemm1 (layer-1 transform). B3 and gemm1 are independent; the
// fusion overlaps B3's latency-bound work under gemm1's compute and removes
// two launch gaps. T no longer aliases bpairs (both live here).
__global__ __launch_bounds__(256) void csr_gemm1_kernel(
    const int* __restrict__ bcnt, const int2* __restrict__ bpairs,
    int* __restrict__ rowptr, int* __restrict__ colb,
    const float* __restrict__ x,
    const float* __restrict__ W1l, const float* __restrict__ W1r,
    const float* __restrict__ b1,
    unsigned* __restrict__ T, unsigned* __restrict__ R)
{
    __shared__ __align__(16) char smem[25600];
    const int t = threadIdx.x;

    if (blockIdx.x >= NBUCK) {
        // ---------------- gemm1 part ----------------
        if (blockIdx.x == NBUCK && t < 32) T[(size_t)NN * 32 + t] = 0u; // zero row
        gemm_body<0>(smem, x, W1l, W1r, b1, T, R, blockIdx.x - NBUCK, t);
        return;
    }

    // ---------------- B3 part (with self-prefix) ----------------
    int* ldeg = (int*)smem;          // 512
    int* lptr = ldeg + 512;          // 512
    int* lcnt = lptr + 512;          // 512
    int* sc   = lcnt + 512;          // 256

    const int b = blockIdx.x;

    // bucket prefix: exclusive sum of bcnt[0..b-1]
    int v = (t < NBUCK) ? bcnt[t] : 0;
    sc[t] = v;
    __syncthreads();
    for (int off = 1; off < 256; off <<= 1) {
        int u = (t >= off) ? sc[t - off] : 0;
        __syncthreads();
        sc[t] += u;
        __syncthreads();
    }
    const int base = (b == 0) ? 0 : sc[b - 1];
    if (b == 0 && t == 0) rowptr[NN] = NE;

    const int n0 = b << BSHIFT;
    const int cnt = min(bcnt[b], SLOTS);
    const int2* src = bpairs + (size_t)b * SLOTS;

    for (int i = t; i < BWIDTH; i += 256) { ldeg[i] = 0; lcnt[i] = 0; }
    __syncthreads();

    for (int i = t; i < cnt; i += 256)
        atomicAdd(&ldeg[src[i].y - n0], 1);
    __syncthreads();

    int a0 = ldeg[2 * t], a1 = ldeg[2 * t + 1];
    int s = a0 + a1;
    sc[t] = s;
    __syncthreads();
    for (int off = 1; off < 256; off <<= 1) {
        int u = (t >= off) ? sc[t - off] : 0;
        __syncthreads();
        sc[t] += u;
        __syncthreads();
    }
    int exc = sc[t] - s;
    lptr[2 * t] = exc;
    lptr[2 * t + 1] = exc + a0;
    __syncthreads();

    for (int i = t; i < BWIDTH; i += 256) {
        int gn = n0 + i;
        if (gn < NN) rowptr[gn] = base + lptr[i];
    }

    for (int i = t; i < cnt; i += 256) {
        int2 p = src[i];
        int li = p.y - n0;
        int pos = lptr[li] + atomicAdd(&lcnt[li], 1);
        colb[base + pos] = p.x << 7;   // byte offset into bf16 table
    }
}

// ---------------------------------------------------------------------------
// Standalone layer-2 GEMM (bf16 input features).
__global__ __launch_bounds__(256) void gemm2_kernel(
    const unsigned* __restrict__ feat,
    const float* __restrict__ Wl, const float* __restrict__ Wr,
    const float* __restrict__ bias,
    unsigned* __restrict__ outt, unsigned* __restrict__ outr)
{
    __shared__ __align__(16) char smem[25600];
    gemm_body<1>(smem, feat, Wl, Wr, bias, outt, outr, blockIdx.x, threadIdx.x);
}

// ---------------------------------------------------------------------------
// Gather-mean (bf16 table) + epilogue: rh(bf16) <- relu(mean + rh).
// 2 nodes per wave; lane = half(1) x slot(2) x c8(3); 4-deep pipeline
// (4 independent gathers in flight, 2 accumulator banks).
__global__ void aggregate_relu_kernel(const int* __restrict__ rowptr,
                                      const int* __restrict__ colb,
                                      const unsigned* __restrict__ tt,  // (NN+1) x 32
                                      unsigned* rh) {                   // NN x 32
    const int wv   = (blockIdx.x * blockDim.x + threadIdx.x) >> 6;
    const int lane = threadIdx.x & 63;
    const int half = lane >> 5;
    const int slot = (lane >> 3) & 3;
    const int c8   = lane & 7;
    const int node = 2 * wv + half;
    if (node >= NN) return;

    const int beg = rowptr[node], end = rowptr[node + 1];
    const int deg = end - beg;
    int niter = (deg + 3) >> 2;
    niter = max(niter, __shfl_xor(niter, 32));   // wave-uniform

    const char* tb = (const char*)tt;
    const int zoff = NN * 128;                   // zero row (byte offset)
    v2f a0 = {0.f, 0.f}, a1 = {0.f, 0.f}, a2 = {0.f, 0.f}, a3 = {0.f, 0.f};
    v2f b0 = {0.f, 0.f}, b1 = {0.f, 0.f}, b2 = {0.f, 0.f}, b3 = {0.f, 0.f};

    int jj = beg + slot;
    int it = 0;
    for (; it + 4 <= niter; it += 4, jj += 16) {
        int jc0 = min(jj,      end - 1);
        int jc1 = min(jj + 4,  end - 1);
        int jc2 = min(jj + 8,  end - 1);
        int jc3 = min(jj + 12, end - 1);
        int o0 = colb[jc0];
        int o1 = colb[jc1];
        int o2 = colb[jc2];
        int o3 = colb[jc3];
        o0 = (jj      < end) ? o0 : zoff;
        o1 = (jj + 4  < end) ? o1 : zoff;
        o2 = (jj + 8  < end) ? o2 : zoff;
        o3 = (jj + 12 < end) ? o3 : zoff;
        uint4 u0 = *(const uint4*)(tb + (size_t)(unsigned)o0 + 16 * c8);
        uint4 u1 = *(const uint4*)(tb + (size_t)(unsigned)o1 + 16 * c8);
        uint4 u2 = *(const uint4*)(tb + (size_t)(unsigned)o2 + 16 * c8);
        uint4 u3 = *(const uint4*)(tb + (size_t)(unsigned)o3 + 16 * c8);
        a0 += unpk(u0.x); a1 += unpk(u0.y); a2 += unpk(u0.z); a3 += unpk(u0.w);
        b0 += unpk(u1.x); b1 += unpk(u1.y); b2 += unpk(u1.z); b3 += unpk(u1.w);
        a0 += unpk(u2.x); a1 += unpk(u2.y); a2 += unpk(u2.z); a3 += unpk(u2.w);
        b0 += unpk(u3.x); b1 += unpk(u3.y); b2 += unpk(u3.z); b3 += unpk(u3.w);
    }
    for (; it < niter; ++it, jj += 4) {
        int jc0 = min(jj, end - 1);
        int o0 = colb[jc0];
        o0 = (jj < end) ? o0 : zoff;
        uint4 u0 = *(const uint4*)(tb + (size_t)(unsigned)o0 + 16 * c8);
        a0 += unpk(u0.x); a1 += unpk(u0.y); a2 += unpk(u0.z); a3 += unpk(u0.w);
    }
    a0 += b0; a1 += b1; a2 += b2; a3 += b3;

    a0[0] += __shfl_xor(a0[0], 8);  a0[1] += __shfl_xor(a0[1], 8);
    a1[0] += __shfl_xor(a1[0], 8);  a1[1] += __shfl_xor(a1[1], 8);
    a2[0] += __shfl_xor(a2[0], 8);  a2[1] += __shfl_xor(a2[1], 8);
    a3[0] += __shfl_xor(a3[0], 8);  a3[1] += __shfl_xor(a3[1], 8);
    a0[0] += __shfl_xor(a0[0], 16); a0[1] += __shfl_xor(a0[1], 16);
    a1[0] += __shfl_xor(a1[0], 16); a1[1] += __shfl_xor(a1[1], 16);
    a2[0] += __shfl_xor(a2[0], 16); a2[1] += __shfl_xor(a2[1], 16);
    a3[0] += __shfl_xor(a3[0], 16); a3[1] += __shfl_xor(a3[1], 16);

    if (slot == 0) {
        float inv = 1.0f / fmaxf((float)deg, 1.0f);
        unsigned* p = rh + (size_t)node * 32 + 4 * c8;
        uint4 rr = *(const uint4*)p;
        v2f q0 = unpk(rr.x), q1 = unpk(rr.y), q2 = unpk(rr.z), q3 = unpk(rr.w);
        float h0 = fmaxf(fmaf(a0[0], inv, q0[0]), 0.0f);
        float h1 = fmaxf(fmaf(a0[1], inv, q0[1]), 0.0f);
        float h2 = fmaxf(fmaf(a1[0], inv, q1[0]), 0.0f);
        float h3 = fmaxf(fmaf(a1[1], inv, q1[1]), 0.0f);
        float h4 = fmaxf(fmaf(a2[0], inv, q2[0]), 0.0f);
        float h5 = fmaxf(fmaf(a2[1], inv, q2[1]), 0.0f);
        float h6 = fmaxf(fmaf(a3[0], inv, q3[0]), 0.0f);
        float h7 = fmaxf(fmaf(a3[1], inv, q3[1]), 0.0f);
        uint4 wv4;
        wv4.x = f2bf(h0) | (f2bf(h1) << 16);
        wv4.y = f2bf(h2) | (f2bf(h3) << 16);
        wv4.z = f2bf(h4) | (f2bf(h5) << 16);
        wv4.w = f2bf(h6) | (f2bf(h7) << 16);
        *(uint4*)p = wv4;
    }
}

// ---------------------------------------------------------------------------
// Head GEMM: out = h(bf16) @ Wlin.T + blin.
__global__ __launch_bounds__(256) void head_kernel(
    const unsigned* __restrict__ hu,      // NN x 32 bf16x2
    const float* __restrict__ Wlin,
    const float* __restrict__ blin,
    float* __restrict__ out)
{
    __shared__ float As[64][132];
    __shared__ float Bs[64][18];
    const int t = threadIdx.x;

    {
        int c = t & 15, j = t >> 4;
        float4 v = *(const float4*)(Wlin + (size_t)c * 64 + 4 * j);
        Bs[4 * j + 0][c] = v.x; Bs[4 * j + 1][c] = v.y;
        Bs[4 * j + 2][c] = v.z; Bs[4 * j + 3][c] = v.w;
    }
    const int m0 = blockIdx.x * 128;
    {
        int kq = t & 7;          // k = 8*kq .. 8*kq+7
        int nb = t >> 3;         // 0..31
        for (int rep = 0; rep < 4; ++rep) {
            int n = nb + 32 * rep;
            int gn = m0 + n;
            uint4 u = (gn < NN) ? *(const uint4*)(hu + (size_t)gn * 32 + 4 * kq)
                                : make_uint4(0u, 0u, 0u, 0u);
            int kk = 8 * kq;
            As[kk + 0][n] = u2f(u.x << 16); As[kk + 1][n] = u2f(u.x & 0xFFFF0000u);
            As[kk + 2][n] = u2f(u.y << 16); As[kk + 3][n] = u2f(u.y & 0xFFFF0000u);
            As[kk + 4][n] = u2f(u.z << 16); As[kk + 5][n] = u2f(u.z & 0xFFFF0000u);
            As[kk + 6][n] = u2f(u.w << 16); As[kk + 7][n] = u2f(u.w & 0xFFFF0000u);
        }
    }
    __syncthreads();

    const int tn = t & 31;
    const int tc = t >> 5;
    const int c0 = 2 * tc;
    float acc[4][2];
    #pragma unroll
    for (int i = 0; i < 4; ++i) { acc[i][0] = blin[c0]; acc[i][1] = blin[c0 + 1]; }

    #pragma unroll 16
    for (int k = 0; k < 64; ++k) {
        float4 a = *(const float4*)&As[k][4 * tn];
        float b0 = Bs[k][c0], b1 = Bs[k][c0 + 1];
        float av[4] = {a.x, a.y, a.z, a.w};
        #pragma unroll
        for (int i = 0; i < 4; ++i) {
            acc[i][0] = fmaf(av[i], b0, acc[i][0]);
            acc[i][1] = fmaf(av[i], b1, acc[i][1]);
        }
    }
    #pragma unroll
    for (int i = 0; i < 4; ++i) {
        int gn = m0 + 4 * tn + i;
        if (gn < NN)
            *(float2*)(out + (size_t)gn * 16 + c0) = make_float2(acc[i][0], acc[i][1]);
    }
}

// ---------------------------------------------------------------------------
extern "C" void kernel_launch(void* const* d_in, const int* in_sizes, int n_in,
                              void* d_out, int out_size, void* d_ws, size_t ws_size,
                              hipStream_t stream) {
    const float* x    = (const float*)d_in[0];
    const void*  ei   = d_in[1];
    const float* W1l  = (const float*)d_in[2];
    const float* b1   = (const float*)d_in[3];
    const float* W1r  = (const float*)d_in[4];
    const float* W2l  = (const float*)d_in[5];
    const float* b2   = (const float*)d_in[6];
    const float* W2r  = (const float*)d_in[7];
    const float* Wlin = (const float*)d_in[8];
    const float* blin = (const float*)d_in[9];
    float* out = (float*)d_out;

    char* w = (char*)d_ws;
    int*      flag   = (int*)w;                                   // @ 0
    int*      bcnt   = (int*)(w + (size_t)4 * 1024);              // @ 4K
    int*      rowptr = (int*)(w + (size_t)1024 * 1024);           // @ 1M  (400 KB+4)
    int*      colb   = (int*)(w + (size_t)2 * 1024 * 1024);       // @ 2M  (6.4 MB)
    int2*     bpairs = (int2*)(w + (size_t)10 * 1024 * 1024);     // @ 10M (19.3 MB)
    unsigned* T      = (unsigned*)(w + (size_t)30 * 1024 * 1024); // @ 30M (12.8 MB + zero row)
    unsigned* R      = (unsigned*)(w + (size_t)43 * 1024 * 1024); // @ 43M (12.8 MB bf16 r/h)

    // ---- CSR build prologue ----
    detect_mode_kernel<<<1, 256, 0, stream>>>((const int*)ei, flag, bcnt);
    bucket_scatter_kernel<<<B1_BLOCKS, 256, 0, stream>>>(ei, flag, bcnt, bpairs);

    // ---- fused: B3 (blocks 0..195) + layer-1 GEMM (blocks 196..) ----
    csr_gemm1_kernel<<<NBUCK + GEMM_BLOCKS, 256, 0, stream>>>(
        bcnt, bpairs, rowptr, colb, x, W1l, W1r, b1, T, R);

    const int aggWaves  = (NN + 1) / 2;                 // 2 nodes per wave
    const int aggBlocks = (aggWaves * 64 + 255) / 256;
    const int headBlocks = (NN + 127) / 128;

    aggregate_relu_kernel<<<aggBlocks, 256, 0, stream>>>(rowptr, colb, T, R); // h1 in R

    gemm2_kernel<<<GEMM_BLOCKS, 256, 0, stream>>>(R, W2l, W2r, b2, T, R);
    aggregate_relu_kernel<<<aggBlocks, 256, 0, stream>>>(rowptr, colb, T, R); // h2 in R

    head_kernel<<<headBlocks, 256, 0, stream>>>(R, Wlin, blin, out);
}

// Round 13
// 153.581 us; speedup vs baseline: 19.8210x; 1.0611x over previous
//
#include <hip/hip_runtime.h>

#define NN 100000
#define NE 1600000
// IN_CH = HID = 64, OUT_CH = 16

// ---- bucketed CSR build geometry ----
#define BSHIFT 9
#define BWIDTH 512
#define NBUCK 196
#define SLOTS 12288
#define CHUNK 2048                               // edges per B1 block
#define B1_BLOCKS ((NE + CHUNK - 1) / CHUNK)     // 782
#define GEMM_BLOCKS ((NN + 63) / 64)             // 1563

typedef float    v2f __attribute__((ext_vector_type(2)));
typedef unsigned v2u __attribute__((ext_vector_type(2)));
typedef short    bf16x8 __attribute__((ext_vector_type(8)));
typedef float    f32x4  __attribute__((ext_vector_type(4)));

// ---- bf16 helpers (RNE pack, exact unpack) ----
__device__ __forceinline__ float u2f(unsigned u) {
    union { unsigned u; float f; } v; v.u = u; return v.f;
}
__device__ __forceinline__ unsigned f2u(float f) {
    union { float f; unsigned u; } v; v.f = f; return v.u;
}
__device__ __forceinline__ unsigned f2bf(float f) {   // bf16 in low 16, RNE
    unsigned u = f2u(f);
    return (u + 0x7FFFu + ((u >> 16) & 1u)) >> 16;
}
__device__ __forceinline__ v2f unpk(unsigned x) {
    v2u w; w[0] = x << 16; w[1] = x & 0xFFFF0000u;
    union { v2u u; v2f f; } c; c.u = w; return c.f;
}

// ---------------------------------------------------------------------------
// Detect int64 vs int32 edge_index; also zeroes bcnt.
__global__ void detect_mode_kernel(const int* ei32, int* flag, int* bcnt) {
    __shared__ int any_nonzero;
    if (threadIdx.x == 0) any_nonzero = 0;
    if (threadIdx.x < NBUCK) bcnt[threadIdx.x] = 0;
    __syncthreads();
    int idx = 1 + 2 * threadIdx.x;
    if (ei32[idx] != 0) atomicOr(&any_nonzero, 1);
    __syncthreads();
    if (threadIdx.x == 0) flag[0] = (any_nonzero == 0) ? 1 : 0;  // 1 => int64
}

__device__ __forceinline__ void load_edge(const void* ei, int is64, int e,
                                          int& s, int& d) {
    if (is64) {
        const long long* p = (const long long*)ei;
        s = (int)p[e];
        d = (int)p[NE + e];
    } else {
        const int* p = (const int*)ei;
        s = p[e];
        d = p[NE + e];
    }
}

// ---------------------------------------------------------------------------
// MFMA GEMM body: t(bf16) = feat @ Wl.T ; r(bf16, +bias) = feat @ Wr.T.
// Block = 256 thr = 4 waves; tile 64 nodes x 128 ch; wave w owns 32 channels.
// A,B staged in LDS as bf16, row stride 72 (16B-aligned b128 reads).
// mfma_f32_16x16x32_bf16: A-frag lane: feat[n0+(l&15)][ks*32+(l>>4)*8+j];
// B-frag lane: W[c0+(l&15)][same k]; D: col=lane&15 (=c), row=(l>>4)*4+i (=n).
template<int BF16IN>
__device__ __forceinline__ void gemm_mfma_body(
    char* smem, const void* __restrict__ featv,
    const float* __restrict__ Wl, const float* __restrict__ Wr,
    const float* __restrict__ bias,
    unsigned* __restrict__ outt, unsigned* __restrict__ outr,
    int tile, int t)
{
    unsigned short* Als = (unsigned short*)smem;            // [64][72] bf16
    unsigned short* Bls = (unsigned short*)(smem + 9216);   // [128][72] bf16
    const int lane = t & 63, w = t >> 6;
    const int m0 = tile * 64;
    const float*    featf = (const float*)featv;
    const unsigned* featu = (const unsigned*)featv;

    // ---- stage A: 512 tasks (row, k8-slot) ----
    #pragma unroll
    for (int rep = 0; rep < 2; ++rep) {
        int task = t + 256 * rep;
        int row = task >> 3, s = task & 7;
        int gn = m0 + row;
        uint4 u;
        if (BF16IN) {
            u = (gn < NN) ? *(const uint4*)(featu + (size_t)gn * 32 + 4 * s)
                          : make_uint4(0u, 0u, 0u, 0u);
        } else {
            if (gn < NN) {
                float4 v0 = *(const float4*)(featf + (size_t)gn * 64 + 8 * s);
                float4 v1 = *(const float4*)(featf + (size_t)gn * 64 + 8 * s + 4);
                u.x = f2bf(v0.x) | (f2bf(v0.y) << 16);
                u.y = f2bf(v0.z) | (f2bf(v0.w) << 16);
                u.z = f2bf(v1.x) | (f2bf(v1.y) << 16);
                u.w = f2bf(v1.z) | (f2bf(v1.w) << 16);
            } else u = make_uint4(0u, 0u, 0u, 0u);
        }
        *(uint4*)(Als + row * 72 + 8 * s) = u;
    }
    // ---- stage B: 1024 tasks (c, k8-slot) ----
    #pragma unroll
    for (int rep = 0; rep < 4; ++rep) {
        int task = t + 256 * rep;
        int c = task >> 3, s = task & 7;
        const float* Wsrc = (c < 64) ? (Wl + (size_t)c * 64)
                                     : (Wr + (size_t)(c - 64) * 64);
        float4 v0 = *(const float4*)(Wsrc + 8 * s);
        float4 v1 = *(const float4*)(Wsrc + 8 * s + 4);
        uint4 u;
        u.x = f2bf(v0.x) | (f2bf(v0.y) << 16);
        u.y = f2bf(v0.z) | (f2bf(v0.w) << 16);
        u.z = f2bf(v1.x) | (f2bf(v1.y) << 16);
        u.w = f2bf(v1.z) | (f2bf(v1.w) << 16);
        *(uint4*)(Bls + c * 72 + 8 * s) = u;
    }
    __syncthreads();

    const int r = lane & 15, g = lane >> 4;
    const int cw0 = 32 * w;

    bf16x8 bf[2][2];
    #pragma unroll
    for (int ct = 0; ct < 2; ++ct)
        #pragma unroll
        for (int ks = 0; ks < 2; ++ks) {
            int c = cw0 + 16 * ct + r;
            bf[ct][ks] = *(const bf16x8*)(Bls + c * 72 + (ks * 4 + g) * 8);
        }

    f32x4 acc[4][2];
    #pragma unroll
    for (int nt = 0; nt < 4; ++nt)
        #pragma unroll
        for (int ct = 0; ct < 2; ++ct)
            acc[nt][ct] = (f32x4){0.f, 0.f, 0.f, 0.f};

    #pragma unroll
    for (int nt = 0; nt < 4; ++nt) {
        bf16x8 af[2];
        #pragma unroll
        for (int ks = 0; ks < 2; ++ks) {
            int rr = nt * 16 + r;
            af[ks] = *(const bf16x8*)(Als + rr * 72 + (ks * 4 + g) * 8);
        }
        #pragma unroll
        for (int ct = 0; ct < 2; ++ct)
            #pragma unroll
            for (int ks = 0; ks < 2; ++ks)
                acc[nt][ct] = __builtin_amdgcn_mfma_f32_16x16x32_bf16(
                    af[ks], bf[ct][ks], acc[nt][ct], 0, 0, 0);
    }

    // ---- epilogue: direct bf16 stores (D: row=g*4+i, col=r) ----
    unsigned short* Tb = (unsigned short*)outt;
    unsigned short* Rb = (unsigned short*)outr;
    #pragma unroll
    for (int ct = 0; ct < 2; ++ct) {
        int c = cw0 + 16 * ct + r;
        float badd = (c >= 64) ? bias[c - 64] : 0.f;
        unsigned short* dst = (c < 64) ? (Tb + c) : (Rb + (c - 64));
        #pragma unroll
        for (int nt = 0; nt < 4; ++nt)
            #pragma unroll
            for (int i = 0; i < 4; ++i) {
                int row = m0 + nt * 16 + g * 4 + i;
                if (row < NN)
                    dst[(size_t)row * 64] = (unsigned short)f2bf(acc[nt][ct][i] + badd);
            }
    }
}

// ---------------------------------------------------------------------------
// FUSED: blocks [0, B1_BLOCKS) bucket the edges (B1, CHUNK=2048); blocks
// [B1_BLOCKS, ..) run the layer-1 MFMA GEMM. The two parts are independent
// (B1: edges -> bcnt/bpairs; gemm1: x/W -> T/R), so B1's latency-bound waves
// overlap gemm1's compute.
__global__ __launch_bounds__(256) void b1_gemm1_kernel(
    const void* ei, const int* flag,
    int* __restrict__ bcnt, int2* __restrict__ bpairs,
    const float* __restrict__ x,
    const float* __restrict__ W1l, const float* __restrict__ W1r,
    const float* __restrict__ b1,
    unsigned* __restrict__ T, unsigned* __restrict__ R)
{
    __shared__ __align__(16) char smem[27648];
    const int t = threadIdx.x;

    if (blockIdx.x >= B1_BLOCKS) {
        if (blockIdx.x == B1_BLOCKS && t < 32) T[(size_t)NN * 32 + t] = 0u; // zero row
        gemm_mfma_body<0>(smem, x, W1l, W1r, b1, T, R, blockIdx.x - B1_BLOCKS, t);
        return;
    }

    // ---------------- B1 part ----------------
    int2* stage = (int2*)smem;                                   // 16384
    unsigned short* sbuck = (unsigned short*)(smem + 16384);     // 4096
    int* hist  = (int*)(smem + 20480);                           // 784
    int* scanb = (int*)(smem + 21264);
    int* gbase = (int*)(smem + 22048);
    int* lofs  = (int*)(smem + 22832);
    int* sc    = (int*)(smem + 23616);                           // 1024

    const int is64 = *flag;
    const int e0 = blockIdx.x * CHUNK;
    const int nE = min(CHUNK, NE - e0);

    for (int i = t; i < NBUCK; i += 256) { hist[i] = 0; lofs[i] = 0; }
    __syncthreads();

    int sr[8], dr[8];
    #pragma unroll
    for (int rr = 0; rr < 8; ++rr) {
        int e = e0 + t + 256 * rr;
        if (e < NE) load_edge(ei, is64, e, sr[rr], dr[rr]);
        else dr[rr] = -1;
    }
    #pragma unroll
    for (int rr = 0; rr < 8; ++rr)
        if (dr[rr] >= 0) atomicAdd(&hist[dr[rr] >> BSHIFT], 1);
    __syncthreads();

    int v = (t < NBUCK) ? hist[t] : 0;
    sc[t] = v;
    __syncthreads();
    for (int off = 1; off < 256; off <<= 1) {
        int u = (t >= off) ? sc[t - off] : 0;
        __syncthreads();
        sc[t] += u;
        __syncthreads();
    }
    if (t < NBUCK) {
        scanb[t] = sc[t] - v;
        gbase[t] = atomicAdd(&bcnt[t], v);
    }
    __syncthreads();

    #pragma unroll
    for (int rr = 0; rr < 8; ++rr) {
        if (dr[rr] >= 0) {
            int b = dr[rr] >> BSHIFT;
            int p = scanb[b] + atomicAdd(&lofs[b], 1);
            stage[p] = make_int2(sr[rr], dr[rr]);
            sbuck[p] = (unsigned short)b;
        }
    }
    __syncthreads();

    for (int i = t; i < nE; i += 256) {
        int b = sbuck[i];
        int off = gbase[b] + (i - scanb[b]);
        if (off < SLOTS) bpairs[(size_t)b * SLOTS + off] = stage[i];
    }
}

// ---------------------------------------------------------------------------
// B3 (512 threads): bucket -> rowptr + colb, with in-block bucket prefix.
__global__ __launch_bounds__(512) void bucket_to_csr_kernel(
    const int* __restrict__ bcnt, const int2* __restrict__ bpairs,
    int* __restrict__ rowptr, int* __restrict__ colb)
{
    __shared__ int ldeg[512], lptr[512], lcnt[512], sc[512];
    const int t = threadIdx.x, b = blockIdx.x;

    int v = (t < NBUCK) ? bcnt[t] : 0;
    sc[t] = v;
    __syncthreads();
    for (int off = 1; off < 512; off <<= 1) {
        int u = (t >= off) ? sc[t - off] : 0;
        __syncthreads();
        sc[t] += u;
        __syncthreads();
    }
    const int base = (b == 0) ? 0 : sc[b - 1];
    if (b == 0 && t == 0) rowptr[NN] = NE;
    __syncthreads();

    ldeg[t] = 0; lcnt[t] = 0;
    __syncthreads();

    const int n0 = b << BSHIFT;
    const int cnt = min(bcnt[b], SLOTS);
    const int2* src = bpairs + (size_t)b * SLOTS;
    for (int i = t; i < cnt; i += 512)
        atomicAdd(&ldeg[src[i].y - n0], 1);
    __syncthreads();

    int a = ldeg[t];
    sc[t] = a;
    __syncthreads();
    for (int off = 1; off < 512; off <<= 1) {
        int u = (t >= off) ? sc[t - off] : 0;
        __syncthreads();
        sc[t] += u;
        __syncthreads();
    }
    lptr[t] = sc[t] - a;
    __syncthreads();

    int gn = n0 + t;
    if (gn < NN) rowptr[gn] = base + lptr[t];

    for (int i = t; i < cnt; i += 512) {
        int2 p = src[i];
        int li = p.y - n0;
        int pos = lptr[li] + atomicAdd(&lcnt[li], 1);
        colb[base + pos] = p.x << 7;   // byte offset into bf16 table
    }
}

// ---------------------------------------------------------------------------
// Standalone layer-2 MFMA GEMM (bf16 input features; in-place safe per-tile).
__global__ __launch_bounds__(256) void gemm2_kernel(
    const unsigned* __restrict__ feat,
    const float* __restrict__ Wl, const float* __restrict__ Wr,
    const float* __restrict__ bias,
    unsigned* __restrict__ outt, unsigned* __restrict__ outr)
{
    __shared__ __align__(16) char smem[27648];
    gemm_mfma_body<1>(smem, feat, Wl, Wr, bias, outt, outr, blockIdx.x, threadIdx.x);
}

// ---------------------------------------------------------------------------
// Gather-mean (bf16 table) + epilogue: rh(bf16) <- relu(mean + rh).
// 2 nodes per wave; 4-deep pipeline.
__global__ void aggregate_relu_kernel(const int* __restrict__ rowptr,
                                      const int* __restrict__ colb,
                                      const unsigned* __restrict__ tt,  // (NN+1) x 32
                                      unsigned* rh) {                   // NN x 32
    const int wv   = (blockIdx.x * blockDim.x + threadIdx.x) >> 6;
    const int lane = threadIdx.x & 63;
    const int half = lane >> 5;
    const int slot = (lane >> 3) & 3;
    const int c8   = lane & 7;
    const int node = 2 * wv + half;
    if (node >= NN) return;

    const int beg = rowptr[node], end = rowptr[node + 1];
    const int deg = end - beg;
    int niter = (deg + 3) >> 2;
    niter = max(niter, __shfl_xor(niter, 32));   // wave-uniform

    const char* tb = (const char*)tt;
    const int zoff = NN * 128;                   // zero row (byte offset)
    v2f a0 = {0.f, 0.f}, a1 = {0.f, 0.f}, a2 = {0.f, 0.f}, a3 = {0.f, 0.f};
    v2f b0 = {0.f, 0.f}, b1 = {0.f, 0.f}, b2 = {0.f, 0.f}, b3 = {0.f, 0.f};

    int jj = beg + slot;
    int it = 0;
    for (; it + 4 <= niter; it += 4, jj += 16) {
        int jc0 = min(jj,      end - 1);
        int jc1 = min(jj + 4,  end - 1);
        int jc2 = min(jj + 8,  end - 1);
        int jc3 = min(jj + 12, end - 1);
        int o0 = colb[jc0];
        int o1 = colb[jc1];
        int o2 = colb[jc2];
        int o3 = colb[jc3];
        o0 = (jj      < end) ? o0 : zoff;
        o1 = (jj + 4  < end) ? o1 : zoff;
        o2 = (jj + 8  < end) ? o2 : zoff;
        o3 = (jj + 12 < end) ? o3 : zoff;
        uint4 u0 = *(const uint4*)(tb + (size_t)(unsigned)o0 + 16 * c8);
        uint4 u1 = *(const uint4*)(tb + (size_t)(unsigned)o1 + 16 * c8);
        uint4 u2 = *(const uint4*)(tb + (size_t)(unsigned)o2 + 16 * c8);
        uint4 u3 = *(const uint4*)(tb + (size_t)(unsigned)o3 + 16 * c8);
        a0 += unpk(u0.x); a1 += unpk(u0.y); a2 += unpk(u0.z); a3 += unpk(u0.w);
        b0 += unpk(u1.x); b1 += unpk(u1.y); b2 += unpk(u1.z); b3 += unpk(u1.w);
        a0 += unpk(u2.x); a1 += unpk(u2.y); a2 += unpk(u2.z); a3 += unpk(u2.w);
        b0 += unpk(u3.x); b1 += unpk(u3.y); b2 += unpk(u3.z); b3 += unpk(u3.w);
    }
    for (; it < niter; ++it, jj += 4) {
        int jc0 = min(jj, end - 1);
        int o0 = colb[jc0];
        o0 = (jj < end) ? o0 : zoff;
        uint4 u0 = *(const uint4*)(tb + (size_t)(unsigned)o0 + 16 * c8);
        a0 += unpk(u0.x); a1 += unpk(u0.y); a2 += unpk(u0.z); a3 += unpk(u0.w);
    }
    a0 += b0; a1 += b1; a2 += b2; a3 += b3;

    a0[0] += __shfl_xor(a0[0], 8);  a0[1] += __shfl_xor(a0[1], 8);
    a1[0] += __shfl_xor(a1[0], 8);  a1[1] += __shfl_xor(a1[1], 8);
    a2[0] += __shfl_xor(a2[0], 8);  a2[1] += __shfl_xor(a2[1], 8);
    a3[0] += __shfl_xor(a3[0], 8);  a3[1] += __shfl_xor(a3[1], 8);
    a0[0] += __shfl_xor(a0[0], 16); a0[1] += __shfl_xor(a0[1], 16);
    a1[0] += __shfl_xor(a1[0], 16); a1[1] += __shfl_xor(a1[1], 16);
    a2[0] += __shfl_xor(a2[0], 16); a2[1] += __shfl_xor(a2[1], 16);
    a3[0] += __shfl_xor(a3[0], 16); a3[1] += __shfl_xor(a3[1], 16);

    if (slot == 0) {
        float inv = 1.0f / fmaxf((float)deg, 1.0f);
        unsigned* p = rh + (size_t)node * 32 + 4 * c8;
        uint4 rr = *(const uint4*)p;
        v2f q0 = unpk(rr.x), q1 = unpk(rr.y), q2 = unpk(rr.z), q3 = unpk(rr.w);
        float h0 = fmaxf(fmaf(a0[0], inv, q0[0]), 0.0f);
        float h1 = fmaxf(fmaf(a0[1], inv, q0[1]), 0.0f);
        float h2 = fmaxf(fmaf(a1[0], inv, q1[0]), 0.0f);
        float h3 = fmaxf(fmaf(a1[1], inv, q1[1]), 0.0f);
        float h4 = fmaxf(fmaf(a2[0], inv, q2[0]), 0.0f);
        float h5 = fmaxf(fmaf(a2[1], inv, q2[1]), 0.0f);
        float h6 = fmaxf(fmaf(a3[0], inv, q3[0]), 0.0f);
        float h7 = fmaxf(fmaf(a3[1], inv, q3[1]), 0.0f);
        uint4 wv4;
        wv4.x = f2bf(h0) | (f2bf(h1) << 16);
        wv4.y = f2bf(h2) | (f2bf(h3) << 16);
        wv4.z = f2bf(h4) | (f2bf(h5) << 16);
        wv4.w = f2bf(h6) | (f2bf(h7) << 16);
        *(uint4*)p = wv4;
    }
}

// ---------------------------------------------------------------------------
// Head GEMM: out = h(bf16) @ Wlin.T + blin.
__global__ __launch_bounds__(256) void head_kernel(
    const unsigned* __restrict__ hu,      // NN x 32 bf16x2
    const float* __restrict__ Wlin,
    const float* __restrict__ blin,
    float* __restrict__ out)
{
    __shared__ float As[64][132];
    __shared__ float Bs[64][18];
    const int t = threadIdx.x;

    {
        int c = t & 15, j = t >> 4;
        float4 v = *(const float4*)(Wlin + (size_t)c * 64 + 4 * j);
        Bs[4 * j + 0][c] = v.x; Bs[4 * j + 1][c] = v.y;
        Bs[4 * j + 2][c] = v.z; Bs[4 * j + 3][c] = v.w;
    }
    const int m0 = blockIdx.x * 128;
    {
        int kq = t & 7;
        int nb = t >> 3;
        for (int rep = 0; rep < 4; ++rep) {
            int n = nb + 32 * rep;
            int gn = m0 + n;
            uint4 u = (gn < NN) ? *(const uint4*)(hu + (size_t)gn * 32 + 4 * kq)
                                : make_uint4(0u, 0u, 0u, 0u);
            int kk = 8 * kq;
            As[kk + 0][n] = u2f(u.x << 16); As[kk + 1][n] = u2f(u.x & 0xFFFF0000u);
            As[kk + 2][n] = u2f(u.y << 16); As[kk + 3][n] = u2f(u.y & 0xFFFF0000u);
            As[kk + 4][n] = u2f(u.z << 16); As[kk + 5][n] = u2f(u.z & 0xFFFF0000u);
            As[kk + 6][n] = u2f(u.w << 16); As[kk + 7][n] = u2f(u.w & 0xFFFF0000u);
        }
    }
    __syncthreads();

    const int tn = t & 31;
    const int tc = t >> 5;
    const int c0 = 2 * tc;
    float acc[4][2];
    #pragma unroll
    for (int i = 0; i < 4; ++i) { acc[i][0] = blin[c0]; acc[i][1] = blin[c0 + 1]; }

    #pragma unroll 16
    for (int k = 0; k < 64; ++k) {
        float4 a = *(const float4*)&As[k][4 * tn];
        float b0 = Bs[k][c0], b1 = Bs[k][c0 + 1];
        float av[4] = {a.x, a.y, a.z, a.w};
        #pragma unroll
        for (int i = 0; i < 4; ++i) {
            acc[i][0] = fmaf(av[i], b0, acc[i][0]);
            acc[i][1] = fmaf(av[i], b1, acc[i][1]);
        }
    }
    #pragma unroll
    for (int i = 0; i < 4; ++i) {
        int gn = m0 + 4 * tn + i;
        if (gn < NN)
            *(float2*)(out + (size_t)gn * 16 + c0) = make_float2(acc[i][0], acc[i][1]);
    }
}

// ---------------------------------------------------------------------------
extern "C" void kernel_launch(void* const* d_in, const int* in_sizes, int n_in,
                              void* d_out, int out_size, void* d_ws, size_t ws_size,
                              hipStream_t stream) {
    const float* x    = (const float*)d_in[0];
    const void*  ei   = d_in[1];
    const float* W1l  = (const float*)d_in[2];
    const float* b1   = (const float*)d_in[3];
    const float* W1r  = (const float*)d_in[4];
    const float* W2l  = (const float*)d_in[5];
    const float* b2   = (const float*)d_in[6];
    const float* W2r  = (const float*)d_in[7];
    const float* Wlin = (const float*)d_in[8];
    const float* blin = (const float*)d_in[9];
    float* out = (float*)d_out;

    char* w = (char*)d_ws;
    int*      flag   = (int*)w;                                   // @ 0
    int*      bcnt   = (int*)(w + (size_t)4 * 1024);              // @ 4K
    int*      rowptr = (int*)(w + (size_t)1024 * 1024);           // @ 1M  (400 KB+4)
    int*      colb   = (int*)(w + (size_t)2 * 1024 * 1024);       // @ 2M  (6.4 MB)
    int2*     bpairs = (int2*)(w + (size_t)10 * 1024 * 1024);     // @ 10M (19.3 MB)
    unsigned* T      = (unsigned*)(w + (size_t)30 * 1024 * 1024); // @ 30M (12.8 MB + zero row)
    unsigned* R      = (unsigned*)(w + (size_t)43 * 1024 * 1024); // @ 43M (12.8 MB bf16 r/h)

    detect_mode_kernel<<<1, 256, 0, stream>>>((const int*)ei, flag, bcnt);

    // ---- fused: B1 (blocks 0..781) + layer-1 MFMA GEMM (blocks 782..) ----
    b1_gemm1_kernel<<<B1_BLOCKS + GEMM_BLOCKS, 256, 0, stream>>>(
        ei, flag, bcnt, bpairs, x, W1l, W1r, b1, T, R);

    bucket_to_csr_kernel<<<NBUCK, 512, 0, stream>>>(bcnt, bpairs, rowptr, colb);

    const int aggWaves  = (NN + 1) / 2;
    const int aggBlocks = (aggWaves * 64 + 255) / 256;
    const int headBlocks = (NN + 127) / 128;

    aggregate_relu_kernel<<<aggBlocks, 256, 0, stream>>>(rowptr, colb, T, R); // h1 in R

    gemm2_kernel<<<GEMM_BLOCKS, 256, 0, stream>>>(R, W2l, W2r, b2, T, R);
    aggregate_relu_kernel<<<aggBlocks, 256, 0, stream>>>(rowptr, colb, T, R); // h2 in R

    head_kernel<<<headBlocks, 256, 0, stream>>>(R, Wlin, blin, out);
}

// Round 14
// 144.548 us; speedup vs baseline: 21.0596x; 1.0625x over previous
//
#include <hip/hip_runtime.h>

#define NN 100000
#define NE 1600000
// IN_CH = HID = 64, OUT_CH = 16

// ---- bucketed CSR build geometry ----
#define BSHIFT 9
#define BWIDTH 512
#define NBUCK 196
#define SLOTS 12288
#define CHUNK 4096                               // edges per B1 block
#define B1_BLOCKS ((NE + CHUNK - 1) / CHUNK)     // 391
#define GEMM_BLOCKS ((NN + 63) / 64)             // 1563
#define AGG_CAP 1024

typedef float    v2f __attribute__((ext_vector_type(2)));
typedef unsigned v2u __attribute__((ext_vector_type(2)));
typedef short    bf16x8 __attribute__((ext_vector_type(8)));
typedef float    f32x4  __attribute__((ext_vector_type(4)));

// ---- bf16 helpers (RNE pack, exact unpack) ----
__device__ __forceinline__ float u2f(unsigned u) {
    union { unsigned u; float f; } v; v.u = u; return v.f;
}
__device__ __forceinline__ unsigned f2u(float f) {
    union { float f; unsigned u; } v; v.f = f; return v.u;
}
__device__ __forceinline__ unsigned f2bf(float f) {   // bf16 in low 16, RNE
    unsigned u = f2u(f);
    return (u + 0x7FFFu + ((u >> 16) & 1u)) >> 16;
}
__device__ __forceinline__ v2f unpk(unsigned x) {
    v2u w; w[0] = x << 16; w[1] = x & 0xFFFF0000u;
    union { v2u u; v2f f; } c; c.u = w; return c.f;
}
// wave-level inclusive scan (64 lanes)
__device__ __forceinline__ int wave_incl_scan(int v, int lane) {
    #pragma unroll
    for (int off = 1; off < 64; off <<= 1) {
        int u = __shfl_up(v, off);
        if (lane >= off) v += u;
    }
    return v;
}

// ---------------------------------------------------------------------------
// Detect int64 vs int32 edge_index; also zeroes bcnt.
__global__ void detect_mode_kernel(const int* ei32, int* flag, int* bcnt) {
    __shared__ int any_nonzero;
    if (threadIdx.x == 0) any_nonzero = 0;
    if (threadIdx.x < NBUCK) bcnt[threadIdx.x] = 0;
    __syncthreads();
    int idx = 1 + 2 * threadIdx.x;
    if (ei32[idx] != 0) atomicOr(&any_nonzero, 1);
    __syncthreads();
    if (threadIdx.x == 0) flag[0] = (any_nonzero == 0) ? 1 : 0;  // 1 => int64
}

__device__ __forceinline__ void load_edge(const void* ei, int is64, int e,
                                          int& s, int& d) {
    if (is64) {
        const long long* p = (const long long*)ei;
        s = (int)p[e];
        d = (int)p[NE + e];
    } else {
        const int* p = (const int*)ei;
        s = p[e];
        d = p[NE + e];
    }
}

// ---------------------------------------------------------------------------
// MFMA GEMM body: t(bf16) = feat @ Wl.T ; r(bf16, +bias) = feat @ Wr.T.
// Block = 256 thr = 4 waves; tile 64 nodes x 128 ch; wave w owns 32 channels.
template<int BF16IN>
__device__ __forceinline__ void gemm_mfma_body(
    char* smem, const void* __restrict__ featv,
    const float* __restrict__ Wl, const float* __restrict__ Wr,
    const float* __restrict__ bias,
    unsigned* __restrict__ outt, unsigned* __restrict__ outr,
    int tile, int t)
{
    unsigned short* Als = (unsigned short*)smem;            // [64][72] bf16
    unsigned short* Bls = (unsigned short*)(smem + 9216);   // [128][72] bf16
    const int lane = t & 63, w = t >> 6;
    const int m0 = tile * 64;
    const float*    featf = (const float*)featv;
    const unsigned* featu = (const unsigned*)featv;

    #pragma unroll
    for (int rep = 0; rep < 2; ++rep) {
        int task = t + 256 * rep;
        int row = task >> 3, s = task & 7;
        int gn = m0 + row;
        uint4 u;
        if (BF16IN) {
            u = (gn < NN) ? *(const uint4*)(featu + (size_t)gn * 32 + 4 * s)
                          : make_uint4(0u, 0u, 0u, 0u);
        } else {
            if (gn < NN) {
                float4 v0 = *(const float4*)(featf + (size_t)gn * 64 + 8 * s);
                float4 v1 = *(const float4*)(featf + (size_t)gn * 64 + 8 * s + 4);
                u.x = f2bf(v0.x) | (f2bf(v0.y) << 16);
                u.y = f2bf(v0.z) | (f2bf(v0.w) << 16);
                u.z = f2bf(v1.x) | (f2bf(v1.y) << 16);
                u.w = f2bf(v1.z) | (f2bf(v1.w) << 16);
            } else u = make_uint4(0u, 0u, 0u, 0u);
        }
        *(uint4*)(Als + row * 72 + 8 * s) = u;
    }
    #pragma unroll
    for (int rep = 0; rep < 4; ++rep) {
        int task = t + 256 * rep;
        int c = task >> 3, s = task & 7;
        const float* Wsrc = (c < 64) ? (Wl + (size_t)c * 64)
                                     : (Wr + (size_t)(c - 64) * 64);
        float4 v0 = *(const float4*)(Wsrc + 8 * s);
        float4 v1 = *(const float4*)(Wsrc + 8 * s + 4);
        uint4 u;
        u.x = f2bf(v0.x) | (f2bf(v0.y) << 16);
        u.y = f2bf(v0.z) | (f2bf(v0.w) << 16);
        u.z = f2bf(v1.x) | (f2bf(v1.y) << 16);
        u.w = f2bf(v1.z) | (f2bf(v1.w) << 16);
        *(uint4*)(Bls + c * 72 + 8 * s) = u;
    }
    __syncthreads();

    const int r = lane & 15, g = lane >> 4;
    const int cw0 = 32 * w;

    bf16x8 bf[2][2];
    #pragma unroll
    for (int ct = 0; ct < 2; ++ct)
        #pragma unroll
        for (int ks = 0; ks < 2; ++ks) {
            int c = cw0 + 16 * ct + r;
            bf[ct][ks] = *(const bf16x8*)(Bls + c * 72 + (ks * 4 + g) * 8);
        }

    f32x4 acc[4][2];
    #pragma unroll
    for (int nt = 0; nt < 4; ++nt)
        #pragma unroll
        for (int ct = 0; ct < 2; ++ct)
            acc[nt][ct] = (f32x4){0.f, 0.f, 0.f, 0.f};

    #pragma unroll
    for (int nt = 0; nt < 4; ++nt) {
        bf16x8 af[2];
        #pragma unroll
        for (int ks = 0; ks < 2; ++ks) {
            int rr = nt * 16 + r;
            af[ks] = *(const bf16x8*)(Als + rr * 72 + (ks * 4 + g) * 8);
        }
        #pragma unroll
        for (int ct = 0; ct < 2; ++ct)
            #pragma unroll
            for (int ks = 0; ks < 2; ++ks)
                acc[nt][ct] = __builtin_amdgcn_mfma_f32_16x16x32_bf16(
                    af[ks], bf[ct][ks], acc[nt][ct], 0, 0, 0);
    }

    unsigned short* Tb = (unsigned short*)outt;
    unsigned short* Rb = (unsigned short*)outr;
    #pragma unroll
    for (int ct = 0; ct < 2; ++ct) {
        int c = cw0 + 16 * ct + r;
        float badd = (c >= 64) ? bias[c - 64] : 0.f;
        unsigned short* dst = (c < 64) ? (Tb + c) : (Rb + (c - 64));
        #pragma unroll
        for (int nt = 0; nt < 4; ++nt)
            #pragma unroll
            for (int i = 0; i < 4; ++i) {
                int row = m0 + nt * 16 + g * 4 + i;
                if (row < NN)
                    dst[(size_t)row * 64] = (unsigned short)f2bf(acc[nt][ct][i] + badd);
            }
    }
}

// ---------------------------------------------------------------------------
// FUSED: blocks [0, B1_BLOCKS) bucket edges (packed 4B entries, CHUNK=4096,
// shfl scans); blocks [B1_BLOCKS, ..) run the layer-1 MFMA GEMM.
__global__ __launch_bounds__(256) void b1_gemm1_kernel(
    const void* ei, const int* flag,
    int* __restrict__ bcnt, int* __restrict__ bpk,
    const float* __restrict__ x,
    const float* __restrict__ W1l, const float* __restrict__ W1r,
    const float* __restrict__ b1,
    unsigned* __restrict__ T, unsigned* __restrict__ R)
{
    __shared__ __align__(16) char smem[27648];
    const int t = threadIdx.x;

    if (blockIdx.x >= B1_BLOCKS) {
        if (blockIdx.x == B1_BLOCKS && t < 32) T[(size_t)NN * 32 + t] = 0u; // zero row
        gemm_mfma_body<0>(smem, x, W1l, W1r, b1, T, R, blockIdx.x - B1_BLOCKS, t);
        return;
    }

    // ---------------- B1 part ----------------
    int* stage = (int*)smem;                                     // 16384
    unsigned char* sbuck = (unsigned char*)(smem + 16384);       // 4096
    int* hist  = (int*)(smem + 20480);                           // 784
    int* scanb = (int*)(smem + 21264);
    int* gbase = (int*)(smem + 22048);
    int* lofs  = (int*)(smem + 22832);
    int* wsum  = (int*)(smem + 23616);                           // 16

    const int is64 = *flag;
    const int e0 = blockIdx.x * CHUNK;
    const int nE = min(CHUNK, NE - e0);
    const int lane = t & 63, wvi = t >> 6;

    for (int i = t; i < NBUCK; i += 256) { hist[i] = 0; lofs[i] = 0; }
    __syncthreads();

    int sr[16], dr[16];
    #pragma unroll
    for (int rr = 0; rr < 16; ++rr) {
        int e = e0 + t + 256 * rr;
        if (e < NE) load_edge(ei, is64, e, sr[rr], dr[rr]);
        else dr[rr] = -1;
    }
    #pragma unroll
    for (int rr = 0; rr < 16; ++rr)
        if (dr[rr] >= 0) atomicAdd(&hist[dr[rr] >> BSHIFT], 1);
    __syncthreads();

    // 256-wide exclusive scan of hist via wave shfl + wave-sum combine
    int v = (t < NBUCK) ? hist[t] : 0;
    int s = wave_incl_scan(v, lane);
    if (lane == 63) wsum[wvi] = s;
    __syncthreads();
    int add = 0;
    #pragma unroll
    for (int k = 0; k < 3; ++k) if (wvi > k) add += wsum[k];
    s += add;
    if (t < NBUCK) {
        scanb[t] = s - v;
        gbase[t] = atomicAdd(&bcnt[t], v);
    }
    __syncthreads();

    #pragma unroll
    for (int rr = 0; rr < 16; ++rr) {
        if (dr[rr] >= 0) {
            int b = dr[rr] >> BSHIFT;
            int p = scanb[b] + atomicAdd(&lofs[b], 1);
            stage[p] = (sr[rr] << BSHIFT) | (dr[rr] & (BWIDTH - 1));
            sbuck[p] = (unsigned char)b;
        }
    }
    __syncthreads();

    for (int i = t; i < nE; i += 256) {
        int b = sbuck[i];
        int off = gbase[b] + (i - scanb[b]);
        if (off < SLOTS) bpk[(size_t)b * SLOTS + off] = stage[i];
    }
}

// ---------------------------------------------------------------------------
// B3 (512 threads): packed bucket -> rowptr + colb (byte offsets), with
// in-block bucket prefix; all scans via wave shfl.
__global__ __launch_bounds__(512) void bucket_to_csr_kernel(
    const int* __restrict__ bcnt, const int* __restrict__ bpk,
    int* __restrict__ rowptr, int* __restrict__ colb)
{
    __shared__ int ldeg[512], lptr[512], lcnt[512], sc[512], wsum[8];
    const int t = threadIdx.x, b = blockIdx.x;
    const int lane = t & 63, wvi = t >> 6;

    // bucket prefix: exclusive sum of bcnt[0..b-1]
    int v = (t < NBUCK) ? bcnt[t] : 0;
    int s = wave_incl_scan(v, lane);
    if (lane == 63) wsum[wvi] = s;
    __syncthreads();
    int add = 0;
    #pragma unroll
    for (int k = 0; k < 7; ++k) if (wvi > k) add += wsum[k];
    s += add;
    sc[t] = s;
    __syncthreads();
    const int base = (b == 0) ? 0 : sc[b - 1];
    if (b == 0 && t == 0) rowptr[NN] = NE;
    __syncthreads();

    ldeg[t] = 0; lcnt[t] = 0;
    __syncthreads();

    const int n0 = b << BSHIFT;
    const int cnt = min(bcnt[b], SLOTS);
    const int* src = bpk + (size_t)b * SLOTS;
    for (int i = t; i < cnt; i += 512)
        atomicAdd(&ldeg[src[i] & (BWIDTH - 1)], 1);
    __syncthreads();

    int a = ldeg[t];
    int s2 = wave_incl_scan(a, lane);
    if (lane == 63) wsum[wvi] = s2;
    __syncthreads();
    int add2 = 0;
    #pragma unroll
    for (int k = 0; k < 7; ++k) if (wvi > k) add2 += wsum[k];
    s2 += add2;
    lptr[t] = s2 - a;
    __syncthreads();

    int gn = n0 + t;
    if (gn < NN) rowptr[gn] = base + lptr[t];

    for (int i = t; i < cnt; i += 512) {
        int p = src[i];
        int li = p & (BWIDTH - 1);
        int pos = lptr[li] + atomicAdd(&lcnt[li], 1);
        colb[base + pos] = (p >> BSHIFT) << 7;   // src byte offset into table
    }
}

// ---------------------------------------------------------------------------
// Standalone layer-2 MFMA GEMM (bf16 input features; in-place safe per-tile).
__global__ __launch_bounds__(256) void gemm2_kernel(
    const unsigned* __restrict__ feat,
    const float* __restrict__ Wl, const float* __restrict__ Wr,
    const float* __restrict__ bias,
    unsigned* __restrict__ outt, unsigned* __restrict__ outr)
{
    __shared__ __align__(16) char smem[27648];
    gemm_mfma_body<1>(smem, feat, Wl, Wr, bias, outt, outr, blockIdx.x, threadIdx.x);
}

// ---------------------------------------------------------------------------
// Gather-mean (bf16 table) + epilogue: rh(bf16) <- relu(mean + rh).
// Block = 8 nodes (4 waves x 2); the block's col range is CONTIGUOUS -> stage
// it into LDS once (coalesced), making the per-edge chain LDS->gather.
// Overflow (>AGG_CAP entries) falls back to the global path.
#define AGG_STEP(O0, O1, O2, O3)                                              \
    {                                                                         \
        int o0 = O0, o1 = O1, o2 = O2, o3 = O3;                               \
        o0 = (jj      < end) ? o0 : zoff;                                     \
        o1 = (jj + 4  < end) ? o1 : zoff;                                     \
        o2 = (jj + 8  < end) ? o2 : zoff;                                     \
        o3 = (jj + 12 < end) ? o3 : zoff;                                     \
        uint4 u0 = *(const uint4*)(tb + (size_t)(unsigned)o0 + 16 * c8);      \
        uint4 u1 = *(const uint4*)(tb + (size_t)(unsigned)o1 + 16 * c8);      \
        uint4 u2 = *(const uint4*)(tb + (size_t)(unsigned)o2 + 16 * c8);      \
        uint4 u3 = *(const uint4*)(tb + (size_t)(unsigned)o3 + 16 * c8);      \
        a0 += unpk(u0.x); a1 += unpk(u0.y); a2 += unpk(u0.z); a3 += unpk(u0.w);\
        b0 += unpk(u1.x); b1 += unpk(u1.y); b2 += unpk(u1.z); b3 += unpk(u1.w);\
        a0 += unpk(u2.x); a1 += unpk(u2.y); a2 += unpk(u2.z); a3 += unpk(u2.w);\
        b0 += unpk(u3.x); b1 += unpk(u3.y); b2 += unpk(u3.z); b3 += unpk(u3.w);\
    }

__global__ void aggregate_relu_kernel(const int* __restrict__ rowptr,
                                      const int* __restrict__ colb,
                                      const unsigned* __restrict__ tt,  // (NN+1) x 32
                                      unsigned* rh) {                   // NN x 32
    __shared__ int lcol[AGG_CAP];
    const int t = threadIdx.x;
    const int n0 = blockIdx.x * 8;
    const int lane = t & 63;
    const int w = t >> 6;
    const int half = lane >> 5;
    const int slot = (lane >> 3) & 3;
    const int c8   = lane & 7;
    const int node = n0 + 2 * w + half;

    const int cbeg  = rowptr[n0];
    const int cendB = rowptr[min(n0 + 8, NN)];
    const int total = cendB - cbeg;
    const bool fast = (total <= AGG_CAP);
    if (fast) {
        for (int i = t; i < total; i += 256) lcol[i] = colb[cbeg + i];
    }
    __syncthreads();

    if (node >= NN) return;
    const int beg = rowptr[node], end = rowptr[node + 1];
    const int deg = end - beg;
    int niter = (deg + 3) >> 2;
    niter = max(niter, __shfl_xor(niter, 32));   // wave-uniform

    const char* tb = (const char*)tt;
    const int zoff = NN * 128;                   // zero row (byte offset)
    v2f a0 = {0.f, 0.f}, a1 = {0.f, 0.f}, a2 = {0.f, 0.f}, a3 = {0.f, 0.f};
    v2f b0 = {0.f, 0.f}, b1 = {0.f, 0.f}, b2 = {0.f, 0.f}, b3 = {0.f, 0.f};

    int jj = beg + slot;
    int it = 0;
    if (fast) {
        for (; it + 4 <= niter; it += 4, jj += 16) {
            int jc0 = min(jj,      end - 1) - cbeg;
            int jc1 = min(jj + 4,  end - 1) - cbeg;
            int jc2 = min(jj + 8,  end - 1) - cbeg;
            int jc3 = min(jj + 12, end - 1) - cbeg;
            AGG_STEP(lcol[jc0], lcol[jc1], lcol[jc2], lcol[jc3])
        }
        for (; it < niter; ++it, jj += 4) {
            int jc0 = min(jj, end - 1) - cbeg;
            int o0 = lcol[jc0];
            o0 = (jj < end) ? o0 : zoff;
            uint4 u0 = *(const uint4*)(tb + (size_t)(unsigned)o0 + 16 * c8);
            a0 += unpk(u0.x); a1 += unpk(u0.y); a2 += unpk(u0.z); a3 += unpk(u0.w);
        }
    } else {
        for (; it + 4 <= niter; it += 4, jj += 16) {
            int jc0 = min(jj,      end - 1);
            int jc1 = min(jj + 4,  end - 1);
            int jc2 = min(jj + 8,  end - 1);
            int jc3 = min(jj + 12, end - 1);
            AGG_STEP(colb[jc0], colb[jc1], colb[jc2], colb[jc3])
        }
        for (; it < niter; ++it, jj += 4) {
            int jc0 = min(jj, end - 1);
            int o0 = colb[jc0];
            o0 = (jj < end) ? o0 : zoff;
            uint4 u0 = *(const uint4*)(tb + (size_t)(unsigned)o0 + 16 * c8);
            a0 += unpk(u0.x); a1 += unpk(u0.y); a2 += unpk(u0.z); a3 += unpk(u0.w);
        }
    }
    a0 += b0; a1 += b1; a2 += b2; a3 += b3;

    a0[0] += __shfl_xor(a0[0], 8);  a0[1] += __shfl_xor(a0[1], 8);
    a1[0] += __shfl_xor(a1[0], 8);  a1[1] += __shfl_xor(a1[1], 8);
    a2[0] += __shfl_xor(a2[0], 8);  a2[1] += __shfl_xor(a2[1], 8);
    a3[0] += __shfl_xor(a3[0], 8);  a3[1] += __shfl_xor(a3[1], 8);
    a0[0] += __shfl_xor(a0[0], 16); a0[1] += __shfl_xor(a0[1], 16);
    a1[0] += __shfl_xor(a1[0], 16); a1[1] += __shfl_xor(a1[1], 16);
    a2[0] += __shfl_xor(a2[0], 16); a2[1] += __shfl_xor(a2[1], 16);
    a3[0] += __shfl_xor(a3[0], 16); a3[1] += __shfl_xor(a3[1], 16);

    if (slot == 0) {
        float inv = 1.0f / fmaxf((float)deg, 1.0f);
        unsigned* p = rh + (size_t)node * 32 + 4 * c8;
        uint4 rr = *(const uint4*)p;
        v2f q0 = unpk(rr.x), q1 = unpk(rr.y), q2 = unpk(rr.z), q3 = unpk(rr.w);
        float h0 = fmaxf(fmaf(a0[0], inv, q0[0]), 0.0f);
        float h1 = fmaxf(fmaf(a0[1], inv, q0[1]), 0.0f);
        float h2 = fmaxf(fmaf(a1[0], inv, q1[0]), 0.0f);
        float h3 = fmaxf(fmaf(a1[1], inv, q1[1]), 0.0f);
        float h4 = fmaxf(fmaf(a2[0], inv, q2[0]), 0.0f);
        float h5 = fmaxf(fmaf(a2[1], inv, q2[1]), 0.0f);
        float h6 = fmaxf(fmaf(a3[0], inv, q3[0]), 0.0f);
        float h7 = fmaxf(fmaf(a3[1], inv, q3[1]), 0.0f);
        uint4 wv4;
        wv4.x = f2bf(h0) | (f2bf(h1) << 16);
        wv4.y = f2bf(h2) | (f2bf(h3) << 16);
        wv4.z = f2bf(h4) | (f2bf(h5) << 16);
        wv4.w = f2bf(h6) | (f2bf(h7) << 16);
        *(uint4*)p = wv4;
    }
}

// ---------------------------------------------------------------------------
// Head GEMM: out = h(bf16) @ Wlin.T + blin.
__global__ __launch_bounds__(256) void head_kernel(
    const unsigned* __restrict__ hu,      // NN x 32 bf16x2
    const float* __restrict__ Wlin,
    const float* __restrict__ blin,
    float* __restrict__ out)
{
    __shared__ float As[64][132];
    __shared__ float Bs[64][18];
    const int t = threadIdx.x;

    {
        int c = t & 15, j = t >> 4;
        float4 v = *(const float4*)(Wlin + (size_t)c * 64 + 4 * j);
        Bs[4 * j + 0][c] = v.x; Bs[4 * j + 1][c] = v.y;
        Bs[4 * j + 2][c] = v.z; Bs[4 * j + 3][c] = v.w;
    }
    const int m0 = blockIdx.x * 128;
    {
        int kq = t & 7;
        int nb = t >> 3;
        for (int rep = 0; rep < 4; ++rep) {
            int n = nb + 32 * rep;
            int gn = m0 + n;
            uint4 u = (gn < NN) ? *(const uint4*)(hu + (size_t)gn * 32 + 4 * kq)
                                : make_uint4(0u, 0u, 0u, 0u);
            int kk = 8 * kq;
            As[kk + 0][n] = u2f(u.x << 16); As[kk + 1][n] = u2f(u.x & 0xFFFF0000u);
            As[kk + 2][n] = u2f(u.y << 16); As[kk + 3][n] = u2f(u.y & 0xFFFF0000u);
            As[kk + 4][n] = u2f(u.z << 16); As[kk + 5][n] = u2f(u.z & 0xFFFF0000u);
            As[kk + 6][n] = u2f(u.w << 16); As[kk + 7][n] = u2f(u.w & 0xFFFF0000u);
        }
    }
    __syncthreads();

    const int tn = t & 31;
    const int tc = t >> 5;
    const int c0 = 2 * tc;
    float acc[4][2];
    #pragma unroll
    for (int i = 0; i < 4; ++i) { acc[i][0] = blin[c0]; acc[i][1] = blin[c0 + 1]; }

    #pragma unroll 16
    for (int k = 0; k < 64; ++k) {
        float4 a = *(const float4*)&As[k][4 * tn];
        float b0 = Bs[k][c0], b1 = Bs[k][c0 + 1];
        float av[4] = {a.x, a.y, a.z, a.w};
        #pragma unroll
        for (int i = 0; i < 4; ++i) {
            acc[i][0] = fmaf(av[i], b0, acc[i][0]);
            acc[i][1] = fmaf(av[i], b1, acc[i][1]);
        }
    }
    #pragma unroll
    for (int i = 0; i < 4; ++i) {
        int gn = m0 + 4 * tn + i;
        if (gn < NN)
            *(float2*)(out + (size_t)gn * 16 + c0) = make_float2(acc[i][0], acc[i][1]);
    }
}

// ---------------------------------------------------------------------------
extern "C" void kernel_launch(void* const* d_in, const int* in_sizes, int n_in,
                              void* d_out, int out_size, void* d_ws, size_t ws_size,
                              hipStream_t stream) {
    const float* x    = (const float*)d_in[0];
    const void*  ei   = d_in[1];
    const float* W1l  = (const float*)d_in[2];
    const float* b1   = (const float*)d_in[3];
    const float* W1r  = (const float*)d_in[4];
    const float* W2l  = (const float*)d_in[5];
    const float* b2   = (const float*)d_in[6];
    const float* W2r  = (const float*)d_in[7];
    const float* Wlin = (const float*)d_in[8];
    const float* blin = (const float*)d_in[9];
    float* out = (float*)d_out;

    char* w = (char*)d_ws;
    int*      flag   = (int*)w;                                   // @ 0
    int*      bcnt   = (int*)(w + (size_t)4 * 1024);              // @ 4K
    int*      rowptr = (int*)(w + (size_t)1024 * 1024);           // @ 1M  (400 KB+4)
    int*      colb   = (int*)(w + (size_t)2 * 1024 * 1024);       // @ 2M  (6.4 MB)
    int*      bpk    = (int*)(w + (size_t)10 * 1024 * 1024);      // @ 10M (9.6 MB packed)
    unsigned* T      = (unsigned*)(w + (size_t)30 * 1024 * 1024); // @ 30M (12.8 MB + zero row)
    unsigned* R      = (unsigned*)(w + (size_t)43 * 1024 * 1024); // @ 43M (12.8 MB bf16 r/h)

    detect_mode_kernel<<<1, 256, 0, stream>>>((const int*)ei, flag, bcnt);

    // ---- fused: B1 (blocks 0..390) + layer-1 MFMA GEMM (blocks 391..) ----
    b1_gemm1_kernel<<<B1_BLOCKS + GEMM_BLOCKS, 256, 0, stream>>>(
        ei, flag, bcnt, bpk, x, W1l, W1r, b1, T, R);

    bucket_to_csr_kernel<<<NBUCK, 512, 0, stream>>>(bcnt, bpk, rowptr, colb);

    const int aggBlocks = (NN + 7) / 8;        // 12500 (8 nodes per block)
    const int headBlocks = (NN + 127) / 128;

    aggregate_relu_kernel<<<aggBlocks, 256, 0, stream>>>(rowptr, colb, T, R); // h1 in R

    gemm2_kernel<<<GEMM_BLOCKS, 256, 0, stream>>>(R, W2l, W2r, b2, T, R);
    aggregate_relu_kernel<<<aggBlocks, 256, 0, stream>>>(rowptr, colb, T, R); // h2 in R

    head_kernel<<<headBlocks, 256, 0, stream>>>(R, Wlin, blin, out);
}